// Round 1
// baseline (4757.658 us; speedup 1.0000x reference)
//
#include <hip/hip_runtime.h>
#include <hip/hip_bf16.h>
#include <cstdint>
#include <cstddef>

using bf16 = __hip_bfloat16;
typedef __attribute__((ext_vector_type(8))) short   bf16x8_t;  // 8 bf16 (4 VGPRs)
typedef __attribute__((ext_vector_type(4))) float   f32x4_t;   // mfma accumulator

// ---------------- workspace byte offsets ----------------
#define XT_OFF   ((size_t)0)            // [32 wg][256 t][16 r][96] bf16
#define UF_OFF   ((size_t)25165824)     // [336][128] bf16 gate-ordered U strips (fwd)
#define UB_OFF   ((size_t)25251840)     // (bwd)
#define WF_OFF   ((size_t)25337856)     // fwd W shifted strips
#define WB_OFF   ((size_t)25423872)     // bwd W strips
#define DW_OFF   ((size_t)25509888)     // dec_W strips [4][64][256] bf16
#define MW_OFF   ((size_t)25640960)     // mean_W^T strips [4][64][64] bf16
#define SAV_OFF  ((size_t)25673728)     // saved h_back [32 wg][64 slot][16*128] bf16 (8,388,608 B)
#define CST_OFF  ((size_t)34062336)     // fp32 consts (1856 f32)
#define FUF_OFF  ((size_t)34069760)     // FusedF [4][336][64] bf16 (172,032 B)
#define FUB_OFF  ((size_t)34241792)     // FusedB [4][336][64] bf16
#define WS_NEED  ((size_t)34413824)

#define MFMA16(a,b,c) __builtin_amdgcn_mfma_f32_16x16x32_bf16((a),(b),(c),0,0,0)

// counted barrier: drain LDS only; global loads/stores stay in flight
#define BAR()    asm volatile("s_waitcnt lgkmcnt(0)\n\ts_barrier" ::: "memory")
// full drain + barrier (backward->forward phase transition)
#define DRAINB() asm volatile("s_waitcnt vmcnt(0)\n\ts_barrier" ::: "memory")

#define BFLO(u) __uint_as_float(((uint32_t)(u))<<16)
#define BFHI(u) __uint_as_float(((uint32_t)(u))&0xffff0000u)

static __device__ __forceinline__ uint32_t bf16bits(float f){
  bf16 h = __float2bfloat16(f);
  unsigned short u; __builtin_memcpy(&u, &h, 2);
  return (uint32_t)u;
}

// ---------------- static schedule (mask t%16==0, batch-shared) ----------------
// type 0 BCELL: t, save = sav slot (-1 none)
// type 1 FA   : t   (X = xT via pX prefetch)
// type 2 FF   : gisrc 0 = gi from accF regs (prev op is the source DEC), 1 = LDS slot srcidx
// type 3 DEC  : t, lvl, hsrc, srcidx, save = gi LDS slot (-1 odd/IMM), aux&2 = also compute CH gi (accC)
// type 4 CH   : hsrc, srcidx, gisrc 1 = gi from accC regs (prev op is the source DEC), aux = spl spill (-1 none)
struct Op { uint8_t type, t; int8_t lvl, save, hsrc, srcidx, gisrc, aux; };
struct Sched { Op ops[960]; short n; };

constexpr int slot_of(int tp){ int k=(tp-1)/16; int m=tp%16;
  int pos = (m==9)?0:((m==13)?1:((m==15)?2:3)); return 4*k+pos; }

constexpr Sched build_sched(){
  Sched s{}; int i=0;
  for (int t=255; t>=1; --t){
    int tp=t+1, m=tp%16; int8_t sv=-1;
    if (m==9||m==13||m==15||m==0) sv=(int8_t)slot_of(tp);
    s.ops[i++] = Op{(uint8_t)0,(uint8_t)t,(int8_t)0,sv,(int8_t)0,(int8_t)0,(int8_t)0,(int8_t)0};
  }
  s.ops[i++] = Op{(uint8_t)1,(uint8_t)0,(int8_t)0,(int8_t)-1,(int8_t)0,(int8_t)0,(int8_t)0,(int8_t)0}; // FA(0)
  for (int blk=0; blk<16; ++blk){
    int ba=16*blk; bool last=(blk==15);
    int s16=slot_of(ba+16), s9=slot_of(ba+9), s13=slot_of(ba+13), s15=slot_of(ba+15);
#define PD(dt,lv,hs,si,gs,ic) s.ops[i++]=Op{(uint8_t)3,(uint8_t)(ba+(dt)),(int8_t)(lv),(int8_t)(gs),(int8_t)(hs),(int8_t)(si),(int8_t)0,(int8_t)((ic)?2:0)};
#define PC(hs,si,gi,sp)       s.ops[i++]=Op{(uint8_t)4,(uint8_t)0,(int8_t)0,(int8_t)-1,(int8_t)(hs),(int8_t)(si),(int8_t)(gi),(int8_t)(sp)};
#define PFI()                 s.ops[i++]=Op{(uint8_t)2,(uint8_t)0,(int8_t)0,(int8_t)-1,(int8_t)0,(int8_t)0,(int8_t)0,(int8_t)0};
#define PFS(sl)               s.ops[i++]=Op{(uint8_t)2,(uint8_t)0,(int8_t)0,(int8_t)-1,(int8_t)0,(int8_t)(sl),(int8_t)1,(int8_t)0};
#define PA(ft)                s.ops[i++]=Op{(uint8_t)1,(uint8_t)(ba+(ft)),(int8_t)0,(int8_t)-1,(int8_t)0,(int8_t)0,(int8_t)0,(int8_t)0};
    PD(8,3,1,s16,0,1)
    PC(1,s9,1,0) PC(0,0,0,1) PC(0,0,0,-1) PC(0,0,0,-1)
    PD(4,2,2,0,1,1)
    PC(0,0,1,2) PC(0,0,0,-1)
    PD(2,1,2,2,2,1)
    PC(0,0,1,-1)
    PD(1,0,0,0,-1,0)
    PFI() PFS(2)
    PD(3,0,2,2,-1,0)
    PFI() PFS(1)
    PD(6,1,2,0,1,1)
    PC(2,1,1,-1)
    PD(5,0,0,0,-1,0)
    PFI() PFS(1)
    PD(7,0,2,0,-1,0)
    PFI() PFS(0)
    PD(12,2,1,s16,0,1)
    PC(1,s13,1,3) PC(0,0,0,-1)
    PD(10,1,2,3,1,1)
    PC(0,0,1,-1)
    PD(9,0,0,0,-1,0)
    PFI() PFS(1)
    PD(11,0,2,3,-1,0)
    PFI() PFS(0)
    PD(14,1,1,s16,0,1)
    PC(1,s15,1,-1)
    PD(13,0,0,0,-1,0)
    PFI() PFS(0)
    PD(15,0,1,s16,-1,0)
    if(!last){ PFI(); PA(16); }
#undef PD
#undef PC
#undef PFI
#undef PFS
#undef PA
  }
  s.n=(short)i; return s;
}
__constant__ Sched g_sched = build_sched();

// ---------------- prep kernels ----------------
__global__ void k_xt(const float* __restrict__ a, bf16* __restrict__ xT){
  int b=blockIdx.x, t=threadIdx.x;
  int wgi=b>>4, r=b&15;
  bf16* dst = xT + (((size_t)wgi*256 + t)*16 + r)*96;
  const float* ap = a + (size_t)b*64*256*3;
  for (int c=0;c<64;++c) dst[c] = __float2bfloat16(ap[((size_t)c*256+t)*3]);
  dst[64] = __float2bfloat16(ap[(size_t)t*3 + 2]);
  bf16 z = __float2bfloat16(0.f);
  for (int c=65;c<96;++c) dst[c]=z;
}

__global__ void k_obs(const float* __restrict__ a, float* __restrict__ out){
  int b=blockIdx.x, d=threadIdx.x; // 64 threads
  for (int kk=0;kk<16;++kk){ int t=kk*16;
    float v = (d<63)? a[(((size_t)b*64 + d+1)*256 + t)*3]
                    : a[((size_t)b*64*256 + t)*3 + 2];
    out[((size_t)b*64 + d)*256 + t] = v;
  }
}

__global__ void k_wt(const float* __restrict__ gru_U, const float* __restrict__ bgru_U,
                     const float* __restrict__ gru_W, const float* __restrict__ bgru_W,
                     bf16* Uf, bf16* Ub, bf16* Wf, bf16* Wb){
  int c=blockIdx.x, k=threadIdx.x; // 336 x 128
  int g=c/48, rm=c%48, e=rm/16, l=rm%16, j=16*g+l;
  bool val = j<100; int gc = val? (e*100+j) : 0;
  bf16 z = __float2bfloat16(0.f);
  Uf[(size_t)c*128+k] = (val&&k<100)? __float2bfloat16(gru_U[k*300+gc]) : z;
  Ub[(size_t)c*128+k] = (val&&k<100)? __float2bfloat16(bgru_U[k*300+gc]) : z;
  Wf[(size_t)c*128+k] = (val&&k>=1&&k<=64)? __float2bfloat16(gru_W[(k-1)*300+gc]) : z;
  Wb[(size_t)c*128+k] = (val&&k<65)? __float2bfloat16(bgru_W[k*300+gc]) : z;
}

__global__ void k_decw(const float* __restrict__ dec_W, bf16* dWt){
  int idx=blockIdx.x; int lvl=idx/64, n=idx%64; int k=threadIdx.x; // 256 blocks x 256 thr
  float v=0.f;
  if (n<50){
    if (k<100) v = dec_W[(lvl*200+k)*50+n];
    else if (k>=128 && k<228) v = dec_W[(lvl*200+k-28)*50+n];
  }
  dWt[(size_t)idx*256+k] = __float2bfloat16(v);
}

__global__ void k_mw(const float* __restrict__ mean_W, bf16* MW){
  int idx=blockIdx.x; int lvl=idx/64, c=idx%64; int k=threadIdx.x; // 64
  MW[(size_t)idx*64+k] = (k<50)? __float2bfloat16(mean_W[(lvl*50+k)*64+c]) : __float2bfloat16(0.f);
}

__global__ void k_consts(const float* __restrict__ gru_b, const float* __restrict__ bgru_b,
                         const float* __restrict__ mean_b, const float* __restrict__ dec_b,
                         float* cst){
  int tid=threadIdx.x;
  for (int u=tid; u<336; u+=256){
    int c=u; int g=c/48, rm=c%48, e=rm/16, l=rm%16, j=16*g+l;
    float b0f=0,b1f=0,b0b=0,b1b=0;
    if (j<100){ int gc=e*100+j;
      b0f=gru_b[gc];  b1f=gru_b[300+gc];
      b0b=bgru_b[gc]; b1b=bgru_b[300+gc]; }
    cst[u]=b0f; cst[336+u]=b1f; cst[672+u]=b0b; cst[1008+u]=b1b;
  }
  if (tid<256){
    int lvl=tid/64, m=tid%64;
    cst[1344+tid]=mean_b[lvl*64+m];
    // dec col 50: constant 1.0 (dW col-50 weights are zero) -> carries Fused bias row
    cst[1600+tid]=(m<50)? dec_b[lvl*50+m] : ((m==50)? 1.0f : 0.f);
  }
}

// FusedF[lvl][c][k] = (meanW[:,1:] @ gru_W[0:63])[k][gc], row k=50 = mb[1:]@gru_W[0:63] + gru_W[63]
// FusedB[lvl][c][k] = (meanW      @ bgru_W[0:64])[k][gc], row k=50 = mb@bgru_W[0:64] + bgru_W[64]
__global__ void k_fused(const float* __restrict__ mean_W, const float* __restrict__ mean_b,
                        const float* __restrict__ gru_W, const float* __restrict__ bgru_W,
                        bf16* FUF, bf16* FUB){
  int idx=blockIdx.x;            // 4*336
  int lvl=idx/336, c=idx%336;
  int k=threadIdx.x;             // 64
  int g=c/48, rm=c%48, e=rm/16, l=rm%16, j=16*g+l;
  float sf=0.f, sb=0.f;
  if (j<100){
    int gc=e*100+j;
    if (k<50){
      for (int m=0;m<64;++m){
        float w = mean_W[(size_t)(lvl*50+k)*64+m];
        if (m>=1) sf += w * gru_W[(size_t)(m-1)*300+gc];
        sb += w * bgru_W[(size_t)m*300+gc];
      }
    } else if (k==50){
      for (int m=0;m<64;++m){
        float w = mean_b[lvl*64+m];
        if (m>=1) sf += w * gru_W[(size_t)(m-1)*300+gc];
        sb += w * bgru_W[(size_t)m*300+gc];
      }
      sf += gru_W[(size_t)63*300+gc];
      sb += bgru_W[(size_t)64*300+gc];
    }
  }
  FUF[(size_t)idx*64+k] = __float2bfloat16(sf);
  FUB[(size_t)idx*64+k] = __float2bfloat16(sb);
}

__global__ void k_sz(uint4* p){
  p[(size_t)blockIdx.x*256 + threadIdx.x] = make_uint4(0u,0u,0u,0u);
}

// ---------------- main persistent kernel: 32 WGs x 256 thr, 16 batch rows each ----------------
__launch_bounds__(256, 1)
__global__ void naomi_main(unsigned char* __restrict__ ws, float* __restrict__ out){
  const int tid=threadIdx.x, wg=blockIdx.x;
  const int lane=tid&63, wv=tid>>6;
  const int l15=lane&15, q=lane>>4;
  const int ng=(wv<3)?2:1;

  const bf16* xT = (const bf16*)(ws + XT_OFF);
  const bf16* Uf = (const bf16*)(ws + UF_OFF);
  const bf16* Ub = (const bf16*)(ws + UB_OFF);
  const bf16* Wf = (const bf16*)(ws + WF_OFF);
  const bf16* Wb = (const bf16*)(ws + WB_OFF);
  const bf16* dW = (const bf16*)(ws + DW_OFF);
  const bf16* MW = (const bf16*)(ws + MW_OFF);
  const bf16* FUF = (const bf16*)(ws + FUF_OFF);
  const bf16* FUB = (const bf16*)(ws + FUB_OFF);
  bf16* sav = (bf16*)(ws + SAV_OFF);
  unsigned char* sav8 = (unsigned char*)(ws + SAV_OFF);
  const float* cst = (const float*)(ws + CST_OFF);

  // LDS (61,056 B): s_h 2x1696 | s_hbk 2x1696 | s_dec [16][72] | spl 4x[16][128] | gif 3 slots x [3][100][16]
  __shared__ alignas(16) unsigned char smem[61056];
  bf16* s_h    = (bf16*)(smem + 0);      // 6784 B
  bf16* s_hbk  = (bf16*)(smem + 6784);   // 6784 B
  bf16* s_dec  = (bf16*)(smem + 13568);  // 2304 B
  bf16* s_spl  = (bf16*)(smem + 15872);  // 16384 B
  #define GIF_B 32256                    // 28800 B

  for (int u=tid; u<15264; u+=256) ((uint32_t*)smem)[u]=0u;

  // per-thread gate biases [g2][dir] (z/r pre-folded b0+b1)
  float Bz[2][2],Br[2][2],Bn0[2][2],Bn1[2][2];
  #pragma unroll
  for (int g2=0; g2<2; ++g2){
    if (g2<ng){
      int cz=48*(wv+4*g2)+l15;
      Bz[g2][1]=cst[cz]+cst[336+cz];          Br[g2][1]=cst[cz+16]+cst[336+cz+16];
      Bn0[g2][1]=cst[cz+32];                  Bn1[g2][1]=cst[336+cz+32];
      Bz[g2][0]=cst[672+cz]+cst[1008+cz];     Br[g2][0]=cst[672+cz+16]+cst[1008+cz+16];
      Bn0[g2][0]=cst[672+cz+32];              Bn1[g2][0]=cst[1008+cz+32];
    } else {
      Bz[g2][0]=Bz[g2][1]=Br[g2][0]=Br[g2][1]=0.f;
      Bn0[g2][0]=Bn0[g2][1]=Bn1[g2][0]=Bn1[g2][1]=0.f;
    }
  }
  const int c16 = 16*wv+l15;
  float mb_l[4], db_l[4];
  #pragma unroll
  for (int l=0;l<4;++l){ mb_l[l]=cst[1344+l*64+c16]; db_l[l]=cst[1600+l*64+c16]; }

  // U strips resident in registers
  bf16x8_t rUf[2][3][4], rUb[2][3][4];
  #pragma unroll
  for (int g2=0; g2<2; ++g2){
    if (g2<ng){
      #pragma unroll
      for (int e=0;e<3;++e){ int c=48*(wv+4*g2)+16*e+l15;
        #pragma unroll
        for (int s=0;s<4;++s){
          rUf[g2][e][s] = *(const bf16x8_t*)(Uf + (size_t)c*128 + 8*q + 32*s);
          rUb[g2][e][s] = *(const bf16x8_t*)(Ub + (size_t)c*128 + 8*q + 32*s);
        } }
    }
  }
  __syncthreads();

  // fp32 master state in registers
  float h_reg[2][4], hb_reg[2][4];
  #pragma unroll
  for (int g2=0;g2<2;++g2){
    #pragma unroll
    for (int i=0;i<4;++i){ h_reg[g2][i]=0.f; hb_reg[g2][i]=0.f; }
  }
  int hcur=0, bcur=0;

  // prefetch + loop-carried gi registers
  bf16x8_t pX[3], pHB[4];
  float pHold[2][4];
  f32x4_t accF[2][3], accC[2][3];
  #pragma unroll
  for (int g2=0;g2<2;++g2){
    #pragma unroll
    for (int e=0;e<3;++e){ accF[g2][e]=(f32x4_t){0,0,0,0}; accC[g2][e]=(f32x4_t){0,0,0,0}; }
    #pragma unroll
    for (int i=0;i<4;++i) pHold[g2][i]=0.f;
  }
  { // prologue: prefetch X for op[0] (BCELL t=255)
    const Op on = g_sched.ops[0];
    const bf16* px = xT + (((size_t)wg*256 + on.t)*16 + l15)*96 + 8*q;
    #pragma unroll
    for (int s=0;s<3;++s) pX[s] = *(const bf16x8_t*)(px + 32*s);
  }

  const int nops = g_sched.n;
  Op opq = g_sched.ops[0];
  for (int io=0; io<nops; ++io){
    const Op op = opq;
    const Op on = g_sched.ops[(io+1<nops)? io+1 : io];
    opq = on;
    if (io==255) DRAINB();   // backward sav-stores -> forward sav-reads transition
    if (op.type != 3){
      const bool fwd = (op.type==1)||(op.type==2);
      // ---- A fragments (h operand) ----
      bf16x8_t aH[4];
      if (!fwd && op.hsrc==1){
        #pragma unroll
        for (int s=0;s<4;++s) aH[s]=pHB[s];
      } else if (!fwd && op.hsrc==2){
        const bf16* hp = s_spl + (size_t)op.srcidx*2048 + l15*128 + 8*q;
        #pragma unroll
        for (int s=0;s<4;++s) aH[s] = *(const bf16x8_t*)(hp + 32*s);
      } else {
        const bf16* hp = (fwd? s_h + hcur*1696 : s_hbk + bcur*1696) + l15*104 + 8*q;
        #pragma unroll
        for (int s=0;s<4;++s) aH[s] = *(const bf16x8_t*)(hp + 32*s);
      }
      // ---- deferred-FF gi preload from LDS slot ----
      uint2 gw[2][3];
      if (op.type==2 && op.gisrc==1){
        #pragma unroll
        for (int g2=0; g2<2; ++g2){ if (g2<ng){ int j=16*(wv+4*g2)+l15;
          if (j<100){
            #pragma unroll
            for (int e=0;e<3;++e)
              gw[g2][e] = *(const uint2*)(smem + GIF_B + ((size_t)((op.srcidx*3+e)*100 + j)*32 + 8*q));
          } } }
      }
      // ---- U MFMAs (h @ U) ----
      f32x4_t accB[2][3];
      #pragma unroll
      for (int g2=0;g2<2;++g2)
        #pragma unroll
        for (int e=0;e<3;++e) accB[g2][e]=(f32x4_t){0,0,0,0};
      if (fwd){
        #pragma unroll
        for (int g2=0;g2<2;++g2){ if (g2<ng){
          #pragma unroll
          for (int e=0;e<3;++e){
            #pragma unroll
            for (int s=0;s<4;++s)
              accB[g2][e] = MFMA16(aH[s], rUf[g2][e][s], accB[g2][e]);
          } } }
      } else {
        #pragma unroll
        for (int g2=0;g2<2;++g2){ if (g2<ng){
          #pragma unroll
          for (int e=0;e<3;++e){
            #pragma unroll
            for (int s=0;s<4;++s)
              accB[g2][e] = MFMA16(aH[s], rUb[g2][e][s], accB[g2][e]);
          } } }
      }
      // ---- X MFMAs (only raw-input ops: BCELL / FA) ----
      f32x4_t accA[2][3];
      if (op.type<=1){
        #pragma unroll
        for (int g2=0;g2<2;++g2)
          #pragma unroll
          for (int e=0;e<3;++e) accA[g2][e]=(f32x4_t){0,0,0,0};
        const bf16* Wp = fwd? Wf : Wb;
        #pragma unroll
        for (int g2=0;g2<2;++g2){ if (g2<ng){
          #pragma unroll
          for (int e=0;e<3;++e){ int c=48*(wv+4*g2)+16*e+l15;
            const bf16* bp = Wp + (size_t)c*128 + 8*q;
            #pragma unroll
            for (int s=0;s<3;++s)
              accA[g2][e] = MFMA16(pX[s], *(const bf16x8_t*)(bp+32*s), accA[g2][e]);
          } } }
      }
      // ---- prefetch for op[io+1] ----
      if (on.type==0 || on.type==1){
        const bf16* px = xT + (((size_t)wg*256 + on.t)*16 + l15)*96 + 8*q;
        #pragma unroll
        for (int s=0;s<3;++s) pX[s] = *(const bf16x8_t*)(px + 32*s);
      }
      if ((on.type==3 || on.type==4) && on.hsrc==1){
        const bf16* ps = sav + (size_t)(wg*64+on.srcidx)*2048 + l15*128 + 8*q;
        #pragma unroll
        for (int s=0;s<4;++s) pHB[s] = *(const bf16x8_t*)(ps + 32*s);
      }
      if (on.type==4 && on.hsrc==1){
        const bf16* ph = sav + (size_t)(wg*64+on.srcidx)*2048;
        #pragma unroll
        for (int g2=0;g2<2;++g2){ if (g2<ng){ int j=16*(wv+4*g2)+l15;
          if (j<100){
            #pragma unroll
            for (int i=0;i<4;++i) pHold[g2][i] = __bfloat162float(ph[(4*q+i)*128 + j]);
          } } }
      }
      // ---- BCELL: coalesced save of pre-update h_back (current s_hbk buffer) ----
      if (op.type==0 && op.save>=0 && tid<208){
        int r=tid/13, c=tid-13*r;
        const uint4 v = *(const uint4*)(smem + 6784 + bcur*3392 + r*208 + c*16);
        *(uint4*)(sav8 + ((size_t)(wg*64+op.save))*4096 + (size_t)r*256 + c*16) = v;
      }
      // ---- gate stage ----
      bf16* wr = fwd? (s_h + (hcur^1)*1696) : (s_hbk + (bcur^1)*1696);
      const int fi = fwd?1:0;
      #pragma unroll
      for (int g2=0;g2<2;++g2){ if (g2<ng){ int j=16*(wv+4*g2)+l15;
        if (j<100){
          float bz=Bz[g2][fi], br=Br[g2][fi], b0n=Bn0[g2][fi], b1n=Bn1[g2][fi];
          #pragma unroll
          for (int i=0;i<4;++i){
            int r=4*q+i;
            float gz,gr,gn;
            if (op.type<=1){
              gz=accA[g2][0][i]; gr=accA[g2][1][i]; gn=accA[g2][2][i];
            } else if (op.type==2){
              if (op.gisrc==1){
                gz = (i==0)?BFLO(gw[g2][0].x):(i==1)?BFHI(gw[g2][0].x):(i==2)?BFLO(gw[g2][0].y):BFHI(gw[g2][0].y);
                gr = (i==0)?BFLO(gw[g2][1].x):(i==1)?BFHI(gw[g2][1].x):(i==2)?BFLO(gw[g2][1].y):BFHI(gw[g2][1].y);
                gn = (i==0)?BFLO(gw[g2][2].x):(i==1)?BFHI(gw[g2][2].x):(i==2)?BFLO(gw[g2][2].y):BFHI(gw[g2][2].y);
              } else {
                gz=accF[g2][0][i]; gr=accF[g2][1][i]; gn=accF[g2][2][i];
              }
            } else {
              if (op.gisrc==1){ gz=accC[g2][0][i]; gr=accC[g2][1][i]; gn=accC[g2][2][i]; }
              else { gz=0.f; gr=0.f; gn=0.f; }
            }
            float hz=accB[g2][0][i], hr=accB[g2][1][i], hnv=accB[g2][2][i];
            float hold;
            if (fwd) hold = h_reg[g2][i];
            else if (op.hsrc==0) hold = hb_reg[g2][i];
            else if (op.hsrc==1) hold = pHold[g2][i];
            else hold = __bfloat162float(s_spl[(size_t)op.srcidx*2048 + r*128 + j]);
            float az = gz+hz+bz; az=fminf(fmaxf(az,-30.f),30.f);
            float ar = gr+hr+br; ar=fminf(fmaxf(ar,-30.f),30.f);
            float z  = 1.f/(1.f+__expf(-az));
            float rg = 1.f/(1.f+__expf(-ar));
            float an = gn+b0n+rg*(hnv+b1n); an=fminf(fmaxf(an,-15.f),15.f);
            float e2 = __expf(2.f*an);
            float nn = (e2-1.f)/(e2+1.f);
            float hnew = z*hold + (1.f-z)*nn;
            if (fwd) h_reg[g2][i]=hnew; else hb_reg[g2][i]=hnew;
            wr[r*104+j] = __float2bfloat16(hnew);
            if (op.type==4 && op.aux>=0)
              s_spl[(size_t)op.aux*2048 + r*128 + j] = __float2bfloat16(hnew);
          }
        } } }
      if (fwd) hcur^=1; else bcur^=1;
      BAR();
    } else {
      // ---- DEC: dec = relu([h,hb]@decW+db); mean = dec@meanW+mb; gi_ff/gi_ch = dec@Fused ----
      const int lvl=op.lvl, t=op.t, gslot=op.save;
      const bool doC = (op.aux & 2);
      bf16x8_t aG[8];
      { const bf16* hp = s_h + hcur*1696 + l15*104 + 8*q;
        #pragma unroll
        for (int s=0;s<4;++s) aG[s] = *(const bf16x8_t*)(hp + 32*s); }
      if (op.hsrc==1){
        #pragma unroll
        for (int s=0;s<4;++s) aG[4+s]=pHB[s];
      } else if (op.hsrc==2){
        const bf16* hp = s_spl + (size_t)op.srcidx*2048 + l15*128 + 8*q;
        #pragma unroll
        for (int s=0;s<4;++s) aG[4+s] = *(const bf16x8_t*)(hp + 32*s);
      } else {
        const bf16* hp = s_hbk + bcur*1696 + l15*104 + 8*q;
        #pragma unroll
        for (int s=0;s<4;++s) aG[4+s] = *(const bf16x8_t*)(hp + 32*s);
      }
      // early FusedF B-frag loads (latency hidden under gemm1 + barrier; survive the barrier)
      bf16x8_t bFF[2][3][2];
      #pragma unroll
      for (int g2=0;g2<2;++g2){ if (g2<ng){
        #pragma unroll
        for (int e=0;e<3;++e){ int c=48*(wv+4*g2)+16*e+l15;
          const bf16* fp = FUF + ((size_t)(lvl*336+c))*64 + 8*q;
          bFF[g2][e][0] = *(const bf16x8_t*)(fp);
          bFF[g2][e][1] = *(const bf16x8_t*)(fp+32);
        } } }
      // gemm1: [16,256] x dec strips
      { const bf16* bp = dW + ((size_t)(lvl*64 + c16))*256 + 8*q;
        f32x4_t a1=(f32x4_t){0,0,0,0}, a2=(f32x4_t){0,0,0,0};
        #pragma unroll
        for (int s=0;s<8;s+=2){
          a1 = MFMA16(aG[s],   *(const bf16x8_t*)(bp+32*s),     a1);
          a2 = MFMA16(aG[s+1], *(const bf16x8_t*)(bp+32*(s+1)), a2);
        }
        // prefetch for op[io+1]
        if (on.type==0 || on.type==1){
          const bf16* px = xT + (((size_t)wg*256 + on.t)*16 + l15)*96 + 8*q;
          #pragma unroll
          for (int s=0;s<3;++s) pX[s] = *(const bf16x8_t*)(px + 32*s);
        }
        if ((on.type==3 || on.type==4) && on.hsrc==1){
          const bf16* ps = sav + (size_t)(wg*64+on.srcidx)*2048 + l15*128 + 8*q;
          #pragma unroll
          for (int s=0;s<4;++s) pHB[s] = *(const bf16x8_t*)(ps + 32*s);
        }
        if (on.type==4 && on.hsrc==1){
          const bf16* ph = sav + (size_t)(wg*64+on.srcidx)*2048;
          #pragma unroll
          for (int g2=0;g2<2;++g2){ if (g2<ng){ int j=16*(wv+4*g2)+l15;
            if (j<100){
              #pragma unroll
              for (int i=0;i<4;++i) pHold[g2][i] = __bfloat162float(ph[(4*q+i)*128 + j]);
            } } }
        }
        float db = db_l[lvl];   // col 50 carries constant 1.0
        #pragma unroll
        for (int i=0;i<4;++i){ float v=fmaxf(a1[i]+a2[i]+db,0.f); s_dec[(4*q+i)*72 + c16]=__float2bfloat16(v); }
      }
      BAR();
      // aD frags (dec, K=64)
      bf16x8_t aD[2];
      #pragma unroll
      for (int s=0;s<2;++s) aD[s] = *(const bf16x8_t*)(s_dec + l15*72 + 8*q + 32*s);
      // FusedB loads (only when a CH follows)
      bf16x8_t bFB[2][3][2];
      if (doC){
        #pragma unroll
        for (int g2=0;g2<2;++g2){ if (g2<ng){
          #pragma unroll
          for (int e=0;e<3;++e){ int c=48*(wv+4*g2)+16*e+l15;
            const bf16* fp = FUB + ((size_t)(lvl*336+c))*64 + 8*q;
            bFB[g2][e][0] = *(const bf16x8_t*)(fp);
            bFB[g2][e][1] = *(const bf16x8_t*)(fp+32);
          } } }
      }
      // gemm2: mean -> out
      { const bf16* bp = MW + ((size_t)(lvl*64 + c16))*64 + 8*q;
        f32x4_t am=(f32x4_t){0,0,0,0};
        am = MFMA16(aD[0], *(const bf16x8_t*)(bp),    am);
        am = MFMA16(aD[1], *(const bf16x8_t*)(bp+32), am);
        float mb = mb_l[lvl];
        #pragma unroll
        for (int i=0;i<4;++i){ int r=4*q+i; size_t b=(size_t)wg*16+r;
          float m = am[i]+mb;
          if (c16>=1) out[(b*64 + (c16-1))*256 + t] = m;
          else        out[(b*64 + 63)*256 + t]      = 1.0f;
        } }
      // FF gi: accF = dec @ FusedF (bias via dec[50]=1)
      #pragma unroll
      for (int g2=0;g2<2;++g2){ if (g2<ng){
        #pragma unroll
        for (int e=0;e<3;++e){
          f32x4_t acc=(f32x4_t){0,0,0,0};
          acc = MFMA16(aD[0], bFF[g2][e][0], acc);
          acc = MFMA16(aD[1], bFF[g2][e][1], acc);
          accF[g2][e]=acc;
        } } }
      // deferred FF gi -> LDS slot
      if (gslot>=0){
        #pragma unroll
        for (int g2=0;g2<2;++g2){ if (g2<ng){ int j=16*(wv+4*g2)+l15;
          if (j<100){
            #pragma unroll
            for (int e=0;e<3;++e){
              uint2 pw;
              pw.x = bf16bits(accF[g2][e][0]) | (bf16bits(accF[g2][e][1])<<16);
              pw.y = bf16bits(accF[g2][e][2]) | (bf16bits(accF[g2][e][3])<<16);
              *(uint2*)(smem + GIF_B + ((size_t)((gslot*3+e)*100 + j)*32 + 8*q)) = pw;
            }
          } } }
      }
      // CH gi: accC = dec @ FusedB
      if (doC){
        #pragma unroll
        for (int g2=0;g2<2;++g2){ if (g2<ng){
          #pragma unroll
          for (int e=0;e<3;++e){
            f32x4_t acc=(f32x4_t){0,0,0,0};
            acc = MFMA16(aD[0], bFB[g2][e][0], acc);
            acc = MFMA16(aD[1], bFB[g2][e][1], acc);
            accC[g2][e]=acc;
          } } }
      }
      // no end barrier: tail (s_dec reads, gi/out writes) is disjoint from successor's LDS traffic
    }
  }
}

// ---------------- launch ----------------
extern "C" void kernel_launch(void* const* d_in, const int* in_sizes, int n_in,
                              void* d_out, int out_size, void* d_ws, size_t ws_size,
                              hipStream_t stream){
  (void)out_size;
  const float *a=nullptr,*gru_W=nullptr,*gru_U=nullptr,*gru_b=nullptr,*bgru_W=nullptr,
              *bgru_U=nullptr,*bgru_b=nullptr,*dec_W=nullptr,*dec_b=nullptr,
              *mean_W=nullptr,*mean_b=nullptr;
  int nU=0, nb6=0;
  for (int i=0;i<n_in;++i){
    const float* p=(const float*)d_in[i]; int s=in_sizes[i];
    if      (s==25165824) a=p;
    else if (s==19200)    gru_W=p;
    else if (s==19500)    bgru_W=p;
    else if (s==30000)    { if(nU++==0) gru_U=p; else bgru_U=p; }
    else if (s==600)      { if(nb6++==0) gru_b=p; else bgru_b=p; }
    else if (s==40000)    dec_W=p;
    else if (s==200)      dec_b=p;
    else if (s==12800)    mean_W=p;
    else if (s==256)      mean_b=p;
  }
  if (!a||!gru_W||!gru_U||!gru_b||!bgru_W||!bgru_U||!bgru_b||!dec_W||!dec_b||!mean_W||!mean_b){
    a=(const float*)d_in[0]; gru_W=(const float*)d_in[1]; gru_U=(const float*)d_in[2];
    gru_b=(const float*)d_in[3]; bgru_W=(const float*)d_in[4]; bgru_U=(const float*)d_in[5];
    bgru_b=(const float*)d_in[6]; dec_W=(const float*)d_in[7]; dec_b=(const float*)d_in[8];
    mean_W=(const float*)d_in[9]; mean_b=(const float*)d_in[10];
  }
  unsigned char* ws = (unsigned char*)d_ws;
  float* out = (float*)d_out;

  k_obs  <<<512,  64, 0, stream>>>(a, out);
  if (ws_size < WS_NEED) return;

  k_sz   <<<2048, 256, 0, stream>>>((uint4*)(ws+SAV_OFF));
  k_xt   <<<512, 256, 0, stream>>>(a, (bf16*)(ws+XT_OFF));
  k_wt   <<<336, 128, 0, stream>>>(gru_U, bgru_U, gru_W, bgru_W,
                                   (bf16*)(ws+UF_OFF), (bf16*)(ws+UB_OFF),
                                   (bf16*)(ws+WF_OFF), (bf16*)(ws+WB_OFF));
  k_decw <<<256, 256, 0, stream>>>(dec_W, (bf16*)(ws+DW_OFF));
  k_mw   <<<256,  64, 0, stream>>>(mean_W, (bf16*)(ws+MW_OFF));
  k_consts<<<1,  256, 0, stream>>>(gru_b, bgru_b, mean_b, dec_b, (float*)(ws+CST_OFF));
  k_fused<<<1344, 64, 0, stream>>>(mean_W, mean_b, gru_W, bgru_W,
                                   (bf16*)(ws+FUF_OFF), (bf16*)(ws+FUB_OFF));
  naomi_main<<<32, 256, 0, stream>>>(ws, out);
}

// Round 2
// 4724.371 us; speedup vs baseline: 1.0070x; 1.0070x over previous
//
#include <hip/hip_runtime.h>
#include <hip/hip_bf16.h>
#include <cstdint>
#include <cstddef>

using bf16 = __hip_bfloat16;
typedef __attribute__((ext_vector_type(8))) short   bf16x8_t;  // 8 bf16 (4 VGPRs)
typedef __attribute__((ext_vector_type(4))) float   f32x4_t;   // mfma accumulator

// ---------------- workspace byte offsets (total 34,069,760 B) ----------------
#define XT_OFF   ((size_t)0)            // [32 wg][256 t][16 r][96] bf16 (coalesced per-wave X)
#define UF_OFF   ((size_t)25165824)     // [336][128] bf16 gate-ordered U strips (fwd)
#define UB_OFF   ((size_t)25251840)     // (bwd)
#define WF_OFF   ((size_t)25337856)     // fwd W shifted: row k -> gru_W[k-1], k=1..64 (K=128 strip)
#define WB_OFF   ((size_t)25423872)     // bwd W: row k -> bgru_W[k], k=0..64
#define DW_OFF   ((size_t)25509888)     // dec_W strips [4][64][256] bf16
#define MW_OFF   ((size_t)25640960)     // mean_W^T strips [4][64][64] bf16
#define SAV_OFF  ((size_t)25673728)     // saved h_back [32 wg][64 slot][16*128] bf16 (8,388,608 B)
#define CST_OFF  ((size_t)34062336)     // fp32: bf0,bf1,bb0,bb1[336 ea], mb[256], db[256]
#define WS_NEED  ((size_t)34069760)

#define MFMA16(a,b,c) __builtin_amdgcn_mfma_f32_16x16x32_bf16((a),(b),(c),0,0,0)

// ---------------- static schedule (mask t%16==0, batch-shared) ----------------
struct Op { uint8_t type, t; int8_t lvl, save, hsrc, srcidx, gisrc, aux; };
// type: 0=BCELL(bwd,X=xT) 1=FA(fwd,X=xT) 2=FF(fwd,X=ring[t&7]) 3=DEC 4=CH(bwd,X=ring[op.t] if gisrc)
// hsrc: 0=CUR 1=SAV 2=SPL(LDS) ; aux: CH spill slot (-1 none) ; CH: op.t = ring slot
struct Sched { Op ops[960]; short n; };

constexpr int slot_of(int tp){ int k=(tp-1)/16; int m=tp%16;
  int pos = (m==9)?0:((m==13)?1:((m==15)?2:3)); return 4*k+pos; }

constexpr Sched build_sched(){
  Sched s{}; int i=0;
  for (int t=255; t>=1; --t){
    int tp=t+1, m=tp%16; int8_t sv=-1;
    if (m==9||m==13||m==15||m==0) sv=(int8_t)slot_of(tp);
    s.ops[i++] = Op{(uint8_t)0,(uint8_t)t,(int8_t)0,sv,(int8_t)0,(int8_t)0,(int8_t)0,(int8_t)0};
  }
  s.ops[i++] = Op{(uint8_t)1,(uint8_t)0,(int8_t)0,(int8_t)-1,(int8_t)0,(int8_t)0,(int8_t)0,(int8_t)0}; // FA(0)
  for (int blk=0; blk<16; ++blk){
    int ba=16*blk; bool last=(blk==15);
    int s16=slot_of(ba+16), s9=slot_of(ba+9), s13=slot_of(ba+13), s15=slot_of(ba+15);
#define PD(dt,lv,hs,si)   s.ops[i++]=Op{(uint8_t)3,(uint8_t)(ba+(dt)),(int8_t)(lv),(int8_t)-1,(int8_t)(hs),(int8_t)(si),(int8_t)0,(int8_t)0};
#define PC(hs,si,gs,sp,sl) s.ops[i++]=Op{(uint8_t)4,(uint8_t)(sl),(int8_t)0,(int8_t)-1,(int8_t)(hs),(int8_t)(si),(int8_t)(gs),(int8_t)(sp)};
#define PF(ft)            s.ops[i++]=Op{(uint8_t)2,(uint8_t)(ba+(ft)),(int8_t)0,(int8_t)-1,(int8_t)0,(int8_t)0,(int8_t)0,(int8_t)0};
#define PA(ft)            s.ops[i++]=Op{(uint8_t)1,(uint8_t)(ba+(ft)),(int8_t)0,(int8_t)-1,(int8_t)0,(int8_t)0,(int8_t)0,(int8_t)0};
    PD(8,3,1,s16)
    PC(1,s9,1,0,0)  PC(0,0,0,1,0) PC(0,0,0,-1,0) PC(0,0,0,-1,0)  // d8(sp0) d7(sp1) d6 d5
    PD(4,2,2,0)
    PC(0,0,1,2,4) PC(0,0,0,-1,0)                                  // d4(sp2) d3
    PD(2,1,2,2)
    PC(0,0,1,-1,2)                                                // d2
    PD(1,0,0,0)
    PF(1) PF(2)
    PD(3,0,2,2)
    PF(3) PF(4)
    PD(6,1,2,0)
    PC(2,1,1,-1,6)                                                // d6' = gru(ns6, d7=sp1)
    PD(5,0,0,0)
    PF(5) PF(6)
    PD(7,0,2,0)
    PF(7) PF(8)
    PD(12,2,1,s16)
    PC(1,s13,1,3,4) PC(0,0,0,-1,0)                                // d12(sp3) d11
    PD(10,1,2,3)
    PC(0,0,1,-1,2)                                                // d10
    PD(9,0,0,0)
    PF(9) PF(10)
    PD(11,0,2,3)
    PF(11) PF(12)
    PD(14,1,1,s16)
    PC(1,s15,1,-1,6)                                              // d14
    PD(13,0,0,0)
    PF(13) PF(14)
    PD(15,0,1,s16)
    if(!last){ PF(15); PA(16); }
#undef PD
#undef PC
#undef PF
#undef PA
  }
  s.n=(short)i; return s;
}
__constant__ Sched g_sched = build_sched();

// ---------------- prep kernels (fp32 inputs -> bf16 internal) ----------------
__global__ void k_xt(const float* __restrict__ a, bf16* __restrict__ xT){
  int b=blockIdx.x, t=threadIdx.x;
  int wgi=b>>4, r=b&15;
  bf16* dst = xT + (((size_t)wgi*256 + t)*16 + r)*96;
  const float* ap = a + (size_t)b*64*256*3;
  for (int c=0;c<64;++c) dst[c] = __float2bfloat16(ap[((size_t)c*256+t)*3]);
  dst[64] = __float2bfloat16(ap[(size_t)t*3 + 2]);
  bf16 z = __float2bfloat16(0.f);
  for (int c=65;c<96;++c) dst[c]=z;
}

__global__ void k_obs(const float* __restrict__ a, float* __restrict__ out){
  int b=blockIdx.x, d=threadIdx.x; // 64 threads
  for (int kk=0;kk<16;++kk){ int t=kk*16;
    float v = (d<63)? a[(((size_t)b*64 + d+1)*256 + t)*3]
                    : a[((size_t)b*64*256 + t)*3 + 2];
    out[((size_t)b*64 + d)*256 + t] = v;
  }
}

__global__ void k_wt(const float* __restrict__ gru_U, const float* __restrict__ bgru_U,
                     const float* __restrict__ gru_W, const float* __restrict__ bgru_W,
                     bf16* Uf, bf16* Ub, bf16* Wf, bf16* Wb){
  int c=blockIdx.x, k=threadIdx.x; // 336 x 128
  int g=c/48, rm=c%48, e=rm/16, l=rm%16, j=16*g+l;
  bool val = j<100; int gc = val? (e*100+j) : 0;
  bf16 z = __float2bfloat16(0.f);
  Uf[(size_t)c*128+k] = (val&&k<100)? __float2bfloat16(gru_U[k*300+gc]) : z;
  Ub[(size_t)c*128+k] = (val&&k<100)? __float2bfloat16(bgru_U[k*300+gc]) : z;
  Wf[(size_t)c*128+k] = (val&&k>=1&&k<=64)? __float2bfloat16(gru_W[(k-1)*300+gc]) : z;
  Wb[(size_t)c*128+k] = (val&&k<65)? __float2bfloat16(bgru_W[k*300+gc]) : z;
}

__global__ void k_decw(const float* __restrict__ dec_W, bf16* dWt){
  int idx=blockIdx.x; int lvl=idx/64, n=idx%64; int k=threadIdx.x; // 256 blocks x 256 thr
  float v=0.f;
  if (n<50){
    if (k<100) v = dec_W[(lvl*200+k)*50+n];            // h rows 0..99
    else if (k>=128 && k<228) v = dec_W[(lvl*200+k-28)*50+n]; // hb rows 100..199
  }
  dWt[(size_t)idx*256+k] = __float2bfloat16(v);
}

__global__ void k_mw(const float* __restrict__ mean_W, bf16* MW){
  int idx=blockIdx.x; int lvl=idx/64, c=idx%64; int k=threadIdx.x; // 64
  MW[(size_t)idx*64+k] = (k<50)? __float2bfloat16(mean_W[(lvl*50+k)*64+c]) : __float2bfloat16(0.f);
}

__global__ void k_consts(const float* __restrict__ gru_b, const float* __restrict__ bgru_b,
                         const float* __restrict__ mean_b, const float* __restrict__ dec_b,
                         float* cst){
  int tid=threadIdx.x;
  for (int u=tid; u<336; u+=256){
    int c=u; int g=c/48, rm=c%48, e=rm/16, l=rm%16, j=16*g+l;
    float b0f=0,b1f=0,b0b=0,b1b=0;
    if (j<100){ int gc=e*100+j;
      b0f=gru_b[gc];  b1f=gru_b[300+gc];
      b0b=bgru_b[gc]; b1b=bgru_b[300+gc]; }
    cst[u]=b0f; cst[336+u]=b1f; cst[672+u]=b0b; cst[1008+u]=b1b;
  }
  if (tid<256){
    int lvl=tid/64, m=tid%64;
    cst[1344+tid]=mean_b[lvl*64+m];
    cst[1600+tid]=(m<50)? dec_b[lvl*50+m] : 0.f;
  }
}

__global__ void k_sz(uint4* p){
  p[(size_t)blockIdx.x*256 + threadIdx.x] = make_uint4(0u,0u,0u,0u);
}

// ---------------- main persistent kernel: 32 WGs x 512 thr (8 waves), 16 batch rows each ----
// Wave wv (0..6) owns gate-column strip j = 16*wv + l15 (j<100); wave 7 idles in cell work.
// 2 waves/SIMD so latency stalls of one wave overlap the other's issue.
__launch_bounds__(512, 2)
__global__ void naomi_main(unsigned char* __restrict__ ws, float* __restrict__ out){
  const int tid=threadIdx.x, wg=blockIdx.x;
  const int lane=tid&63, wv=tid>>6;     // 0..7
  const int l15=lane&15, q=lane>>4;
  const bool act = (wv<7);
  const int j = 16*wv + l15;            // owned gate column (valid if act && j<100)

  const bf16* xT = (const bf16*)(ws + XT_OFF);
  const bf16* Uf = (const bf16*)(ws + UF_OFF);
  const bf16* Ub = (const bf16*)(ws + UB_OFF);
  const bf16* Wf = (const bf16*)(ws + WF_OFF);
  const bf16* Wb = (const bf16*)(ws + WB_OFF);
  const bf16* dW = (const bf16*)(ws + DW_OFF);
  const bf16* MW = (const bf16*)(ws + MW_OFF);
  bf16* sav = (bf16*)(ws + SAV_OFF);
  unsigned char* sav8 = (unsigned char*)(ws + SAV_OFF);
  const float* cst = (const float*)(ws + CST_OFF);

  // LDS (63,024 B): s_h 2x[16][104] | s_hbk 2x[16][104] | s_dec [16][72]+pad | ring [8][16][120] | spl [4][16][128]
  __shared__ alignas(16) unsigned char smem[63024];
  bf16* s_h    = (bf16*)(smem + 0);      // 6784 B (two 1696-elem buffers)
  bf16* s_hbk  = (bf16*)(smem + 6784);   // 6784 B
  bf16* s_dec  = (bf16*)(smem + 13568);  // 2352 B
  bf16* s_ring = (bf16*)(smem + 15920);  // 30720 B
  bf16* s_spl  = (bf16*)(smem + 46640);  // 16384 B

  for (int u=tid; u<15756; u+=512) ((uint32_t*)smem)[u]=0u;

  // per-thread gate biases [dir: 0=bwd 1=fwd]
  float Bz0[2],Br0[2],Bn0[2],Bz1[2],Br1[2],Bn1[2];
  if (act){
    int cz=48*wv+l15;
    Bz0[1]=cst[cz];      Br0[1]=cst[cz+16];      Bn0[1]=cst[cz+32];
    Bz1[1]=cst[336+cz];  Br1[1]=cst[336+cz+16];  Bn1[1]=cst[336+cz+32];
    Bz0[0]=cst[672+cz];  Br0[0]=cst[672+cz+16];  Bn0[0]=cst[672+cz+32];
    Bz1[0]=cst[1008+cz]; Br1[0]=cst[1008+cz+16]; Bn1[0]=cst[1008+cz+32];
  } else {
    Bz0[0]=Bz0[1]=Br0[0]=Br0[1]=Bn0[0]=Bn0[1]=0.f;
    Bz1[0]=Bz1[1]=Br1[0]=Br1[1]=Bn1[0]=Bn1[1]=0.f;
  }
  const int c16 = 16*wv+l15;            // DEC output column (valid for wv<4)
  float mb_l[4], db_l[4];
  if (wv<4){
    #pragma unroll
    for (int l=0;l<4;++l){ mb_l[l]=cst[1344+l*64+c16]; db_l[l]=cst[1600+l*64+c16]; }
  } else {
    #pragma unroll
    for (int l=0;l<4;++l){ mb_l[l]=0.f; db_l[l]=0.f; }
  }

  // U strips resident in registers (one strip per wave)
  bf16x8_t rUf[3][4], rUb[3][4];
  if (act){
    #pragma unroll
    for (int e=0;e<3;++e){ int c=48*wv+16*e+l15;
      #pragma unroll
      for (int s=0;s<4;++s){
        rUf[e][s] = *(const bf16x8_t*)(Uf + (size_t)c*128 + 8*q + 32*s);
        rUb[e][s] = *(const bf16x8_t*)(Ub + (size_t)c*128 + 8*q + 32*s);
      } }
  }
  __syncthreads();

  // fp32 master state in registers: thread owns (r=4q+i, col j)
  float h_reg[4], hb_reg[4];
  #pragma unroll
  for (int i=0;i<4;++i){ h_reg[i]=0.f; hb_reg[i]=0.f; }
  int hcur=0, bcur=0;

  // prefetch registers
  bf16x8_t pX[3], pHB[4];
  float pHold[4];
  #pragma unroll
  for (int i=0;i<4;++i) pHold[i]=0.f;
  if (act){ // prologue: prefetch X for op[0] (BCELL t=255)
    const Op on = g_sched.ops[0];
    const bf16* px = xT + (((size_t)wg*256 + on.t)*16 + l15)*96 + 8*q;
    #pragma unroll
    for (int s=0;s<3;++s) pX[s] = *(const bf16x8_t*)(px + 32*s);
  }

  const int nops = g_sched.n;
  for (int io=0; io<nops; ++io){
    const Op op = g_sched.ops[io];
    const Op on = g_sched.ops[(io+1<nops)? io+1 : io];
    if (op.type != 3){
      const bool fwd = (op.type==1)||(op.type==2);
      const bool hasX = (op.type<=2)||(op.type==4 && op.gisrc==1);
      // ---- A fragments (h operand) ----
      bf16x8_t aH[4];
      if (act){
        if (!fwd && op.hsrc==1){
          #pragma unroll
          for (int s=0;s<4;++s) aH[s]=pHB[s];
        } else if (!fwd && op.hsrc==2){
          const bf16* hp = s_spl + (size_t)op.srcidx*2048 + l15*128 + 8*q;
          #pragma unroll
          for (int s=0;s<4;++s) aH[s] = *(const bf16x8_t*)(hp + 32*s);
        } else {
          const bf16* hp = (fwd? s_h + hcur*1696 : s_hbk + bcur*1696) + l15*104 + 8*q;
          #pragma unroll
          for (int s=0;s<4;++s) aH[s] = *(const bf16x8_t*)(hp + 32*s);
        }
      }
      // ---- X fragments ----
      bf16x8_t aX[3];
      if (act){
        if (op.type==0 || op.type==1){
          #pragma unroll
          for (int s=0;s<3;++s) aX[s]=pX[s];
        } else if (op.type==2){
          const bf16* xp = s_ring + (size_t)((op.t&7)*16 + l15)*120 + 8*q;
          #pragma unroll
          for (int s=0;s<3;++s) aX[s] = *(const bf16x8_t*)(xp + 32*s);
        } else if (op.type==4 && op.gisrc==1){
          const bf16* xp = s_ring + (size_t)(op.t*16 + l15)*120 + 8*q;
          #pragma unroll
          for (int s=0;s<3;++s) aX[s] = *(const bf16x8_t*)(xp + 32*s);
        }
      }
      // ---- MFMA: U from registers (no memory), then W from global ----
      f32x4_t accB[3], accA[3];
      #pragma unroll
      for (int e=0;e<3;++e){ accB[e]=(f32x4_t){0,0,0,0}; accA[e]=(f32x4_t){0,0,0,0}; }
      if (act){
        if (fwd){
          #pragma unroll
          for (int e=0;e<3;++e){
            #pragma unroll
            for (int s=0;s<4;++s) accB[e] = MFMA16(aH[s], rUf[e][s], accB[e]);
          }
        } else {
          #pragma unroll
          for (int e=0;e<3;++e){
            #pragma unroll
            for (int s=0;s<4;++s) accB[e] = MFMA16(aH[s], rUb[e][s], accB[e]);
          }
        }
        if (hasX){
          const bf16* Wp = fwd? Wf : Wb;
          #pragma unroll
          for (int e=0;e<3;++e){ int c=48*wv+16*e+l15;
            const bf16* bp = Wp + (size_t)c*128 + 8*q;
            #pragma unroll
            for (int s=0;s<3;++s)
              accA[e] = MFMA16(aX[s], *(const bf16x8_t*)(bp+32*s), accA[e]);
          }
        }
      }
      // ---- prefetch for op[io+1] ----
      if (act){
        if (on.type==0 || on.type==1){
          const bf16* px = xT + (((size_t)wg*256 + on.t)*16 + l15)*96 + 8*q;
          #pragma unroll
          for (int s=0;s<3;++s) pX[s] = *(const bf16x8_t*)(px + 32*s);
        }
        if ((on.type==3 || on.type==4) && on.hsrc==1){
          const bf16* ps = sav + (size_t)(wg*64+on.srcidx)*2048 + l15*128 + 8*q;
          #pragma unroll
          for (int s=0;s<4;++s) pHB[s] = *(const bf16x8_t*)(ps + 32*s);
        }
        if (on.type==4 && on.hsrc==1 && j<100){
          const bf16* ph = sav + (size_t)(wg*64+on.srcidx)*2048;
          #pragma unroll
          for (int i=0;i<4;++i) pHold[i] = __bfloat162float(ph[(4*q+i)*128 + j]);
        }
      }
      // ---- BCELL: coalesced save of pre-update h_back (current s_hbk buffer) ----
      if (op.type==0 && op.save>=0 && tid<208){
        int r=tid/13, c=tid-13*r;
        const uint4 v = *(const uint4*)(smem + 6784 + bcur*3392 + r*208 + c*16);
        *(uint4*)(sav8 + ((size_t)(wg*64+op.save))*4096 + (size_t)r*256 + c*16) = v;
      }
      // ---- gate stage (lane-local) ----
      bf16* wr = fwd? (s_h + (hcur^1)*1696) : (s_hbk + (bcur^1)*1696);
      const int fi = fwd?1:0;
      if (act && j<100){
        float b0z=Bz0[fi], b0r=Br0[fi], b0n=Bn0[fi];
        float b1z=Bz1[fi], b1r=Br1[fi], b1n=Bn1[fi];
        #pragma unroll
        for (int i=0;i<4;++i){
          int r=4*q+i;
          float gz=0.f, gr=0.f, gn=0.f;
          if (hasX){ gz=accA[0][i]; gr=accA[1][i]; gn=accA[2][i]; }
          float hz=accB[0][i], hr=accB[1][i], hnv=accB[2][i];
          float hold;
          if (fwd) hold = h_reg[i];
          else if (op.hsrc==0) hold = hb_reg[i];
          else if (op.hsrc==1) hold = pHold[i];
          else hold = __bfloat162float(s_spl[(size_t)op.srcidx*2048 + r*128 + j]);
          float az = gz+b0z+hz+b1z; az=fminf(fmaxf(az,-30.f),30.f);
          float ar = gr+b0r+hr+b1r; ar=fminf(fmaxf(ar,-30.f),30.f);
          float z  = 1.f/(1.f+__expf(-az));
          float rg = 1.f/(1.f+__expf(-ar));
          float an = gn+b0n+rg*(hnv+b1n); an=fminf(fmaxf(an,-15.f),15.f);
          float e2 = __expf(2.f*an);
          float nn = (e2-1.f)/(e2+1.f);
          float hnew = z*hold + (1.f-z)*nn;
          if (fwd) h_reg[i]=hnew; else hb_reg[i]=hnew;
          wr[r*104+j] = __float2bfloat16(hnew);
          if (!fwd && op.type==4 && op.aux>=0)
            s_spl[(size_t)op.aux*2048 + r*128 + j] = __float2bfloat16(hnew);
        }
      }
      if (fwd) hcur^=1; else bcur^=1;
      __syncthreads();
    } else {
      // ---- DEC: dec = relu([h,hb]@decW+db); mean = dec@meanW+mb -> out + ns ring ----
      // Only waves 0..3 compute (64 output cols); waves 4..7 just prefetch + barrier.
      const int lvl=op.lvl, t=op.t, slot=t&7;
      if (wv<4){
        bf16x8_t aG[8];
        { const bf16* hp = s_h + hcur*1696 + l15*104 + 8*q;
          #pragma unroll
          for (int s=0;s<4;++s) aG[s] = *(const bf16x8_t*)(hp + 32*s); }
        if (op.hsrc==1){
          #pragma unroll
          for (int s=0;s<4;++s) aG[4+s]=pHB[s];
        } else if (op.hsrc==2){
          const bf16* hp = s_spl + (size_t)op.srcidx*2048 + l15*128 + 8*q;
          #pragma unroll
          for (int s=0;s<4;++s) aG[4+s] = *(const bf16x8_t*)(hp + 32*s);
        } else {
          const bf16* hp = s_hbk + bcur*1696 + l15*104 + 8*q;
          #pragma unroll
          for (int s=0;s<4;++s) aG[4+s] = *(const bf16x8_t*)(hp + 32*s);
        }
        // gemm1: [16,256] x [256 -> 64 cols]; wave wv owns cols 16wv..16wv+15
        const bf16* bp = dW + ((size_t)(lvl*64 + c16))*256 + 8*q;
        f32x4_t a1=(f32x4_t){0,0,0,0}, a2=(f32x4_t){0,0,0,0};
        #pragma unroll
        for (int s=0;s<8;s+=2){
          a1 = MFMA16(aG[s],   *(const bf16x8_t*)(bp+32*s),     a1);
          a2 = MFMA16(aG[s+1], *(const bf16x8_t*)(bp+32*(s+1)), a2);
        }
        float db = db_l[lvl];
        #pragma unroll
        for (int i=0;i<4;++i){ float v=fmaxf(a1[i]+a2[i]+db,0.f); s_dec[(4*q+i)*72 + c16]=__float2bfloat16(v); }
      }
      // ---- prefetch for op[io+1] (all active waves) ----
      if (act){
        if (on.type==0 || on.type==1){
          const bf16* px = xT + (((size_t)wg*256 + on.t)*16 + l15)*96 + 8*q;
          #pragma unroll
          for (int s=0;s<3;++s) pX[s] = *(const bf16x8_t*)(px + 32*s);
        }
        if ((on.type==3 || on.type==4) && on.hsrc==1){
          const bf16* ps = sav + (size_t)(wg*64+on.srcidx)*2048 + l15*128 + 8*q;
          #pragma unroll
          for (int s=0;s<4;++s) pHB[s] = *(const bf16x8_t*)(ps + 32*s);
        }
        if (on.type==4 && on.hsrc==1 && j<100){
          const bf16* ph = sav + (size_t)(wg*64+on.srcidx)*2048;
          #pragma unroll
          for (int i=0;i<4;++i) pHold[i] = __bfloat162float(ph[(4*q+i)*128 + j]);
        }
      }
      __syncthreads();
      // gemm2: A=dec [16,64], B=mean_W^T strip -> out + ring ns
      if (wv<4){
        bf16x8_t aD[2];
        #pragma unroll
        for (int s=0;s<2;++s) aD[s] = *(const bf16x8_t*)(s_dec + l15*72 + 8*q + 32*s);
        const bf16* bp = MW + ((size_t)(lvl*64 + c16))*64 + 8*q;
        f32x4_t am=(f32x4_t){0,0,0,0};
        am = MFMA16(aD[0], *(const bf16x8_t*)(bp),    am);
        am = MFMA16(aD[1], *(const bf16x8_t*)(bp+32), am);
        float mb = mb_l[lvl];
        #pragma unroll
        for (int i=0;i<4;++i){ int r=4*q+i; size_t b=(size_t)wg*16+r;
          float m = am[i]+mb;
          s_ring[(size_t)(slot*16 + r)*120 + c16] = __float2bfloat16(m);
          if (c16>=1) out[(b*64 + (c16-1))*256 + t] = m;
          else        out[(b*64 + 63)*256 + t]      = 1.0f;
        }
      }
      if (wv==0 && l15==0){ bf16 one=__float2bfloat16(1.0f);
        #pragma unroll
        for (int i=0;i<4;++i) s_ring[(size_t)(slot*16 + 4*q+i)*120 + 64] = one; }
      __syncthreads();
    }
  }
}

// ---------------- launch ----------------
extern "C" void kernel_launch(void* const* d_in, const int* in_sizes, int n_in,
                              void* d_out, int out_size, void* d_ws, size_t ws_size,
                              hipStream_t stream){
  (void)out_size;
  const float *a=nullptr,*gru_W=nullptr,*gru_U=nullptr,*gru_b=nullptr,*bgru_W=nullptr,
              *bgru_U=nullptr,*bgru_b=nullptr,*dec_W=nullptr,*dec_b=nullptr,
              *mean_W=nullptr,*mean_b=nullptr;
  int nU=0, nb6=0;
  for (int i=0;i<n_in;++i){
    const float* p=(const float*)d_in[i]; int s=in_sizes[i];
    if      (s==25165824) a=p;
    else if (s==19200)    gru_W=p;
    else if (s==19500)    bgru_W=p;
    else if (s==30000)    { if(nU++==0) gru_U=p; else bgru_U=p; }
    else if (s==600)      { if(nb6++==0) gru_b=p; else bgru_b=p; }
    else if (s==40000)    dec_W=p;
    else if (s==200)      dec_b=p;
    else if (s==12800)    mean_W=p;
    else if (s==256)      mean_b=p;
  }
  if (!a||!gru_W||!gru_U||!gru_b||!bgru_W||!bgru_U||!bgru_b||!dec_W||!dec_b||!mean_W||!mean_b){
    a=(const float*)d_in[0]; gru_W=(const float*)d_in[1]; gru_U=(const float*)d_in[2];
    gru_b=(const float*)d_in[3]; bgru_W=(const float*)d_in[4]; bgru_U=(const float*)d_in[5];
    bgru_b=(const float*)d_in[6]; dec_W=(const float*)d_in[7]; dec_b=(const float*)d_in[8];
    mean_W=(const float*)d_in[9]; mean_b=(const float*)d_in[10];
  }
  unsigned char* ws = (unsigned char*)d_ws;
  float* out = (float*)d_out;

  k_obs  <<<512,  64, 0, stream>>>(a, out);
  if (ws_size < WS_NEED) return;

  k_sz   <<<2048, 256, 0, stream>>>((uint4*)(ws+SAV_OFF));
  k_xt   <<<512, 256, 0, stream>>>(a, (bf16*)(ws+XT_OFF));
  k_wt   <<<336, 128, 0, stream>>>(gru_U, bgru_U, gru_W, bgru_W,
                                   (bf16*)(ws+UF_OFF), (bf16*)(ws+UB_OFF),
                                   (bf16*)(ws+WF_OFF), (bf16*)(ws+WB_OFF));
  k_decw <<<256, 256, 0, stream>>>(dec_W, (bf16*)(ws+DW_OFF));
  k_mw   <<<256,  64, 0, stream>>>(mean_W, (bf16*)(ws+MW_OFF));
  k_consts<<<1,  256, 0, stream>>>(gru_b, bgru_b, mean_b, dec_b, (float*)(ws+CST_OFF));
  naomi_main<<<32, 512, 0, stream>>>(ws, out);
}

// Round 4
// 4082.739 us; speedup vs baseline: 1.1653x; 1.1572x over previous
//
#include <hip/hip_runtime.h>
#include <hip/hip_bf16.h>
#include <cstdint>
#include <cstddef>

using bf16 = __hip_bfloat16;
typedef __attribute__((ext_vector_type(8))) short   bf16x8_t;  // 8 bf16 (4 VGPRs)
typedef __attribute__((ext_vector_type(4))) float   f32x4_t;   // mfma accumulator

// ---------------- workspace byte offsets (total 34,069,760 B) ----------------
#define XT_OFF   ((size_t)0)            // [32 wg][256 t][16 r][96] bf16 (coalesced per-wave X)
#define UF_OFF   ((size_t)25165824)     // [336][128] bf16 gate-ordered U strips (fwd)
#define UB_OFF   ((size_t)25251840)     // (bwd)
#define WF_OFF   ((size_t)25337856)     // fwd W shifted: row k -> gru_W[k-1], k=1..64 (K=128 strip)
#define WB_OFF   ((size_t)25423872)     // bwd W: row k -> bgru_W[k], k=0..64
#define DW_OFF   ((size_t)25509888)     // dec_W strips [4][64][256] bf16
#define MW_OFF   ((size_t)25640960)     // mean_W^T strips [4][64][64] bf16
#define SAV_OFF  ((size_t)25673728)     // saved h_back [32 wg][64 slot][16*128] bf16 (8,388,608 B)
#define CST_OFF  ((size_t)34062336)     // fp32: bf0,bf1,bb0,bb1[336 ea], mb[256], db[256]
#define WS_NEED  ((size_t)34069760)

#define MFMA16(a,b,c) __builtin_amdgcn_mfma_f32_16x16x32_bf16((a),(b),(c),0,0,0)

// counted barrier: drain LDS only; global loads/stores stay in flight across it.
// All cross-wave traffic inside an op is LDS (s_h/s_hbk/s_dec/s_ring/s_spl), so
// lgkmcnt(0)+s_barrier preserves ordering. Per-wave global loads (pX/pHB/W frags)
// are self-consumed: compiler inserts its own vmcnt waits before use.
#define BAR()    asm volatile("s_waitcnt lgkmcnt(0)\n\ts_barrier" ::: "memory")
// full vmem drain + barrier: the single bwd->fwd transition where sav STORES
// (issued by bwd ops) must be visible to fwd-phase sav READS (same CU/XCD L2).
#define DRAINB() asm volatile("s_waitcnt vmcnt(0)\n\ts_barrier" ::: "memory")

// ---------------- static schedule (mask t%16==0, batch-shared) ----------------
struct Op { uint8_t type, t; int8_t lvl, save, hsrc, srcidx, gisrc, aux; };
// type: 0=BCELL(bwd,X=xT) 1=FA(fwd,X=xT) 2=FF(fwd,X=ring[t&7]) 3=DEC 4=CH(bwd,X=ring[op.t] if gisrc)
// hsrc: 0=CUR 1=SAV 2=SPL(LDS) ; aux: CH spill slot (-1 none) ; CH: op.t = ring slot
struct Sched { Op ops[960]; short n; };

constexpr int slot_of(int tp){ int k=(tp-1)/16; int m=tp%16;
  int pos = (m==9)?0:((m==13)?1:((m==15)?2:3)); return 4*k+pos; }

constexpr Sched build_sched(){
  Sched s{}; int i=0;
  for (int t=255; t>=1; --t){
    int tp=t+1, m=tp%16; int8_t sv=-1;
    if (m==9||m==13||m==15||m==0) sv=(int8_t)slot_of(tp);
    s.ops[i++] = Op{(uint8_t)0,(uint8_t)t,(int8_t)0,sv,(int8_t)0,(int8_t)0,(int8_t)0,(int8_t)0};
  }
  s.ops[i++] = Op{(uint8_t)1,(uint8_t)0,(int8_t)0,(int8_t)-1,(int8_t)0,(int8_t)0,(int8_t)0,(int8_t)0}; // FA(0)
  for (int blk=0; blk<16; ++blk){
    int ba=16*blk; bool last=(blk==15);
    int s16=slot_of(ba+16), s9=slot_of(ba+9), s13=slot_of(ba+13), s15=slot_of(ba+15);
#define PD(dt,lv,hs,si)   s.ops[i++]=Op{(uint8_t)3,(uint8_t)(ba+(dt)),(int8_t)(lv),(int8_t)-1,(int8_t)(hs),(int8_t)(si),(int8_t)0,(int8_t)0};
#define PC(hs,si,gs,sp,sl) s.ops[i++]=Op{(uint8_t)4,(uint8_t)(sl),(int8_t)0,(int8_t)-1,(int8_t)(hs),(int8_t)(si),(int8_t)(gs),(int8_t)(sp)};
#define PF(ft)            s.ops[i++]=Op{(uint8_t)2,(uint8_t)(ba+(ft)),(int8_t)0,(int8_t)-1,(int8_t)0,(int8_t)0,(int8_t)0,(int8_t)0};
#define PA(ft)            s.ops[i++]=Op{(uint8_t)1,(uint8_t)(ba+(ft)),(int8_t)0,(int8_t)-1,(int8_t)0,(int8_t)0,(int8_t)0,(int8_t)0};
    PD(8,3,1,s16)
    PC(1,s9,1,0,0)  PC(0,0,0,1,0) PC(0,0,0,-1,0) PC(0,0,0,-1,0)  // d8(sp0) d7(sp1) d6 d5
    PD(4,2,2,0)
    PC(0,0,1,2,4) PC(0,0,0,-1,0)                                  // d4(sp2) d3
    PD(2,1,2,2)
    PC(0,0,1,-1,2)                                                // d2
    PD(1,0,0,0)
    PF(1) PF(2)
    PD(3,0,2,2)
    PF(3) PF(4)
    PD(6,1,2,0)
    PC(2,1,1,-1,6)                                                // d6' = gru(ns6, d7=sp1)
    PD(5,0,0,0)
    PF(5) PF(6)
    PD(7,0,2,0)
    PF(7) PF(8)
    PD(12,2,1,s16)
    PC(1,s13,1,3,4) PC(0,0,0,-1,0)                                // d12(sp3) d11
    PD(10,1,2,3)
    PC(0,0,1,-1,2)                                                // d10
    PD(9,0,0,0)
    PF(9) PF(10)
    PD(11,0,2,3)
    PF(11) PF(12)
    PD(14,1,1,s16)
    PC(1,s15,1,-1,6)                                              // d14
    PD(13,0,0,0)
    PF(13) PF(14)
    PD(15,0,1,s16)
    if(!last){ PF(15); PA(16); }
#undef PD
#undef PC
#undef PF
#undef PA
  }
  s.n=(short)i; return s;
}
__constant__ Sched g_sched = build_sched();

// ---------------- prep kernels (fp32 inputs -> bf16 internal) ----------------
__global__ void k_xt(const float* __restrict__ a, bf16* __restrict__ xT){
  int b=blockIdx.x, t=threadIdx.x;
  int wgi=b>>4, r=b&15;
  bf16* dst = xT + (((size_t)wgi*256 + t)*16 + r)*96;
  const float* ap = a + (size_t)b*64*256*3;
  for (int c=0;c<64;++c) dst[c] = __float2bfloat16(ap[((size_t)c*256+t)*3]);
  dst[64] = __float2bfloat16(ap[(size_t)t*3 + 2]);
  bf16 z = __float2bfloat16(0.f);
  for (int c=65;c<96;++c) dst[c]=z;
}

__global__ void k_obs(const float* __restrict__ a, float* __restrict__ out){
  int b=blockIdx.x, d=threadIdx.x; // 64 threads
  for (int kk=0;kk<16;++kk){ int t=kk*16;
    float v = (d<63)? a[(((size_t)b*64 + d+1)*256 + t)*3]
                    : a[((size_t)b*64*256 + t)*3 + 2];
    out[((size_t)b*64 + d)*256 + t] = v;
  }
}

__global__ void k_wt(const float* __restrict__ gru_U, const float* __restrict__ bgru_U,
                     const float* __restrict__ gru_W, const float* __restrict__ bgru_W,
                     bf16* Uf, bf16* Ub, bf16* Wf, bf16* Wb){
  int c=blockIdx.x, k=threadIdx.x; // 336 x 128
  int g=c/48, rm=c%48, e=rm/16, l=rm%16, j=16*g+l;
  bool val = j<100; int gc = val? (e*100+j) : 0;
  bf16 z = __float2bfloat16(0.f);
  Uf[(size_t)c*128+k] = (val&&k<100)? __float2bfloat16(gru_U[k*300+gc]) : z;
  Ub[(size_t)c*128+k] = (val&&k<100)? __float2bfloat16(bgru_U[k*300+gc]) : z;
  Wf[(size_t)c*128+k] = (val&&k>=1&&k<=64)? __float2bfloat16(gru_W[(k-1)*300+gc]) : z;
  Wb[(size_t)c*128+k] = (val&&k<65)? __float2bfloat16(bgru_W[k*300+gc]) : z;
}

__global__ void k_decw(const float* __restrict__ dec_W, bf16* dWt){
  int idx=blockIdx.x; int lvl=idx/64, n=idx%64; int k=threadIdx.x; // 256 blocks x 256 thr
  float v=0.f;
  if (n<50){
    if (k<100) v = dec_W[(lvl*200+k)*50+n];            // h rows 0..99
    else if (k>=128 && k<228) v = dec_W[(lvl*200+k-28)*50+n]; // hb rows 100..199
  }
  dWt[(size_t)idx*256+k] = __float2bfloat16(v);
}

__global__ void k_mw(const float* __restrict__ mean_W, bf16* MW){
  int idx=blockIdx.x; int lvl=idx/64, c=idx%64; int k=threadIdx.x; // 64
  MW[(size_t)idx*64+k] = (k<50)? __float2bfloat16(mean_W[(lvl*50+k)*64+c]) : __float2bfloat16(0.f);
}

__global__ void k_consts(const float* __restrict__ gru_b, const float* __restrict__ bgru_b,
                         const float* __restrict__ mean_b, const float* __restrict__ dec_b,
                         float* cst){
  int tid=threadIdx.x;
  for (int u=tid; u<336; u+=256){
    int c=u; int g=c/48, rm=c%48, e=rm/16, l=rm%16, j=16*g+l;
    float b0f=0,b1f=0,b0b=0,b1b=0;
    if (j<100){ int gc=e*100+j;
      b0f=gru_b[gc];  b1f=gru_b[300+gc];
      b0b=bgru_b[gc]; b1b=bgru_b[300+gc]; }
    cst[u]=b0f; cst[336+u]=b1f; cst[672+u]=b0b; cst[1008+u]=b1b;
  }
  if (tid<256){
    int lvl=tid/64, m=tid%64;
    cst[1344+tid]=mean_b[lvl*64+m];
    cst[1600+tid]=(m<50)? dec_b[lvl*50+m] : 0.f;
  }
}

__global__ void k_sz(uint4* p){
  p[(size_t)blockIdx.x*256 + threadIdx.x] = make_uint4(0u,0u,0u,0u);
}

// ---------------- main persistent kernel: 32 WGs x 256 thr, 16 batch rows each ----------------
__launch_bounds__(256, 1)
__global__ void naomi_main(unsigned char* __restrict__ ws, float* __restrict__ out){
  const int tid=threadIdx.x, wg=blockIdx.x;
  const int lane=tid&63, wv=tid>>6;
  const int l15=lane&15, q=lane>>4;
  const int ng=(wv<3)?2:1;

  const bf16* xT = (const bf16*)(ws + XT_OFF);
  const bf16* Uf = (const bf16*)(ws + UF_OFF);
  const bf16* Ub = (const bf16*)(ws + UB_OFF);
  const bf16* Wf = (const bf16*)(ws + WF_OFF);
  const bf16* Wb = (const bf16*)(ws + WB_OFF);
  const bf16* dW = (const bf16*)(ws + DW_OFF);
  const bf16* MW = (const bf16*)(ws + MW_OFF);
  bf16* sav = (bf16*)(ws + SAV_OFF);
  unsigned char* sav8 = (unsigned char*)(ws + SAV_OFF);
  const float* cst = (const float*)(ws + CST_OFF);

  // LDS (63,024 B): s_h 2x[16][104] | s_hbk 2x[16][104] | s_dec [16][72]+pad | ring [8][16][120] | spl [4][16][128]
  __shared__ alignas(16) unsigned char smem[63024];
  bf16* s_h    = (bf16*)(smem + 0);      // 6784 B (two 1696-elem buffers)
  bf16* s_hbk  = (bf16*)(smem + 6784);   // 6784 B
  bf16* s_dec  = (bf16*)(smem + 13568);  // 2352 B
  bf16* s_ring = (bf16*)(smem + 15920);  // 30720 B
  bf16* s_spl  = (bf16*)(smem + 46640);  // 16384 B

  for (int u=tid; u<15756; u+=256) ((uint32_t*)smem)[u]=0u;

  // per-thread gate biases [g2][dir: 0=bwd 1=fwd]
  float Bz0[2][2],Br0[2][2],Bn0[2][2],Bz1[2][2],Br1[2][2],Bn1[2][2];
  #pragma unroll
  for (int g2=0; g2<2; ++g2){
    if (g2<ng){
      int cz=48*(wv+4*g2)+l15;
      Bz0[g2][1]=cst[cz];      Br0[g2][1]=cst[cz+16];      Bn0[g2][1]=cst[cz+32];
      Bz1[g2][1]=cst[336+cz];  Br1[g2][1]=cst[336+cz+16];  Bn1[g2][1]=cst[336+cz+32];
      Bz0[g2][0]=cst[672+cz];  Br0[g2][0]=cst[672+cz+16];  Bn0[g2][0]=cst[672+cz+32];
      Bz1[g2][0]=cst[1008+cz]; Br1[g2][0]=cst[1008+cz+16]; Bn1[g2][0]=cst[1008+cz+32];
    } else {
      Bz0[g2][0]=Bz0[g2][1]=Br0[g2][0]=Br0[g2][1]=Bn0[g2][0]=Bn0[g2][1]=0.f;
      Bz1[g2][0]=Bz1[g2][1]=Br1[g2][0]=Br1[g2][1]=Bn1[g2][0]=Bn1[g2][1]=0.f;
    }
  }
  const int c16 = 16*wv+l15;
  float mb_l[4], db_l[4];
  #pragma unroll
  for (int l=0;l<4;++l){ mb_l[l]=cst[1344+l*64+c16]; db_l[l]=cst[1600+l*64+c16]; }

  // U strips resident in registers for the whole kernel
  bf16x8_t rUf[2][3][4], rUb[2][3][4];
  #pragma unroll
  for (int g2=0; g2<2; ++g2){
    if (g2<ng){
      #pragma unroll
      for (int e=0;e<3;++e){ int c=48*(wv+4*g2)+16*e+l15;
        #pragma unroll
        for (int s=0;s<4;++s){
          rUf[g2][e][s] = *(const bf16x8_t*)(Uf + (size_t)c*128 + 8*q + 32*s);
          rUb[g2][e][s] = *(const bf16x8_t*)(Ub + (size_t)c*128 + 8*q + 32*s);
        } }
    }
  }
  __syncthreads();

  // fp32 master state in registers: thread owns (r=4q+i, j=16*(wv+4*g2)+l15)
  float h_reg[2][4], hb_reg[2][4];
  #pragma unroll
  for (int g2=0;g2<2;++g2){
    #pragma unroll
    for (int i=0;i<4;++i){ h_reg[g2][i]=0.f; hb_reg[g2][i]=0.f; }
  }
  int hcur=0, bcur=0;

  // prefetch registers
  bf16x8_t pX[3], pHB[4];
  float pHold[2][4];
  #pragma unroll
  for (int g2=0;g2<2;++g2){
    #pragma unroll
    for (int i=0;i<4;++i) pHold[g2][i]=0.f;
  }
  { // prologue: prefetch for op[0] (BCELL t=255 -> X only)
    const Op on = g_sched.ops[0];
    const bf16* px = xT + (((size_t)wg*256 + on.t)*16 + l15)*96 + 8*q;
    #pragma unroll
    for (int s=0;s<3;++s) pX[s] = *(const bf16x8_t*)(px + 32*s);
  }

  const int nops = g_sched.n;
  for (int io=0; io<nops; ++io){
    const Op op = g_sched.ops[io];
    const Op on = g_sched.ops[(io+1<nops)? io+1 : io];
    if (io==255) DRAINB();   // bwd sav-stores -> fwd sav-reads transition
    if (op.type != 3){
      const bool fwd = (op.type==1)||(op.type==2);
      const bool hasX = (op.type==0)||(op.type==1)||(op.type==2)||(op.type==4 && op.gisrc==1);
      // ---- A fragments (h operand) ----
      bf16x8_t aH[4];
      if (!fwd && op.hsrc==1){
        #pragma unroll
        for (int s=0;s<4;++s) aH[s]=pHB[s];
      } else if (!fwd && op.hsrc==2){
        const bf16* hp = s_spl + (size_t)op.srcidx*2048 + l15*128 + 8*q;
        #pragma unroll
        for (int s=0;s<4;++s) aH[s] = *(const bf16x8_t*)(hp + 32*s);
      } else {
        const bf16* hp = (fwd? s_h + hcur*1696 : s_hbk + bcur*1696) + l15*104 + 8*q;
        #pragma unroll
        for (int s=0;s<4;++s) aH[s] = *(const bf16x8_t*)(hp + 32*s);
      }
      // ---- X fragments ----
      bf16x8_t aX[3];
      if (op.type==0 || op.type==1){
        #pragma unroll
        for (int s=0;s<3;++s) aX[s]=pX[s];
      } else if (op.type==2){
        const bf16* xp = s_ring + (size_t)((op.t&7)*16 + l15)*120 + 8*q;
        #pragma unroll
        for (int s=0;s<3;++s) aX[s] = *(const bf16x8_t*)(xp + 32*s);
      } else if (op.type==4 && op.gisrc==1){
        const bf16* xp = s_ring + (size_t)(op.t*16 + l15)*120 + 8*q;
        #pragma unroll
        for (int s=0;s<3;++s) aX[s] = *(const bf16x8_t*)(xp + 32*s);
      }
      // ---- MFMA: U from registers first (no memory), then W from global ----
      f32x4_t accB[2][3], accA[2][3];
      #pragma unroll
      for (int g2=0;g2<2;++g2)
        #pragma unroll
        for (int e=0;e<3;++e){ accB[g2][e]=(f32x4_t){0,0,0,0}; accA[g2][e]=(f32x4_t){0,0,0,0}; }
      if (fwd){
        #pragma unroll
        for (int g2=0;g2<2;++g2){ if (g2<ng){
          #pragma unroll
          for (int e=0;e<3;++e){
            #pragma unroll
            for (int s=0;s<4;++s)
              accB[g2][e] = MFMA16(aH[s], rUf[g2][e][s], accB[g2][e]);
          } } }
      } else {
        #pragma unroll
        for (int g2=0;g2<2;++g2){ if (g2<ng){
          #pragma unroll
          for (int e=0;e<3;++e){
            #pragma unroll
            for (int s=0;s<4;++s)
              accB[g2][e] = MFMA16(aH[s], rUb[g2][e][s], accB[g2][e]);
          } } }
      }
      if (hasX){
        const bf16* Wp = fwd? Wf : Wb;
        #pragma unroll
        for (int g2=0;g2<2;++g2){ if (g2<ng){
          #pragma unroll
          for (int e=0;e<3;++e){ int c=48*(wv+4*g2)+16*e+l15;
            const bf16* bp = Wp + (size_t)c*128 + 8*q;
            #pragma unroll
            for (int s=0;s<3;++s)
              accA[g2][e] = MFMA16(aX[s], *(const bf16x8_t*)(bp+32*s), accA[g2][e]);
          } } }
      }
      // ---- prefetch for op[io+1] ----
      if (on.type==0 || on.type==1){
        const bf16* px = xT + (((size_t)wg*256 + on.t)*16 + l15)*96 + 8*q;
        #pragma unroll
        for (int s=0;s<3;++s) pX[s] = *(const bf16x8_t*)(px + 32*s);
      }
      if ((on.type==3 || on.type==4) && on.hsrc==1){
        const bf16* ps = sav + (size_t)(wg*64+on.srcidx)*2048 + l15*128 + 8*q;
        #pragma unroll
        for (int s=0;s<4;++s) pHB[s] = *(const bf16x8_t*)(ps + 32*s);
      }
      if (on.type==4 && on.hsrc==1){
        const bf16* ph = sav + (size_t)(wg*64+on.srcidx)*2048;
        #pragma unroll
        for (int g2=0;g2<2;++g2){ if (g2<ng){ int j=16*(wv+4*g2)+l15;
          if (j<100){
            #pragma unroll
            for (int i=0;i<4;++i) pHold[g2][i] = __bfloat162float(ph[(4*q+i)*128 + j]);
          } } }
      }
      // ---- BCELL: coalesced save of pre-update h_back (bf16 copy of current s_hbk buffer) ----
      if (op.type==0 && op.save>=0 && tid<208){
        int r=tid/13, c=tid-13*r;
        const uint4 v = *(const uint4*)(smem + 6784 + bcur*3392 + r*208 + c*16);
        *(uint4*)(sav8 + ((size_t)(wg*64+op.save))*4096 + (size_t)r*256 + c*16) = v;
      }
      // ---- gate stage (lane-local; holds in registers) ----
      bf16* wr = fwd? (s_h + (hcur^1)*1696) : (s_hbk + (bcur^1)*1696);
      const int fi = fwd?1:0;
      #pragma unroll
      for (int g2=0;g2<2;++g2){ if (g2<ng){ int j=16*(wv+4*g2)+l15;
        if (j<100){
          float b0z=Bz0[g2][fi], b0r=Br0[g2][fi], b0n=Bn0[g2][fi];
          float b1z=Bz1[g2][fi], b1r=Br1[g2][fi], b1n=Bn1[g2][fi];
          #pragma unroll
          for (int i=0;i<4;++i){
            int r=4*q+i;
            float gz=0.f, gr=0.f, gn=0.f;
            if (hasX){ gz=accA[g2][0][i]; gr=accA[g2][1][i]; gn=accA[g2][2][i]; }
            float hz=accB[g2][0][i], hr=accB[g2][1][i], hnv=accB[g2][2][i];
            float hold;
            if (fwd) hold = h_reg[g2][i];
            else if (op.hsrc==0) hold = hb_reg[g2][i];
            else if (op.hsrc==1) hold = pHold[g2][i];
            else hold = __bfloat162float(s_spl[(size_t)op.srcidx*2048 + r*128 + j]);
            float az = gz+b0z+hz+b1z; az=fminf(fmaxf(az,-30.f),30.f);
            float ar = gr+b0r+hr+b1r; ar=fminf(fmaxf(ar,-30.f),30.f);
            float z  = 1.f/(1.f+__expf(-az));
            float rg = 1.f/(1.f+__expf(-ar));
            float an = gn+b0n+rg*(hnv+b1n); an=fminf(fmaxf(an,-15.f),15.f);
            float e2 = __expf(2.f*an);
            float nn = (e2-1.f)/(e2+1.f);
            float hnew = z*hold + (1.f-z)*nn;
            if (fwd) h_reg[g2][i]=hnew; else hb_reg[g2][i]=hnew;
            wr[r*104+j] = __float2bfloat16(hnew);
            if (!fwd && op.type==4 && op.aux>=0)
              s_spl[(size_t)op.aux*2048 + r*128 + j] = __float2bfloat16(hnew);
          }
        } } }
      if (fwd) hcur^=1; else bcur^=1;
      BAR();
    } else {
      // ---- DEC: dec = relu([h,hb]@decW+db); mean = dec@meanW+mb -> out + ns ring ----
      const int lvl=op.lvl, t=op.t, slot=t&7;
      bf16x8_t aG[8];
      { const bf16* hp = s_h + hcur*1696 + l15*104 + 8*q;
        #pragma unroll
        for (int s=0;s<4;++s) aG[s] = *(const bf16x8_t*)(hp + 32*s); }
      if (op.hsrc==1){
        #pragma unroll
        for (int s=0;s<4;++s) aG[4+s]=pHB[s];
      } else if (op.hsrc==2){
        const bf16* hp = s_spl + (size_t)op.srcidx*2048 + l15*128 + 8*q;
        #pragma unroll
        for (int s=0;s<4;++s) aG[4+s] = *(const bf16x8_t*)(hp + 32*s);
      } else {
        const bf16* hp = s_hbk + bcur*1696 + l15*104 + 8*q;
        #pragma unroll
        for (int s=0;s<4;++s) aG[4+s] = *(const bf16x8_t*)(hp + 32*s);
      }
      // gemm1: [16,256] x [256 -> 64 cols]; wave wv owns cols 16wv..16wv+15
      { const bf16* bp = dW + ((size_t)(lvl*64 + c16))*256 + 8*q;
        f32x4_t a1=(f32x4_t){0,0,0,0}, a2=(f32x4_t){0,0,0,0};
        #pragma unroll
        for (int s=0;s<8;s+=2){
          a1 = MFMA16(aG[s],   *(const bf16x8_t*)(bp+32*s),    a1);
          a2 = MFMA16(aG[s+1], *(const bf16x8_t*)(bp+32*(s+1)), a2);
        }
        // prefetch for op[io+1]
        if (on.type==0 || on.type==1){
          const bf16* px = xT + (((size_t)wg*256 + on.t)*16 + l15)*96 + 8*q;
          #pragma unroll
          for (int s=0;s<3;++s) pX[s] = *(const bf16x8_t*)(px + 32*s);
        }
        if ((on.type==3 || on.type==4) && on.hsrc==1){
          const bf16* ps = sav + (size_t)(wg*64+on.srcidx)*2048 + l15*128 + 8*q;
          #pragma unroll
          for (int s=0;s<4;++s) pHB[s] = *(const bf16x8_t*)(ps + 32*s);
        }
        if (on.type==4 && on.hsrc==1){
          const bf16* ph = sav + (size_t)(wg*64+on.srcidx)*2048;
          #pragma unroll
          for (int g2=0;g2<2;++g2){ if (g2<ng){ int j=16*(wv+4*g2)+l15;
            if (j<100){
              #pragma unroll
              for (int i=0;i<4;++i) pHold[g2][i] = __bfloat162float(ph[(4*q+i)*128 + j]);
            } } }
        }
        float db = db_l[lvl];
        #pragma unroll
        for (int i=0;i<4;++i){ float v=fmaxf(a1[i]+a2[i]+db,0.f); s_dec[(4*q+i)*72 + c16]=__float2bfloat16(v); }
      }
      BAR();
      // gemm2: A=dec [16,64], B=mean_W^T strip -> out + ring ns
      bf16x8_t aD[2];
      #pragma unroll
      for (int s=0;s<2;++s) aD[s] = *(const bf16x8_t*)(s_dec + l15*72 + 8*q + 32*s);
      { const bf16* bp = MW + ((size_t)(lvl*64 + c16))*64 + 8*q;
        f32x4_t am=(f32x4_t){0,0,0,0};
        #pragma unroll
        for (int s=0;s<2;++s) am = MFMA16(aD[s], *(const bf16x8_t*)(bp+32*s), am);
        float mb = mb_l[lvl];
        #pragma unroll
        for (int i=0;i<4;++i){ int r=4*q+i; size_t b=(size_t)wg*16+r;
          float m = am[i]+mb;
          s_ring[(size_t)(slot*16 + r)*120 + c16] = __float2bfloat16(m);
          if (c16>=1) out[(b*64 + (c16-1))*256 + t] = m;
          else        out[(b*64 + 63)*256 + t]      = 1.0f;
        } }
      if (wv==0 && l15==0){ bf16 one=__float2bfloat16(1.0f);
        #pragma unroll
        for (int i=0;i<4;++i) s_ring[(size_t)(slot*16 + 4*q+i)*120 + 64] = one; }
      BAR();
    }
  }
}

// ---------------- launch ----------------
extern "C" void kernel_launch(void* const* d_in, const int* in_sizes, int n_in,
                              void* d_out, int out_size, void* d_ws, size_t ws_size,
                              hipStream_t stream){
  (void)out_size;
  const float *a=nullptr,*gru_W=nullptr,*gru_U=nullptr,*gru_b=nullptr,*bgru_W=nullptr,
              *bgru_U=nullptr,*bgru_b=nullptr,*dec_W=nullptr,*dec_b=nullptr,
              *mean_W=nullptr,*mean_b=nullptr;
  int nU=0, nb6=0;
  for (int i=0;i<n_in;++i){
    const float* p=(const float*)d_in[i]; int s=in_sizes[i];
    if      (s==25165824) a=p;
    else if (s==19200)    gru_W=p;
    else if (s==19500)    bgru_W=p;
    else if (s==30000)    { if(nU++==0) gru_U=p; else bgru_U=p; }
    else if (s==600)      { if(nb6++==0) gru_b=p; else bgru_b=p; }
    else if (s==40000)    dec_W=p;
    else if (s==200)      dec_b=p;
    else if (s==12800)    mean_W=p;
    else if (s==256)      mean_b=p;
  }
  if (!a||!gru_W||!gru_U||!gru_b||!bgru_W||!bgru_U||!bgru_b||!dec_W||!dec_b||!mean_W||!mean_b){
    a=(const float*)d_in[0]; gru_W=(const float*)d_in[1]; gru_U=(const float*)d_in[2];
    gru_b=(const float*)d_in[3]; bgru_W=(const float*)d_in[4]; bgru_U=(const float*)d_in[5];
    bgru_b=(const float*)d_in[6]; dec_W=(const float*)d_in[7]; dec_b=(const float*)d_in[8];
    mean_W=(const float*)d_in[9]; mean_b=(const float*)d_in[10];
  }
  unsigned char* ws = (unsigned char*)d_ws;
  float* out = (float*)d_out;

  k_obs  <<<512,  64, 0, stream>>>(a, out);
  if (ws_size < WS_NEED) return;

  k_sz   <<<2048, 256, 0, stream>>>((uint4*)(ws+SAV_OFF));
  k_xt   <<<512, 256, 0, stream>>>(a, (bf16*)(ws+XT_OFF));
  k_wt   <<<336, 128, 0, stream>>>(gru_U, bgru_U, gru_W, bgru_W,
                                   (bf16*)(ws+UF_OFF), (bf16*)(ws+UB_OFF),
                                   (bf16*)(ws+WF_OFF), (bf16*)(ws+WB_OFF));
  k_decw <<<256, 256, 0, stream>>>(dec_W, (bf16*)(ws+DW_OFF));
  k_mw   <<<256,  64, 0, stream>>>(mean_W, (bf16*)(ws+MW_OFF));
  k_consts<<<1,  256, 0, stream>>>(gru_b, bgru_b, mean_b, dec_b, (float*)(ws+CST_OFF));
  naomi_main<<<32, 256, 0, stream>>>(ws, out);
}

// Round 5
// 3341.188 us; speedup vs baseline: 1.4239x; 1.2219x over previous
//
#include <hip/hip_runtime.h>
#include <hip/hip_bf16.h>
#include <cstdint>
#include <cstddef>

using bf16 = __hip_bfloat16;
typedef __attribute__((ext_vector_type(8))) short   bf16x8_t;  // 8 bf16 (4 VGPRs)
typedef __attribute__((ext_vector_type(4))) float   f32x4_t;   // mfma accumulator

// ---------------- workspace byte offsets ----------------
#define XT_OFF   ((size_t)0)            // [32 wg][256 t][16 r][96] bf16 (coalesced per-wave X)
#define UF_OFF   ((size_t)25165824)     // [336][128] bf16 gate-ordered U strips (fwd)
#define UB_OFF   ((size_t)25251840)     // (bwd)
#define WF_OFF   ((size_t)25337856)     // fwd W shifted: row k -> gru_W[k-1], k=1..64 (K=128 strip)
#define WB_OFF   ((size_t)25423872)     // bwd W: row k -> bgru_W[k], k=0..64
#define DW_OFF   ((size_t)25509888)     // dec_W strips [4][64][256] bf16
#define MW_OFF   ((size_t)25640960)     // mean_W^T strips [4][64][64] bf16
#define SAV_OFF  ((size_t)25673728)     // saved h_back [32 wg][64 slot][16*128] bf16 (8,388,608 B)
#define CST_OFF  ((size_t)34062336)     // fp32: bf0,bf1,bb0,bb1[336 ea], mb[256], db[256]
#define WBF_OFF  ((size_t)34069760)     // Wb frag-linear [7 strip][3 e][2 s][64 lane][16B] = 43,008 B
#define WS_NEED  ((size_t)34112768)

#define MFMA16(a,b,c) __builtin_amdgcn_mfma_f32_16x16x32_bf16((a),(b),(c),0,0,0)

// counted barrier: drain LDS only; global loads/stores stay in flight across it.
#define BAR()    asm volatile("s_waitcnt lgkmcnt(0)\n\ts_barrier" ::: "memory")

// ---------------- static schedule (mask t%16==0, batch-shared) ----------------
struct Op { uint8_t type, t; int8_t lvl, save, hsrc, srcidx, gisrc, aux; };
// type: 0=BCELL(bwd,X=xT) 1=FA(fwd,X=xT) 2=FF(fwd,X=ring[t&7]) 3=DEC 4=CH(bwd,X=ring[op.t] if gisrc)
// hsrc: 0=CUR 1=SAV 2=SPL(LDS) ; aux: CH spill slot (-1 none) ; CH: op.t = ring slot
struct Sched { Op ops[960]; short n; };

constexpr int slot_of(int tp){ int k=(tp-1)/16; int m=tp%16;
  int pos = (m==9)?0:((m==13)?1:((m==15)?2:3)); return 4*k+pos; }

constexpr Sched build_sched(){
  Sched s{}; int i=0;
  for (int t=255; t>=1; --t){
    int tp=t+1, m=tp%16; int8_t sv=-1;
    if (m==9||m==13||m==15||m==0) sv=(int8_t)slot_of(tp);
    s.ops[i++] = Op{(uint8_t)0,(uint8_t)t,(int8_t)0,sv,(int8_t)0,(int8_t)0,(int8_t)0,(int8_t)0};
  }
  s.ops[i++] = Op{(uint8_t)1,(uint8_t)0,(int8_t)0,(int8_t)-1,(int8_t)0,(int8_t)0,(int8_t)0,(int8_t)0}; // FA(0)
  for (int blk=0; blk<16; ++blk){
    int ba=16*blk; bool last=(blk==15);
    int s16=slot_of(ba+16), s9=slot_of(ba+9), s13=slot_of(ba+13), s15=slot_of(ba+15);
#define PD(dt,lv,hs,si)   s.ops[i++]=Op{(uint8_t)3,(uint8_t)(ba+(dt)),(int8_t)(lv),(int8_t)-1,(int8_t)(hs),(int8_t)(si),(int8_t)0,(int8_t)0};
#define PC(hs,si,gs,sp,sl) s.ops[i++]=Op{(uint8_t)4,(uint8_t)(sl),(int8_t)0,(int8_t)-1,(int8_t)(hs),(int8_t)(si),(int8_t)(gs),(int8_t)(sp)};
#define PF(ft)            s.ops[i++]=Op{(uint8_t)2,(uint8_t)(ba+(ft)),(int8_t)0,(int8_t)-1,(int8_t)0,(int8_t)0,(int8_t)0,(int8_t)0};
#define PA(ft)            s.ops[i++]=Op{(uint8_t)1,(uint8_t)(ba+(ft)),(int8_t)0,(int8_t)-1,(int8_t)0,(int8_t)0,(int8_t)0,(int8_t)0};
    PD(8,3,1,s16)
    PC(1,s9,1,0,0)  PC(0,0,0,1,0) PC(0,0,0,-1,0) PC(0,0,0,-1,0)  // d8(sp0) d7(sp1) d6 d5
    PD(4,2,2,0)
    PC(0,0,1,2,4) PC(0,0,0,-1,0)                                  // d4(sp2) d3
    PD(2,1,2,2)
    PC(0,0,1,-1,2)                                                // d2
    PD(1,0,0,0)
    PF(1) PF(2)
    PD(3,0,2,2)
    PF(3) PF(4)
    PD(6,1,2,0)
    PC(2,1,1,-1,6)                                                // d6' = gru(ns6, d7=sp1)
    PD(5,0,0,0)
    PF(5) PF(6)
    PD(7,0,2,0)
    PF(7) PF(8)
    PD(12,2,1,s16)
    PC(1,s13,1,3,4) PC(0,0,0,-1,0)                                // d12(sp3) d11
    PD(10,1,2,3)
    PC(0,0,1,-1,2)                                                // d10
    PD(9,0,0,0)
    PF(9) PF(10)
    PD(11,0,2,3)
    PF(11) PF(12)
    PD(14,1,1,s16)
    PC(1,s15,1,-1,6)                                              // d14
    PD(13,0,0,0)
    PF(13) PF(14)
    PD(15,0,1,s16)
    if(!last){ PF(15); PA(16); }
#undef PD
#undef PC
#undef PF
#undef PA
  }
  s.n=(short)i; return s;
}
__constant__ Sched g_sched = build_sched();

// ---------------- prep kernels (fp32 inputs -> bf16 internal) ----------------
__global__ void k_xt(const float* __restrict__ a, bf16* __restrict__ xT){
  int b=blockIdx.x, t=threadIdx.x;
  int wgi=b>>4, r=b&15;
  bf16* dst = xT + (((size_t)wgi*256 + t)*16 + r)*96;
  const float* ap = a + (size_t)b*64*256*3;
  for (int c=0;c<64;++c) dst[c] = __float2bfloat16(ap[((size_t)c*256+t)*3]);
  dst[64] = __float2bfloat16(ap[(size_t)t*3 + 2]);
  bf16 z = __float2bfloat16(0.f);
  for (int c=65;c<96;++c) dst[c]=z;
}

__global__ void k_obs(const float* __restrict__ a, float* __restrict__ out){
  int b=blockIdx.x, d=threadIdx.x; // 64 threads
  for (int kk=0;kk<16;++kk){ int t=kk*16;
    float v = (d<63)? a[(((size_t)b*64 + d+1)*256 + t)*3]
                    : a[((size_t)b*64*256 + t)*3 + 2];
    out[((size_t)b*64 + d)*256 + t] = v;
  }
}

__global__ void k_wt(const float* __restrict__ gru_U, const float* __restrict__ bgru_U,
                     const float* __restrict__ gru_W, const float* __restrict__ bgru_W,
                     bf16* Uf, bf16* Ub, bf16* Wf, bf16* Wb){
  int c=blockIdx.x, k=threadIdx.x; // 336 x 128
  int g=c/48, rm=c%48, e=rm/16, l=rm%16, j=16*g+l;
  bool val = j<100; int gc = val? (e*100+j) : 0;
  bf16 z = __float2bfloat16(0.f);
  Uf[(size_t)c*128+k] = (val&&k<100)? __float2bfloat16(gru_U[k*300+gc]) : z;
  Ub[(size_t)c*128+k] = (val&&k<100)? __float2bfloat16(bgru_U[k*300+gc]) : z;
  Wf[(size_t)c*128+k] = (val&&k>=1&&k<=64)? __float2bfloat16(gru_W[(k-1)*300+gc]) : z;
  Wb[(size_t)c*128+k] = (val&&k<65)? __float2bfloat16(bgru_W[k*300+gc]) : z;
}

// Wb frag-linear copy: [strip st][e][s][lane] <- Wb[c=48st+16e+(lane&15)][k=32s+8*(lane>>4) .. +7]
__global__ void k_wbf(const bf16* __restrict__ Wb, uint4* __restrict__ dst){
  int bid=blockIdx.x;  // 42
  int l=threadIdx.x;   // 64
  int st=bid/6, r=bid%6, e=r/2, s=r%2;
  int c=48*st+16*e+(l&15);
  int k=8*(l>>4)+32*s;
  dst[bid*64+l] = *(const uint4*)(Wb + (size_t)c*128 + k);
}

__global__ void k_decw(const float* __restrict__ dec_W, bf16* dWt){
  int idx=blockIdx.x; int lvl=idx/64, n=idx%64; int k=threadIdx.x; // 256 blocks x 256 thr
  float v=0.f;
  if (n<50){
    if (k<100) v = dec_W[(lvl*200+k)*50+n];            // h rows 0..99
    else if (k>=128 && k<228) v = dec_W[(lvl*200+k-28)*50+n]; // hb rows 100..199
  }
  dWt[(size_t)idx*256+k] = __float2bfloat16(v);
}

__global__ void k_mw(const float* __restrict__ mean_W, bf16* MW){
  int idx=blockIdx.x; int lvl=idx/64, c=idx%64; int k=threadIdx.x; // 64
  MW[(size_t)idx*64+k] = (k<50)? __float2bfloat16(mean_W[(lvl*50+k)*64+c]) : __float2bfloat16(0.f);
}

__global__ void k_consts(const float* __restrict__ gru_b, const float* __restrict__ bgru_b,
                         const float* __restrict__ mean_b, const float* __restrict__ dec_b,
                         float* cst){
  int tid=threadIdx.x;
  for (int u=tid; u<336; u+=256){
    int c=u; int g=c/48, rm=c%48, e=rm/16, l=rm%16, j=16*g+l;
    float b0f=0,b1f=0,b0b=0,b1b=0;
    if (j<100){ int gc=e*100+j;
      b0f=gru_b[gc];  b1f=gru_b[300+gc];
      b0b=bgru_b[gc]; b1b=bgru_b[300+gc]; }
    cst[u]=b0f; cst[336+u]=b1f; cst[672+u]=b0b; cst[1008+u]=b1b;
  }
  if (tid<256){
    int lvl=tid/64, m=tid%64;
    cst[1344+tid]=mean_b[lvl*64+m];
    cst[1600+tid]=(m<50)? dec_b[lvl*50+m] : 0.f;
  }
}

__global__ void k_sz(uint4* p){
  p[(size_t)blockIdx.x*256 + threadIdx.x] = make_uint4(0u,0u,0u,0u);
}

// ---------------- specialized backward GRU cell ----------------
static __device__ __forceinline__ void bcell_step(
  int t, int bc, int sv,
  unsigned char* smem, const bf16* xT, unsigned char* sav8,
  int wg, int tid, int l15, int q, int wv, int ng,
  const bf16x8_t (&rUb)[2][3][4], const float (&W64v)[2][3],
  const float (&Bz0)[2][2], const float (&Br0)[2][2], const float (&Bn0)[2][2],
  const float (&Bz1)[2][2], const float (&Br1)[2][2], const float (&Bn1)[2][2],
  float (&hb_reg)[2][4], bf16x8_t (&pX)[3])
{
  const int lane = tid & 63;
  // issue next-X prefetch first (HBM latency hides under this op's compute)
  const bf16* px = xT + (((size_t)wg*256 + (t-1))*16 + l15)*96 + 8*q;
  bf16x8_t nX0 = *(const bf16x8_t*)(px);
  bf16x8_t nX1 = *(const bf16x8_t*)(px + 32);
  // aH fragments from s_hbk[bc]
  const bf16* hp = (const bf16*)(smem + 6784) + bc*1696 + l15*104 + 8*q;
  bf16x8_t aH[4];
  #pragma unroll
  for (int s=0;s<4;++s) aH[s] = *(const bf16x8_t*)(hp + 32*s);

  f32x4_t accB[2][3], accA[2][3];
  #pragma unroll
  for (int g2=0;g2<2;++g2)
    #pragma unroll
    for (int e=0;e<3;++e){ accB[g2][e]=(f32x4_t){0,0,0,0}; accA[g2][e]=(f32x4_t){0,0,0,0}; }

  // h @ Ub (registers)
  #pragma unroll
  for (int g2=0;g2<2;++g2){ if (g2<ng){
    #pragma unroll
    for (int e=0;e<3;++e){
      #pragma unroll
      for (int s=0;s<4;++s)
        accB[g2][e] = MFMA16(aH[s], rUb[g2][e][s], accB[g2][e]);
    } } }
  // X @ Wb (LDS frag-linear, k=0..63; mask row folded via W64v)
  #pragma unroll
  for (int g2=0;g2<2;++g2){ if (g2<ng){
    #pragma unroll
    for (int e=0;e<3;++e){
      #pragma unroll
      for (int s=0;s<2;++s){
        const bf16x8_t bw = *(const bf16x8_t*)(smem + 15920 + ((((wv+4*g2)*3+e)*2+s)<<10) + lane*16);
        accA[g2][e] = MFMA16(pX[s], bw, accA[g2][e]);
      } } } }
  // save pre-update h_back (coalesced uint4)
  if (sv>=0 && tid<208){
    int r=tid/13, cc=tid-13*r;
    const uint4 v = *(const uint4*)(smem + 6784 + bc*3392 + r*208 + cc*16);
    *(uint4*)(sav8 + ((size_t)(wg*64+sv))*4096 + (size_t)r*256 + cc*16) = v;
  }
  // gate (bwd biases, fi=0)
  const bool mk = ((t&15)==0);
  bf16* wr = (bf16*)(smem + 6784) + (bc^1)*1696;
  #pragma unroll
  for (int g2=0;g2<2;++g2){ if (g2<ng){ int j=16*(wv+4*g2)+l15;
    if (j<100){
      float b0z=Bz0[g2][0], b0r=Br0[g2][0], b0n=Bn0[g2][0];
      float b1z=Bz1[g2][0], b1r=Br1[g2][0], b1n=Bn1[g2][0];
      #pragma unroll
      for (int i=0;i<4;++i){
        int r=4*q+i;
        float gz=accA[g2][0][i], gr=accA[g2][1][i], gn=accA[g2][2][i];
        if (mk){ gz+=W64v[g2][0]; gr+=W64v[g2][1]; gn+=W64v[g2][2]; }
        float hz=accB[g2][0][i], hr=accB[g2][1][i], hnv=accB[g2][2][i];
        float hold = hb_reg[g2][i];
        float az = gz+b0z+hz+b1z; az=fminf(fmaxf(az,-30.f),30.f);
        float ar = gr+b0r+hr+b1r; ar=fminf(fmaxf(ar,-30.f),30.f);
        float z  = 1.f/(1.f+__expf(-az));
        float rg = 1.f/(1.f+__expf(-ar));
        float an = gn+b0n+rg*(hnv+b1n); an=fminf(fmaxf(an,-15.f),15.f);
        float e2 = __expf(2.f*an);
        float nn = (e2-1.f)/(e2+1.f);
        float hnew = z*hold + (1.f-z)*nn;
        hb_reg[g2][i]=hnew;
        wr[r*104+j] = __float2bfloat16(hnew);
      }
    } } }
  pX[0]=nX0; pX[1]=nX1;
  BAR();
}

// ---------------- main persistent kernel: 32 WGs x 256 thr, 16 batch rows each ----------------
__launch_bounds__(256, 1)
__global__ void naomi_main(unsigned char* __restrict__ ws, float* __restrict__ out){
  const int tid=threadIdx.x, wg=blockIdx.x;
  const int lane=tid&63, wv=tid>>6;
  const int l15=lane&15, q=lane>>4;
  const int ng=(wv<3)?2:1;

  const bf16* xT = (const bf16*)(ws + XT_OFF);
  const bf16* Uf = (const bf16*)(ws + UF_OFF);
  const bf16* Ub = (const bf16*)(ws + UB_OFF);
  const bf16* Wf = (const bf16*)(ws + WF_OFF);
  const bf16* Wb = (const bf16*)(ws + WB_OFF);
  const bf16* dW = (const bf16*)(ws + DW_OFF);
  const bf16* MW = (const bf16*)(ws + MW_OFF);
  bf16* sav = (bf16*)(ws + SAV_OFF);
  unsigned char* sav8 = (unsigned char*)(ws + SAV_OFF);
  const float* cst = (const float*)(ws + CST_OFF);

  // LDS (63,024 B): s_h 2x[16][104] | s_hbk 2x[16][104] | s_dec [16][72]+pad | ring [8][16][120] | spl [4][16][128]
  // During the bwd sweep the ring/spl region (15920..58928) is overlaid with Wb frags; re-zeroed at transition.
  __shared__ alignas(16) unsigned char smem[63024];
  bf16* s_h    = (bf16*)(smem + 0);      // 6784 B (two 1696-elem buffers)
  bf16* s_hbk  = (bf16*)(smem + 6784);   // 6784 B
  bf16* s_dec  = (bf16*)(smem + 13568);  // 2352 B
  bf16* s_ring = (bf16*)(smem + 15920);  // 30720 B
  bf16* s_spl  = (bf16*)(smem + 46640);  // 16384 B

  // zero s_h / s_hbk / s_dec only (ring/spl zeroed at bwd->fwd transition)
  for (int u=tid; u<3980; u+=256) ((uint32_t*)smem)[u]=0u;
  // stage Wb frags into the overlay region
  { uint4* df=(uint4*)(smem+15920); const uint4* sf=(const uint4*)(ws+WBF_OFF);
    for (int u=tid; u<2688; u+=256) df[u]=sf[u]; }

  // per-thread gate biases [g2][dir: 0=bwd 1=fwd]
  float Bz0[2][2],Br0[2][2],Bn0[2][2],Bz1[2][2],Br1[2][2],Bn1[2][2];
  #pragma unroll
  for (int g2=0; g2<2; ++g2){
    if (g2<ng){
      int cz=48*(wv+4*g2)+l15;
      Bz0[g2][1]=cst[cz];      Br0[g2][1]=cst[cz+16];      Bn0[g2][1]=cst[cz+32];
      Bz1[g2][1]=cst[336+cz];  Br1[g2][1]=cst[336+cz+16];  Bn1[g2][1]=cst[336+cz+32];
      Bz0[g2][0]=cst[672+cz];  Br0[g2][0]=cst[672+cz+16];  Bn0[g2][0]=cst[672+cz+32];
      Bz1[g2][0]=cst[1008+cz]; Br1[g2][0]=cst[1008+cz+16]; Bn1[g2][0]=cst[1008+cz+32];
    } else {
      Bz0[g2][0]=Bz0[g2][1]=Br0[g2][0]=Br0[g2][1]=Bn0[g2][0]=Bn0[g2][1]=0.f;
      Bz1[g2][0]=Bz1[g2][1]=Br1[g2][0]=Br1[g2][1]=Bn1[g2][0]=Bn1[g2][1]=0.f;
    }
  }
  const int c16 = 16*wv+l15;
  float mb_l[4], db_l[4];
  #pragma unroll
  for (int l=0;l<4;++l){ mb_l[l]=cst[1344+l*64+c16]; db_l[l]=cst[1600+l*64+c16]; }

  // Ub strips resident in registers (Uf deferred to after the bwd sweep)
  bf16x8_t rUf[2][3][4], rUb[2][3][4];
  #pragma unroll
  for (int g2=0; g2<2; ++g2){
    if (g2<ng){
      #pragma unroll
      for (int e=0;e<3;++e){ int c=48*(wv+4*g2)+16*e+l15;
        #pragma unroll
        for (int s=0;s<4;++s)
          rUb[g2][e][s] = *(const bf16x8_t*)(Ub + (size_t)c*128 + 8*q + 32*s);
      }
    }
  }
  // mask-row weights (Wb row 64), folded out of the X-GEMM
  float W64v[2][3];
  #pragma unroll
  for (int g2=0; g2<2; ++g2){
    if (g2<ng){
      #pragma unroll
      for (int e=0;e<3;++e){ int c=48*(wv+4*g2)+16*e+l15;
        W64v[g2][e] = __bfloat162float(Wb[(size_t)c*128 + 64]); }
    } else { W64v[g2][0]=W64v[g2][1]=W64v[g2][2]=0.f; }
  }
  __syncthreads();

  // fp32 master state in registers
  float h_reg[2][4], hb_reg[2][4];
  #pragma unroll
  for (int g2=0;g2<2;++g2){
    #pragma unroll
    for (int i=0;i<4;++i){ h_reg[g2][i]=0.f; hb_reg[g2][i]=0.f; }
  }
  int hcur=0, bcur=0;

  // prefetch registers
  bf16x8_t pX[3], pHB[4];
  float pHold[2][4];
  #pragma unroll
  for (int g2=0;g2<2;++g2){
    #pragma unroll
    for (int i=0;i<4;++i) pHold[g2][i]=0.f;
  }
  { // prologue: prefetch X(t=255)
    const bf16* px = xT + (((size_t)wg*256 + 255)*16 + l15)*96 + 8*q;
    #pragma unroll
    for (int s=0;s<3;++s) pX[s] = *(const bf16x8_t*)(px + 32*s);
  }

  // ================= specialized backward sweep: t = 255 .. 1 =================
  bcell_step(255, 0, 63, smem, xT, sav8, wg, tid, l15, q, wv, ng,
             rUb, W64v, Bz0, Br0, Bn0, Bz1, Br1, Bn1, hb_reg, pX);
  for (int t=254; t>=2; t-=2){
    int m=t&15;
    int sv1 = (m==8)? ((t>>4)<<2) : (m==12)? (((t>>4)<<2)+1) : (m==14)? (((t>>4)<<2)+2) : -1;
    bcell_step(t, 1, sv1, smem, xT, sav8, wg, tid, l15, q, wv, ng,
               rUb, W64v, Bz0, Br0, Bn0, Bz1, Br1, Bn1, hb_reg, pX);
    int sv2 = (((t-1)&15)==15)? ((((t-1)>>4)<<2)+3) : -1;
    bcell_step(t-1, 0, sv2, smem, xT, sav8, wg, tid, l15, q, wv, ng,
               rUb, W64v, Bz0, Br0, Bn0, Bz1, Br1, Bn1, hb_reg, pX);
  }
  bcur = 1;   // parity after 255 steps

  // ================= bwd -> fwd transition =================
  // re-zero the overlay region (ring / spl; FF reads pad cols, spl reads pad cols -> must be 0)
  for (int u=3980+tid; u<15756; u+=256) ((uint32_t*)smem)[u]=0u;
  // load Uf strips now
  #pragma unroll
  for (int g2=0; g2<2; ++g2){
    if (g2<ng){
      #pragma unroll
      for (int e=0;e<3;++e){ int c=48*(wv+4*g2)+16*e+l15;
        #pragma unroll
        for (int s=0;s<4;++s)
          rUf[g2][e][s] = *(const bf16x8_t*)(Uf + (size_t)c*128 + 8*q + 32*s);
      }
    }
  }
  // complete pX for FA(0): slice 2 (t=0) was not loaded by the bwd loop
  pX[2] = *(const bf16x8_t*)(xT + (((size_t)wg*256 + 0)*16 + l15)*96 + 8*q + 64);
  __syncthreads();   // full drain: sav stores visible, LDS zeros visible

  // ================= forward phase op-machine (ops 255..n-1) =================
  const int nops = g_sched.n;
  for (int io=255; io<nops; ++io){
    const Op op = g_sched.ops[io];
    const Op on = g_sched.ops[(io+1<nops)? io+1 : io];
    if (op.type != 3){
      const bool fwd = (op.type==1)||(op.type==2);
      const bool hasX = (op.type==1)||(op.type==2)||(op.type==4 && op.gisrc==1);
      // ---- A fragments (h operand) ----
      bf16x8_t aH[4];
      if (!fwd && op.hsrc==1){
        #pragma unroll
        for (int s=0;s<4;++s) aH[s]=pHB[s];
      } else if (!fwd && op.hsrc==2){
        const bf16* hp = s_spl + (size_t)op.srcidx*2048 + l15*128 + 8*q;
        #pragma unroll
        for (int s=0;s<4;++s) aH[s] = *(const bf16x8_t*)(hp + 32*s);
      } else {
        const bf16* hp = (fwd? s_h + hcur*1696 : s_hbk + bcur*1696) + l15*104 + 8*q;
        #pragma unroll
        for (int s=0;s<4;++s) aH[s] = *(const bf16x8_t*)(hp + 32*s);
      }
      // ---- X fragments ----
      bf16x8_t aX[3];
      if (op.type==1){
        #pragma unroll
        for (int s=0;s<3;++s) aX[s]=pX[s];
      } else if (op.type==2){
        const bf16* xp = s_ring + (size_t)((op.t&7)*16 + l15)*120 + 8*q;
        #pragma unroll
        for (int s=0;s<3;++s) aX[s] = *(const bf16x8_t*)(xp + 32*s);
      } else if (op.type==4 && op.gisrc==1){
        const bf16* xp = s_ring + (size_t)(op.t*16 + l15)*120 + 8*q;
        #pragma unroll
        for (int s=0;s<3;++s) aX[s] = *(const bf16x8_t*)(xp + 32*s);
      }
      // ---- MFMA: U from registers first, then W from global ----
      f32x4_t accB[2][3], accA[2][3];
      #pragma unroll
      for (int g2=0;g2<2;++g2)
        #pragma unroll
        for (int e=0;e<3;++e){ accB[g2][e]=(f32x4_t){0,0,0,0}; accA[g2][e]=(f32x4_t){0,0,0,0}; }
      if (fwd){
        #pragma unroll
        for (int g2=0;g2<2;++g2){ if (g2<ng){
          #pragma unroll
          for (int e=0;e<3;++e){
            #pragma unroll
            for (int s=0;s<4;++s)
              accB[g2][e] = MFMA16(aH[s], rUf[g2][e][s], accB[g2][e]);
          } } }
      } else {
        #pragma unroll
        for (int g2=0;g2<2;++g2){ if (g2<ng){
          #pragma unroll
          for (int e=0;e<3;++e){
            #pragma unroll
            for (int s=0;s<4;++s)
              accB[g2][e] = MFMA16(aH[s], rUb[g2][e][s], accB[g2][e]);
          } } }
      }
      if (hasX){
        const bf16* Wp = fwd? Wf : Wb;
        #pragma unroll
        for (int g2=0;g2<2;++g2){ if (g2<ng){
          #pragma unroll
          for (int e=0;e<3;++e){ int c=48*(wv+4*g2)+16*e+l15;
            const bf16* bp = Wp + (size_t)c*128 + 8*q;
            #pragma unroll
            for (int s=0;s<3;++s)
              accA[g2][e] = MFMA16(aX[s], *(const bf16x8_t*)(bp+32*s), accA[g2][e]);
          } } }
      }
      // ---- prefetch for op[io+1] ----
      if (on.type==1){
        const bf16* px = xT + (((size_t)wg*256 + on.t)*16 + l15)*96 + 8*q;
        #pragma unroll
        for (int s=0;s<3;++s) pX[s] = *(const bf16x8_t*)(px + 32*s);
      }
      if ((on.type==3 || on.type==4) && on.hsrc==1){
        const bf16* ps = sav + (size_t)(wg*64+on.srcidx)*2048 + l15*128 + 8*q;
        #pragma unroll
        for (int s=0;s<4;++s) pHB[s] = *(const bf16x8_t*)(ps + 32*s);
      }
      if (on.type==4 && on.hsrc==1){
        const bf16* ph = sav + (size_t)(wg*64+on.srcidx)*2048;
        #pragma unroll
        for (int g2=0;g2<2;++g2){ if (g2<ng){ int j=16*(wv+4*g2)+l15;
          if (j<100){
            #pragma unroll
            for (int i=0;i<4;++i) pHold[g2][i] = __bfloat162float(ph[(4*q+i)*128 + j]);
          } } }
      }
      // ---- gate stage (lane-local; holds in registers) ----
      bf16* wr = fwd? (s_h + (hcur^1)*1696) : (s_hbk + (bcur^1)*1696);
      const int fi = fwd?1:0;
      #pragma unroll
      for (int g2=0;g2<2;++g2){ if (g2<ng){ int j=16*(wv+4*g2)+l15;
        if (j<100){
          float b0z=Bz0[g2][fi], b0r=Br0[g2][fi], b0n=Bn0[g2][fi];
          float b1z=Bz1[g2][fi], b1r=Br1[g2][fi], b1n=Bn1[g2][fi];
          #pragma unroll
          for (int i=0;i<4;++i){
            int r=4*q+i;
            float gz=0.f, gr=0.f, gn=0.f;
            if (hasX){ gz=accA[g2][0][i]; gr=accA[g2][1][i]; gn=accA[g2][2][i]; }
            float hz=accB[g2][0][i], hr=accB[g2][1][i], hnv=accB[g2][2][i];
            float hold;
            if (fwd) hold = h_reg[g2][i];
            else if (op.hsrc==0) hold = hb_reg[g2][i];
            else if (op.hsrc==1) hold = pHold[g2][i];
            else hold = __bfloat162float(s_spl[(size_t)op.srcidx*2048 + r*128 + j]);
            float az = gz+b0z+hz+b1z; az=fminf(fmaxf(az,-30.f),30.f);
            float ar = gr+b0r+hr+b1r; ar=fminf(fmaxf(ar,-30.f),30.f);
            float z  = 1.f/(1.f+__expf(-az));
            float rg = 1.f/(1.f+__expf(-ar));
            float an = gn+b0n+rg*(hnv+b1n); an=fminf(fmaxf(an,-15.f),15.f);
            float e2 = __expf(2.f*an);
            float nn = (e2-1.f)/(e2+1.f);
            float hnew = z*hold + (1.f-z)*nn;
            if (fwd) h_reg[g2][i]=hnew; else hb_reg[g2][i]=hnew;
            wr[r*104+j] = __float2bfloat16(hnew);
            if (!fwd && op.type==4 && op.aux>=0)
              s_spl[(size_t)op.aux*2048 + r*128 + j] = __float2bfloat16(hnew);
          }
        } } }
      if (fwd) hcur^=1; else bcur^=1;
      BAR();
    } else {
      // ---- DEC: dec = relu([h,hb]@decW+db); mean = dec@meanW+mb -> out + ns ring ----
      const int lvl=op.lvl, t=op.t, slot=t&7;
      bf16x8_t aG[8];
      { const bf16* hp = s_h + hcur*1696 + l15*104 + 8*q;
        #pragma unroll
        for (int s=0;s<4;++s) aG[s] = *(const bf16x8_t*)(hp + 32*s); }
      if (op.hsrc==1){
        #pragma unroll
        for (int s=0;s<4;++s) aG[4+s]=pHB[s];
      } else if (op.hsrc==2){
        const bf16* hp = s_spl + (size_t)op.srcidx*2048 + l15*128 + 8*q;
        #pragma unroll
        for (int s=0;s<4;++s) aG[4+s] = *(const bf16x8_t*)(hp + 32*s);
      } else {
        const bf16* hp = s_hbk + bcur*1696 + l15*104 + 8*q;
        #pragma unroll
        for (int s=0;s<4;++s) aG[4+s] = *(const bf16x8_t*)(hp + 32*s);
      }
      // gemm1: [16,256] x [256 -> 64 cols]; wave wv owns cols 16wv..16wv+15
      { const bf16* bp = dW + ((size_t)(lvl*64 + c16))*256 + 8*q;
        f32x4_t a1=(f32x4_t){0,0,0,0}, a2=(f32x4_t){0,0,0,0};
        #pragma unroll
        for (int s=0;s<8;s+=2){
          a1 = MFMA16(aG[s],   *(const bf16x8_t*)(bp+32*s),    a1);
          a2 = MFMA16(aG[s+1], *(const bf16x8_t*)(bp+32*(s+1)), a2);
        }
        // prefetch for op[io+1]
        if (on.type==1){
          const bf16* px = xT + (((size_t)wg*256 + on.t)*16 + l15)*96 + 8*q;
          #pragma unroll
          for (int s=0;s<3;++s) pX[s] = *(const bf16x8_t*)(px + 32*s);
        }
        if ((on.type==3 || on.type==4) && on.hsrc==1){
          const bf16* ps = sav + (size_t)(wg*64+on.srcidx)*2048 + l15*128 + 8*q;
          #pragma unroll
          for (int s=0;s<4;++s) pHB[s] = *(const bf16x8_t*)(ps + 32*s);
        }
        if (on.type==4 && on.hsrc==1){
          const bf16* ph = sav + (size_t)(wg*64+on.srcidx)*2048;
          #pragma unroll
          for (int g2=0;g2<2;++g2){ if (g2<ng){ int j=16*(wv+4*g2)+l15;
            if (j<100){
              #pragma unroll
              for (int i=0;i<4;++i) pHold[g2][i] = __bfloat162float(ph[(4*q+i)*128 + j]);
            } } }
        }
        float db = db_l[lvl];
        #pragma unroll
        for (int i=0;i<4;++i){ float v=fmaxf(a1[i]+a2[i]+db,0.f); s_dec[(4*q+i)*72 + c16]=__float2bfloat16(v); }
      }
      BAR();
      // gemm2: A=dec [16,64], B=mean_W^T strip -> out + ring ns
      bf16x8_t aD[2];
      #pragma unroll
      for (int s=0;s<2;++s) aD[s] = *(const bf16x8_t*)(s_dec + l15*72 + 8*q + 32*s);
      { const bf16* bp = MW + ((size_t)(lvl*64 + c16))*64 + 8*q;
        f32x4_t am=(f32x4_t){0,0,0,0};
        #pragma unroll
        for (int s=0;s<2;++s) am = MFMA16(aD[s], *(const bf16x8_t*)(bp+32*s), am);
        float mb = mb_l[lvl];
        #pragma unroll
        for (int i=0;i<4;++i){ int r=4*q+i; size_t b=(size_t)wg*16+r;
          float m = am[i]+mb;
          s_ring[(size_t)(slot*16 + r)*120 + c16] = __float2bfloat16(m);
          if (c16>=1) out[(b*64 + (c16-1))*256 + t] = m;
          else        out[(b*64 + 63)*256 + t]      = 1.0f;
        } }
      if (wv==0 && l15==0){ bf16 one=__float2bfloat16(1.0f);
        #pragma unroll
        for (int i=0;i<4;++i) s_ring[(size_t)(slot*16 + 4*q+i)*120 + 64] = one; }
      BAR();
    }
  }
}

// ---------------- launch ----------------
extern "C" void kernel_launch(void* const* d_in, const int* in_sizes, int n_in,
                              void* d_out, int out_size, void* d_ws, size_t ws_size,
                              hipStream_t stream){
  (void)out_size;
  const float *a=nullptr,*gru_W=nullptr,*gru_U=nullptr,*gru_b=nullptr,*bgru_W=nullptr,
              *bgru_U=nullptr,*bgru_b=nullptr,*dec_W=nullptr,*dec_b=nullptr,
              *mean_W=nullptr,*mean_b=nullptr;
  int nU=0, nb6=0;
  for (int i=0;i<n_in;++i){
    const float* p=(const float*)d_in[i]; int s=in_sizes[i];
    if      (s==25165824) a=p;
    else if (s==19200)    gru_W=p;
    else if (s==19500)    bgru_W=p;
    else if (s==30000)    { if(nU++==0) gru_U=p; else bgru_U=p; }
    else if (s==600)      { if(nb6++==0) gru_b=p; else bgru_b=p; }
    else if (s==40000)    dec_W=p;
    else if (s==200)      dec_b=p;
    else if (s==12800)    mean_W=p;
    else if (s==256)      mean_b=p;
  }
  if (!a||!gru_W||!gru_U||!gru_b||!bgru_W||!bgru_U||!bgru_b||!dec_W||!dec_b||!mean_W||!mean_b){
    a=(const float*)d_in[0]; gru_W=(const float*)d_in[1]; gru_U=(const float*)d_in[2];
    gru_b=(const float*)d_in[3]; bgru_W=(const float*)d_in[4]; bgru_U=(const float*)d_in[5];
    bgru_b=(const float*)d_in[6]; dec_W=(const float*)d_in[7]; dec_b=(const float*)d_in[8];
    mean_W=(const float*)d_in[9]; mean_b=(const float*)d_in[10];
  }
  unsigned char* ws = (unsigned char*)d_ws;
  float* out = (float*)d_out;

  k_obs  <<<512,  64, 0, stream>>>(a, out);
  if (ws_size < WS_NEED) return;

  k_sz   <<<2048, 256, 0, stream>>>((uint4*)(ws+SAV_OFF));
  k_xt   <<<512, 256, 0, stream>>>(a, (bf16*)(ws+XT_OFF));
  k_wt   <<<336, 128, 0, stream>>>(gru_U, bgru_U, gru_W, bgru_W,
                                   (bf16*)(ws+UF_OFF), (bf16*)(ws+UB_OFF),
                                   (bf16*)(ws+WF_OFF), (bf16*)(ws+WB_OFF));
  k_wbf  <<<42,   64, 0, stream>>>((const bf16*)(ws+WB_OFF), (uint4*)(ws+WBF_OFF));
  k_decw <<<256, 256, 0, stream>>>(dec_W, (bf16*)(ws+DW_OFF));
  k_mw   <<<256,  64, 0, stream>>>(mean_W, (bf16*)(ws+MW_OFF));
  k_consts<<<1,  256, 0, stream>>>(gru_b, bgru_b, mean_b, dec_b, (float*)(ws+CST_OFF));
  naomi_main<<<32, 256, 0, stream>>>(ws, out);
}

// Round 6
// 2714.518 us; speedup vs baseline: 1.7527x; 1.2309x over previous
//
#include <hip/hip_runtime.h>
#include <hip/hip_bf16.h>
#include <cstdint>
#include <cstddef>

using bf16 = __hip_bfloat16;
typedef __attribute__((ext_vector_type(8))) short   bf16x8_t;  // 8 bf16 (4 VGPRs)
typedef __attribute__((ext_vector_type(4))) float   f32x4_t;   // mfma accumulator

// ---------------- workspace byte offsets ----------------
#define XT_OFF   ((size_t)0)            // [32 wg][256 t][16 r][96] bf16 (coalesced per-wave X)
#define UF_OFF   ((size_t)25165824)     // [336][128] bf16 gate-ordered U strips (fwd)
#define UB_OFF   ((size_t)25251840)     // (bwd)
#define WF_OFF   ((size_t)25337856)     // fwd W shifted: row k -> gru_W[k-1], k=1..64 (K=128 strip)
#define WB_OFF   ((size_t)25423872)     // bwd W: row k -> bgru_W[k], k=0..64
#define DW_OFF   ((size_t)25509888)     // dec_W strips [4][64][256] bf16
#define MW_OFF   ((size_t)25640960)     // mean_W^T strips [4][64][64] bf16
#define SAV_OFF  ((size_t)25673728)     // saved h_back [32 wg][64 slot][16*128] bf16 (8,388,608 B)
#define CST_OFF  ((size_t)34062336)     // fp32: bf0,bf1,bb0,bb1[336 ea], mb[256], db[256]
#define WBF_OFF  ((size_t)34069760)     // frag-linear W tables: [Wb 43008 B][Wf 43008 B]
#define WS_NEED  ((size_t)34155776)

// LDS frag-table bases (permanent)
#define WBF_LDS  63024
#define WFF_LDS  106032
// total LDS = 63024 + 86016 = 149,040 B (<= 160 KiB, 1 WG/CU)

#define MFMA16(a,b,c) __builtin_amdgcn_mfma_f32_16x16x32_bf16((a),(b),(c),0,0,0)

// counted barrier: drain LDS only; global loads/stores stay in flight across it.
#define BAR()    asm volatile("s_waitcnt lgkmcnt(0)\n\ts_barrier" ::: "memory")

// ---------------- static schedule (mask t%16==0, batch-shared) ----------------
struct Op { uint8_t type, t; int8_t lvl, save, hsrc, srcidx, gisrc, aux; };
// type: 0=BCELL(bwd,X=xT) 1=FA(fwd,X=xT) 2=FF(fwd,X=ring[t&7]) 3=DEC 4=CH(bwd,X=ring[op.t] if gisrc)
// hsrc: 0=CUR 1=SAV 2=SPL(LDS) ; aux: CH spill slot (-1 none) ; CH: op.t = ring slot
struct Sched { Op ops[960]; short n; };

constexpr int slot_of(int tp){ int k=(tp-1)/16; int m=tp%16;
  int pos = (m==9)?0:((m==13)?1:((m==15)?2:3)); return 4*k+pos; }

constexpr Sched build_sched(){
  Sched s{}; int i=0;
  for (int t=255; t>=1; --t){
    int tp=t+1, m=tp%16; int8_t sv=-1;
    if (m==9||m==13||m==15||m==0) sv=(int8_t)slot_of(tp);
    s.ops[i++] = Op{(uint8_t)0,(uint8_t)t,(int8_t)0,sv,(int8_t)0,(int8_t)0,(int8_t)0,(int8_t)0};
  }
  s.ops[i++] = Op{(uint8_t)1,(uint8_t)0,(int8_t)0,(int8_t)-1,(int8_t)0,(int8_t)0,(int8_t)0,(int8_t)0}; // FA(0)
  for (int blk=0; blk<16; ++blk){
    int ba=16*blk; bool last=(blk==15);
    int s16=slot_of(ba+16), s9=slot_of(ba+9), s13=slot_of(ba+13), s15=slot_of(ba+15);
#define PD(dt,lv,hs,si)   s.ops[i++]=Op{(uint8_t)3,(uint8_t)(ba+(dt)),(int8_t)(lv),(int8_t)-1,(int8_t)(hs),(int8_t)(si),(int8_t)0,(int8_t)0};
#define PC(hs,si,gs,sp,sl) s.ops[i++]=Op{(uint8_t)4,(uint8_t)(sl),(int8_t)0,(int8_t)-1,(int8_t)(hs),(int8_t)(si),(int8_t)(gs),(int8_t)(sp)};
#define PF(ft)            s.ops[i++]=Op{(uint8_t)2,(uint8_t)(ba+(ft)),(int8_t)0,(int8_t)-1,(int8_t)0,(int8_t)0,(int8_t)0,(int8_t)0};
#define PA(ft)            s.ops[i++]=Op{(uint8_t)1,(uint8_t)(ba+(ft)),(int8_t)0,(int8_t)-1,(int8_t)0,(int8_t)0,(int8_t)0,(int8_t)0};
    PD(8,3,1,s16)
    PC(1,s9,1,0,0)  PC(0,0,0,1,0) PC(0,0,0,-1,0) PC(0,0,0,-1,0)  // d8(sp0) d7(sp1) d6 d5
    PD(4,2,2,0)
    PC(0,0,1,2,4) PC(0,0,0,-1,0)                                  // d4(sp2) d3
    PD(2,1,2,2)
    PC(0,0,1,-1,2)                                                // d2
    PD(1,0,0,0)
    PF(1) PF(2)
    PD(3,0,2,2)
    PF(3) PF(4)
    PD(6,1,2,0)
    PC(2,1,1,-1,6)                                                // d6' = gru(ns6, d7=sp1)
    PD(5,0,0,0)
    PF(5) PF(6)
    PD(7,0,2,0)
    PF(7) PF(8)
    PD(12,2,1,s16)
    PC(1,s13,1,3,4) PC(0,0,0,-1,0)                                // d12(sp3) d11
    PD(10,1,2,3)
    PC(0,0,1,-1,2)                                                // d10
    PD(9,0,0,0)
    PF(9) PF(10)
    PD(11,0,2,3)
    PF(11) PF(12)
    PD(14,1,1,s16)
    PC(1,s15,1,-1,6)                                              // d14
    PD(13,0,0,0)
    PF(13) PF(14)
    PD(15,0,1,s16)
    if(!last){ PF(15); PA(16); }
#undef PD
#undef PC
#undef PF
#undef PA
  }
  s.n=(short)i; return s;
}
__constant__ Sched g_sched = build_sched();

// ---------------- prep kernels (fp32 inputs -> bf16 internal) ----------------
__global__ void k_xt(const float* __restrict__ a, bf16* __restrict__ xT){
  int b=blockIdx.x, t=threadIdx.x;
  int wgi=b>>4, r=b&15;
  bf16* dst = xT + (((size_t)wgi*256 + t)*16 + r)*96;
  const float* ap = a + (size_t)b*64*256*3;
  for (int c=0;c<64;++c) dst[c] = __float2bfloat16(ap[((size_t)c*256+t)*3]);
  dst[64] = __float2bfloat16(ap[(size_t)t*3 + 2]);
  bf16 z = __float2bfloat16(0.f);
  for (int c=65;c<96;++c) dst[c]=z;
}

__global__ void k_obs(const float* __restrict__ a, float* __restrict__ out){
  int b=blockIdx.x, d=threadIdx.x; // 64 threads
  for (int kk=0;kk<16;++kk){ int t=kk*16;
    float v = (d<63)? a[(((size_t)b*64 + d+1)*256 + t)*3]
                    : a[((size_t)b*64*256 + t)*3 + 2];
    out[((size_t)b*64 + d)*256 + t] = v;
  }
}

__global__ void k_wt(const float* __restrict__ gru_U, const float* __restrict__ bgru_U,
                     const float* __restrict__ gru_W, const float* __restrict__ bgru_W,
                     bf16* Uf, bf16* Ub, bf16* Wf, bf16* Wb){
  int c=blockIdx.x, k=threadIdx.x; // 336 x 128
  int g=c/48, rm=c%48, e=rm/16, l=rm%16, j=16*g+l;
  bool val = j<100; int gc = val? (e*100+j) : 0;
  bf16 z = __float2bfloat16(0.f);
  Uf[(size_t)c*128+k] = (val&&k<100)? __float2bfloat16(gru_U[k*300+gc]) : z;
  Ub[(size_t)c*128+k] = (val&&k<100)? __float2bfloat16(bgru_U[k*300+gc]) : z;
  Wf[(size_t)c*128+k] = (val&&k>=1&&k<=64)? __float2bfloat16(gru_W[(k-1)*300+gc]) : z;
  Wb[(size_t)c*128+k] = (val&&k<65)? __float2bfloat16(bgru_W[k*300+gc]) : z;
}

// frag-linear copy of W tables (k=0..63, 2 slices): [tbl][strip st][e][s][lane]
__global__ void k_wbf(const bf16* __restrict__ Wb, const bf16* __restrict__ Wf,
                      uint4* __restrict__ dst){
  int bid=blockIdx.x;  // 84: 0..41 Wb, 42..83 Wf
  int l=threadIdx.x;   // 64
  int tbl=bid/42, r2=bid%42;
  int st=r2/6, rr=r2%6, e=rr/2, s=rr%2;
  int c=48*st+16*e+(l&15);
  int k=8*(l>>4)+32*s;
  const bf16* src = tbl? Wf : Wb;
  dst[bid*64+l] = *(const uint4*)(src + (size_t)c*128 + k);
}

__global__ void k_decw(const float* __restrict__ dec_W, bf16* dWt){
  int idx=blockIdx.x; int lvl=idx/64, n=idx%64; int k=threadIdx.x; // 256 blocks x 256 thr
  float v=0.f;
  if (n<50){
    if (k<100) v = dec_W[(lvl*200+k)*50+n];            // h rows 0..99
    else if (k>=128 && k<228) v = dec_W[(lvl*200+k-28)*50+n]; // hb rows 100..199
  }
  dWt[(size_t)idx*256+k] = __float2bfloat16(v);
}

__global__ void k_mw(const float* __restrict__ mean_W, bf16* MW){
  int idx=blockIdx.x; int lvl=idx/64, c=idx%64; int k=threadIdx.x; // 64
  MW[(size_t)idx*64+k] = (k<50)? __float2bfloat16(mean_W[(lvl*50+k)*64+c]) : __float2bfloat16(0.f);
}

__global__ void k_consts(const float* __restrict__ gru_b, const float* __restrict__ bgru_b,
                         const float* __restrict__ mean_b, const float* __restrict__ dec_b,
                         float* cst){
  int tid=threadIdx.x;
  for (int u=tid; u<336; u+=256){
    int c=u; int g=c/48, rm=c%48, e=rm/16, l=rm%16, j=16*g+l;
    float b0f=0,b1f=0,b0b=0,b1b=0;
    if (j<100){ int gc=e*100+j;
      b0f=gru_b[gc];  b1f=gru_b[300+gc];
      b0b=bgru_b[gc]; b1b=bgru_b[300+gc]; }
    cst[u]=b0f; cst[336+u]=b1f; cst[672+u]=b0b; cst[1008+u]=b1b;
  }
  if (tid<256){
    int lvl=tid/64, m=tid%64;
    cst[1344+tid]=mean_b[lvl*64+m];
    cst[1600+tid]=(m<50)? dec_b[lvl*50+m] : 0.f;
  }
}

__global__ void k_sz(uint4* p){
  p[(size_t)blockIdx.x*256 + threadIdx.x] = make_uint4(0u,0u,0u,0u);
}

// ---------------- specialized backward GRU cell ----------------
static __device__ __forceinline__ void bcell_step(
  int t, int bc, int sv,
  unsigned char* smem, const bf16* xT, unsigned char* sav8,
  int wg, int tid, int l15, int q, int wv, int ng,
  const bf16x8_t (&rUb)[2][3][4], const float (&W64b)[2][3],
  const float (&Bz0)[2][2], const float (&Br0)[2][2], const float (&Bn0)[2][2],
  const float (&Bz1)[2][2], const float (&Br1)[2][2], const float (&Bn1)[2][2],
  float (&hb_reg)[2][4], bf16x8_t (&pX)[2])
{
  const int lane = tid & 63;
  // issue next-X prefetch first (HBM latency hides under this op's compute)
  const bf16* px = xT + (((size_t)wg*256 + (t-1))*16 + l15)*96 + 8*q;
  bf16x8_t nX0 = *(const bf16x8_t*)(px);
  bf16x8_t nX1 = *(const bf16x8_t*)(px + 32);
  // aH fragments from s_hbk[bc]
  const bf16* hp = (const bf16*)(smem + 6784) + bc*1696 + l15*104 + 8*q;
  bf16x8_t aH[4];
  #pragma unroll
  for (int s=0;s<4;++s) aH[s] = *(const bf16x8_t*)(hp + 32*s);

  f32x4_t accB[2][3], accA[2][3];
  #pragma unroll
  for (int g2=0;g2<2;++g2)
    #pragma unroll
    for (int e=0;e<3;++e){ accB[g2][e]=(f32x4_t){0,0,0,0}; accA[g2][e]=(f32x4_t){0,0,0,0}; }

  // h @ Ub (registers)
  #pragma unroll
  for (int g2=0;g2<2;++g2){ if (g2<ng){
    #pragma unroll
    for (int e=0;e<3;++e){
      #pragma unroll
      for (int s=0;s<4;++s)
        accB[g2][e] = MFMA16(aH[s], rUb[g2][e][s], accB[g2][e]);
    } } }
  // X @ Wb (LDS frag-linear, k=0..63; mask row folded via W64b)
  #pragma unroll
  for (int g2=0;g2<2;++g2){ if (g2<ng){
    #pragma unroll
    for (int e=0;e<3;++e){
      #pragma unroll
      for (int s=0;s<2;++s){
        const bf16x8_t bw = *(const bf16x8_t*)(smem + WBF_LDS + ((((wv+4*g2)*3+e)*2+s)<<10) + lane*16);
        accA[g2][e] = MFMA16(pX[s], bw, accA[g2][e]);
      } } } }
  // save pre-update h_back (coalesced uint4)
  if (sv>=0 && tid<208){
    int r=tid/13, cc=tid-13*r;
    const uint4 v = *(const uint4*)(smem + 6784 + bc*3392 + r*208 + cc*16);
    *(uint4*)(sav8 + ((size_t)(wg*64+sv))*4096 + (size_t)r*256 + cc*16) = v;
  }
  // gate (bwd biases, fi=0)
  const bool mk = ((t&15)==0);
  bf16* wr = (bf16*)(smem + 6784) + (bc^1)*1696;
  #pragma unroll
  for (int g2=0;g2<2;++g2){ if (g2<ng){ int j=16*(wv+4*g2)+l15;
    if (j<100){
      float b0z=Bz0[g2][0], b0r=Br0[g2][0], b0n=Bn0[g2][0];
      float b1z=Bz1[g2][0], b1r=Br1[g2][0], b1n=Bn1[g2][0];
      #pragma unroll
      for (int i=0;i<4;++i){
        int r=4*q+i;
        float gz=accA[g2][0][i], gr=accA[g2][1][i], gn=accA[g2][2][i];
        if (mk){ gz+=W64b[g2][0]; gr+=W64b[g2][1]; gn+=W64b[g2][2]; }
        float hz=accB[g2][0][i], hr=accB[g2][1][i], hnv=accB[g2][2][i];
        float hold = hb_reg[g2][i];
        float az = gz+b0z+hz+b1z; az=fminf(fmaxf(az,-30.f),30.f);
        float ar = gr+b0r+hr+b1r; ar=fminf(fmaxf(ar,-30.f),30.f);
        float z  = 1.f/(1.f+__expf(-az));
        float rg = 1.f/(1.f+__expf(-ar));
        float an = gn+b0n+rg*(hnv+b1n); an=fminf(fmaxf(an,-15.f),15.f);
        float e2 = __expf(2.f*an);
        float nn = (e2-1.f)/(e2+1.f);
        float hnew = z*hold + (1.f-z)*nn;
        hb_reg[g2][i]=hnew;
        wr[r*104+j] = __float2bfloat16(hnew);
      }
    } } }
  pX[0]=nX0; pX[1]=nX1;
  BAR();
}

// ---------------- main persistent kernel: 32 WGs x 256 thr, 16 batch rows each ----------------
__launch_bounds__(256, 1)
__global__ void naomi_main(unsigned char* __restrict__ ws, float* __restrict__ out){
  const int tid=threadIdx.x, wg=blockIdx.x;
  const int lane=tid&63, wv=tid>>6;
  const int l15=lane&15, q=lane>>4;
  const int ng=(wv<3)?2:1;

  const bf16* xT = (const bf16*)(ws + XT_OFF);
  const bf16* Uf = (const bf16*)(ws + UF_OFF);
  const bf16* Ub = (const bf16*)(ws + UB_OFF);
  const bf16* Wf = (const bf16*)(ws + WF_OFF);
  const bf16* Wb = (const bf16*)(ws + WB_OFF);
  const bf16* dW = (const bf16*)(ws + DW_OFF);
  const bf16* MW = (const bf16*)(ws + MW_OFF);
  bf16* sav = (bf16*)(ws + SAV_OFF);
  unsigned char* sav8 = (unsigned char*)(ws + SAV_OFF);
  const float* cst = (const float*)(ws + CST_OFF);

  // LDS (149,040 B): s_h 2x[16][104] | s_hbk 2x[16][104] | s_dec [16][72]+pad |
  //   ring [8][16][120] | spl [4][16][128] | Wb frags 43008 | Wf frags 43008
  __shared__ alignas(16) unsigned char smem[149040];
  bf16* s_h    = (bf16*)(smem + 0);      // 6784 B (two 1696-elem buffers)
  bf16* s_hbk  = (bf16*)(smem + 6784);   // 6784 B
  bf16* s_dec  = (bf16*)(smem + 13568);  // 2352 B
  bf16* s_ring = (bf16*)(smem + 15920);  // 30720 B
  bf16* s_spl  = (bf16*)(smem + 46640);  // 16384 B

  // zero the state region once (h/hbk initial zeros; spl/s_dec pad NaN-safety)
  for (int u=tid; u<15756; u+=256) ((uint32_t*)smem)[u]=0u;
  // stage W frag tables (Wb then Wf) into permanent LDS
  { uint4* df=(uint4*)(smem+WBF_LDS); const uint4* sf=(const uint4*)(ws+WBF_OFF);
    for (int u=tid; u<5376; u+=256) df[u]=sf[u]; }

  // per-thread gate biases [g2][dir: 0=bwd 1=fwd]
  float Bz0[2][2],Br0[2][2],Bn0[2][2],Bz1[2][2],Br1[2][2],Bn1[2][2];
  #pragma unroll
  for (int g2=0; g2<2; ++g2){
    if (g2<ng){
      int cz=48*(wv+4*g2)+l15;
      Bz0[g2][1]=cst[cz];      Br0[g2][1]=cst[cz+16];      Bn0[g2][1]=cst[cz+32];
      Bz1[g2][1]=cst[336+cz];  Br1[g2][1]=cst[336+cz+16];  Bn1[g2][1]=cst[336+cz+32];
      Bz0[g2][0]=cst[672+cz];  Br0[g2][0]=cst[672+cz+16];  Bn0[g2][0]=cst[672+cz+32];
      Bz1[g2][0]=cst[1008+cz]; Br1[g2][0]=cst[1008+cz+16]; Bn1[g2][0]=cst[1008+cz+32];
    } else {
      Bz0[g2][0]=Bz0[g2][1]=Br0[g2][0]=Br0[g2][1]=Bn0[g2][0]=Bn0[g2][1]=0.f;
      Bz1[g2][0]=Bz1[g2][1]=Br1[g2][0]=Br1[g2][1]=Bn1[g2][0]=Bn1[g2][1]=0.f;
    }
  }
  const int c16 = 16*wv+l15;
  float mb_l[4], db_l[4];
  #pragma unroll
  for (int l=0;l<4;++l){ mb_l[l]=cst[1344+l*64+c16]; db_l[l]=cst[1600+l*64+c16]; }

  // Ub strips resident in registers (Uf deferred to after the bwd sweep)
  bf16x8_t rUf[2][3][4], rUb[2][3][4];
  #pragma unroll
  for (int g2=0; g2<2; ++g2){
    if (g2<ng){
      #pragma unroll
      for (int e=0;e<3;++e){ int c=48*(wv+4*g2)+16*e+l15;
        #pragma unroll
        for (int s=0;s<4;++s)
          rUb[g2][e][s] = *(const bf16x8_t*)(Ub + (size_t)c*128 + 8*q + 32*s);
      }
    }
  }
  // constant-channel weights (row 64 of each W strip), folded out of the X-GEMMs
  float W64b[2][3], W64f[2][3];
  #pragma unroll
  for (int g2=0; g2<2; ++g2){
    if (g2<ng){
      #pragma unroll
      for (int e=0;e<3;++e){ int c=48*(wv+4*g2)+16*e+l15;
        W64b[g2][e] = __bfloat162float(Wb[(size_t)c*128 + 64]);
        W64f[g2][e] = __bfloat162float(Wf[(size_t)c*128 + 64]); }
    } else {
      W64b[g2][0]=W64b[g2][1]=W64b[g2][2]=0.f;
      W64f[g2][0]=W64f[g2][1]=W64f[g2][2]=0.f;
    }
  }
  __syncthreads();

  // fp32 master state in registers
  float h_reg[2][4], hb_reg[2][4];
  #pragma unroll
  for (int g2=0;g2<2;++g2){
    #pragma unroll
    for (int i=0;i<4;++i){ h_reg[g2][i]=0.f; hb_reg[g2][i]=0.f; }
  }
  int hcur=0, bcur=0;

  // prefetch registers
  bf16x8_t pX[2], pHB[4];
  float pHold[2][4];
  #pragma unroll
  for (int g2=0;g2<2;++g2){
    #pragma unroll
    for (int i=0;i<4;++i) pHold[g2][i]=0.f;
  }
  { // prologue: prefetch X(t=255), 2 slices
    const bf16* px = xT + (((size_t)wg*256 + 255)*16 + l15)*96 + 8*q;
    pX[0] = *(const bf16x8_t*)(px);
    pX[1] = *(const bf16x8_t*)(px + 32);
  }

  // ================= specialized backward sweep: t = 255 .. 1 =================
  bcell_step(255, 0, 63, smem, xT, sav8, wg, tid, l15, q, wv, ng,
             rUb, W64b, Bz0, Br0, Bn0, Bz1, Br1, Bn1, hb_reg, pX);
  for (int t=254; t>=2; t-=2){
    int m=t&15;
    int sv1 = (m==8)? ((t>>4)<<2) : (m==12)? (((t>>4)<<2)+1) : (m==14)? (((t>>4)<<2)+2) : -1;
    bcell_step(t, 1, sv1, smem, xT, sav8, wg, tid, l15, q, wv, ng,
               rUb, W64b, Bz0, Br0, Bn0, Bz1, Br1, Bn1, hb_reg, pX);
    int sv2 = (((t-1)&15)==15)? ((((t-1)>>4)<<2)+3) : -1;
    bcell_step(t-1, 0, sv2, smem, xT, sav8, wg, tid, l15, q, wv, ng,
               rUb, W64b, Bz0, Br0, Bn0, Bz1, Br1, Bn1, hb_reg, pX);
  }
  bcur = 1;   // parity after 255 steps

  // ================= bwd -> fwd transition =================
  // load Uf strips now (pX already holds X(t=0) slices 0,1 from the last bcell prefetch)
  #pragma unroll
  for (int g2=0; g2<2; ++g2){
    if (g2<ng){
      #pragma unroll
      for (int e=0;e<3;++e){ int c=48*(wv+4*g2)+16*e+l15;
        #pragma unroll
        for (int s=0;s<4;++s)
          rUf[g2][e][s] = *(const bf16x8_t*)(Uf + (size_t)c*128 + 8*q + 32*s);
      }
    }
  }
  __syncthreads();   // full drain: sav stores visible before fwd sav reads

  // ================= forward phase op-machine (ops 255..n-1) =================
  const int nops = g_sched.n;
  for (int io=255; io<nops; ++io){
    const Op op = g_sched.ops[io];
    const Op on = g_sched.ops[(io+1<nops)? io+1 : io];
    if (op.type != 3){
      const bool fwd = (op.type==1)||(op.type==2);
      const bool hasX = (op.type==1)||(op.type==2)||(op.type==4 && op.gisrc==1);
      // ---- A fragments (h operand) ----
      bf16x8_t aH[4];
      if (!fwd && op.hsrc==1){
        #pragma unroll
        for (int s=0;s<4;++s) aH[s]=pHB[s];
      } else if (!fwd && op.hsrc==2){
        const bf16* hp = s_spl + (size_t)op.srcidx*2048 + l15*128 + 8*q;
        #pragma unroll
        for (int s=0;s<4;++s) aH[s] = *(const bf16x8_t*)(hp + 32*s);
      } else {
        const bf16* hp = (fwd? s_h + hcur*1696 : s_hbk + bcur*1696) + l15*104 + 8*q;
        #pragma unroll
        for (int s=0;s<4;++s) aH[s] = *(const bf16x8_t*)(hp + 32*s);
      }
      // ---- X fragments (2 slices; constant channel folded) ----
      bf16x8_t aX[2];
      if (op.type==1){
        aX[0]=pX[0]; aX[1]=pX[1];
      } else if (op.type==2){
        const bf16* xp = s_ring + (size_t)((op.t&7)*16 + l15)*120 + 8*q;
        aX[0] = *(const bf16x8_t*)(xp);
        aX[1] = *(const bf16x8_t*)(xp + 32);
      } else if (op.type==4 && op.gisrc==1){
        const bf16* xp = s_ring + (size_t)(op.t*16 + l15)*120 + 8*q;
        aX[0] = *(const bf16x8_t*)(xp);
        aX[1] = *(const bf16x8_t*)(xp + 32);
      }
      // ---- MFMA: U from registers, X@W from LDS frags ----
      f32x4_t accB[2][3], accA[2][3];
      #pragma unroll
      for (int g2=0;g2<2;++g2)
        #pragma unroll
        for (int e=0;e<3;++e){ accB[g2][e]=(f32x4_t){0,0,0,0}; accA[g2][e]=(f32x4_t){0,0,0,0}; }
      if (fwd){
        #pragma unroll
        for (int g2=0;g2<2;++g2){ if (g2<ng){
          #pragma unroll
          for (int e=0;e<3;++e){
            #pragma unroll
            for (int s=0;s<4;++s)
              accB[g2][e] = MFMA16(aH[s], rUf[g2][e][s], accB[g2][e]);
          } } }
      } else {
        #pragma unroll
        for (int g2=0;g2<2;++g2){ if (g2<ng){
          #pragma unroll
          for (int e=0;e<3;++e){
            #pragma unroll
            for (int s=0;s<4;++s)
              accB[g2][e] = MFMA16(aH[s], rUb[g2][e][s], accB[g2][e]);
          } } }
      }
      if (hasX){
        const unsigned char* fb = smem + (fwd? WFF_LDS : WBF_LDS);
        #pragma unroll
        for (int g2=0;g2<2;++g2){ if (g2<ng){
          #pragma unroll
          for (int e=0;e<3;++e){
            #pragma unroll
            for (int s=0;s<2;++s){
              const bf16x8_t bw = *(const bf16x8_t*)(fb + ((((wv+4*g2)*3+e)*2+s)<<10) + lane*16);
              accA[g2][e] = MFMA16(aX[s], bw, accA[g2][e]);
            } } } }
      }
      // ---- prefetch for op[io+1] ----
      if (on.type==1){
        const bf16* px = xT + (((size_t)wg*256 + on.t)*16 + l15)*96 + 8*q;
        pX[0] = *(const bf16x8_t*)(px);
        pX[1] = *(const bf16x8_t*)(px + 32);
      }
      if ((on.type==3 || on.type==4) && on.hsrc==1){
        const bf16* ps = sav + (size_t)(wg*64+on.srcidx)*2048 + l15*128 + 8*q;
        #pragma unroll
        for (int s=0;s<4;++s) pHB[s] = *(const bf16x8_t*)(ps + 32*s);
      }
      if (on.type==4 && on.hsrc==1){
        const bf16* ph = sav + (size_t)(wg*64+on.srcidx)*2048;
        #pragma unroll
        for (int g2=0;g2<2;++g2){ if (g2<ng){ int j=16*(wv+4*g2)+l15;
          if (j<100){
            #pragma unroll
            for (int i=0;i<4;++i) pHold[g2][i] = __bfloat162float(ph[(4*q+i)*128 + j]);
          } } }
      }
      // ---- gate stage (lane-local; holds in registers) ----
      bf16* wr = fwd? (s_h + (hcur^1)*1696) : (s_hbk + (bcur^1)*1696);
      const int fi = fwd?1:0;
      #pragma unroll
      for (int g2=0;g2<2;++g2){ if (g2<ng){ int j=16*(wv+4*g2)+l15;
        if (j<100){
          float b0z=Bz0[g2][fi], b0r=Br0[g2][fi], b0n=Bn0[g2][fi];
          float b1z=Bz1[g2][fi], b1r=Br1[g2][fi], b1n=Bn1[g2][fi];
          float wz=0.f, wrr=0.f, wn=0.f;
          if (hasX){
            if (fwd){ wz=W64f[g2][0]; wrr=W64f[g2][1]; wn=W64f[g2][2]; }
            else    { wz=W64b[g2][0]; wrr=W64b[g2][1]; wn=W64b[g2][2]; }
          }
          #pragma unroll
          for (int i=0;i<4;++i){
            int r=4*q+i;
            float gz=0.f, gr=0.f, gn=0.f;
            if (hasX){ gz=accA[g2][0][i]+wz; gr=accA[g2][1][i]+wrr; gn=accA[g2][2][i]+wn; }
            float hz=accB[g2][0][i], hr=accB[g2][1][i], hnv=accB[g2][2][i];
            float hold;
            if (fwd) hold = h_reg[g2][i];
            else if (op.hsrc==0) hold = hb_reg[g2][i];
            else if (op.hsrc==1) hold = pHold[g2][i];
            else hold = __bfloat162float(s_spl[(size_t)op.srcidx*2048 + r*128 + j]);
            float az = gz+b0z+hz+b1z; az=fminf(fmaxf(az,-30.f),30.f);
            float ar = gr+b0r+hr+b1r; ar=fminf(fmaxf(ar,-30.f),30.f);
            float z  = 1.f/(1.f+__expf(-az));
            float rg = 1.f/(1.f+__expf(-ar));
            float an = gn+b0n+rg*(hnv+b1n); an=fminf(fmaxf(an,-15.f),15.f);
            float e2 = __expf(2.f*an);
            float nn = (e2-1.f)/(e2+1.f);
            float hnew = z*hold + (1.f-z)*nn;
            if (fwd) h_reg[g2][i]=hnew; else hb_reg[g2][i]=hnew;
            wr[r*104+j] = __float2bfloat16(hnew);
            if (!fwd && op.type==4 && op.aux>=0)
              s_spl[(size_t)op.aux*2048 + r*128 + j] = __float2bfloat16(hnew);
          }
        } } }
      if (fwd) hcur^=1; else bcur^=1;
      BAR();
    } else {
      // ---- DEC: dec = relu([h,hb]@decW+db); mean = dec@meanW+mb -> out + ns ring ----
      const int lvl=op.lvl, t=op.t, slot=t&7;
      // hoist gemm2 B-frag loads: latency hides under gemm1 + BAR (lgkm-only barrier)
      const bf16* bpM = MW + ((size_t)(lvl*64 + c16))*64 + 8*q;
      const bf16x8_t mw0 = *(const bf16x8_t*)(bpM);
      const bf16x8_t mw1 = *(const bf16x8_t*)(bpM + 32);
      bf16x8_t aG[8];
      { const bf16* hp = s_h + hcur*1696 + l15*104 + 8*q;
        #pragma unroll
        for (int s=0;s<4;++s) aG[s] = *(const bf16x8_t*)(hp + 32*s); }
      if (op.hsrc==1){
        #pragma unroll
        for (int s=0;s<4;++s) aG[4+s]=pHB[s];
      } else if (op.hsrc==2){
        const bf16* hp = s_spl + (size_t)op.srcidx*2048 + l15*128 + 8*q;
        #pragma unroll
        for (int s=0;s<4;++s) aG[4+s] = *(const bf16x8_t*)(hp + 32*s);
      } else {
        const bf16* hp = s_hbk + bcur*1696 + l15*104 + 8*q;
        #pragma unroll
        for (int s=0;s<4;++s) aG[4+s] = *(const bf16x8_t*)(hp + 32*s);
      }
      // gemm1: [16,256] x [256 -> 64 cols]; wave wv owns cols 16wv..16wv+15
      { const bf16* bp = dW + ((size_t)(lvl*64 + c16))*256 + 8*q;
        f32x4_t a1=(f32x4_t){0,0,0,0}, a2=(f32x4_t){0,0,0,0};
        #pragma unroll
        for (int s=0;s<8;s+=2){
          a1 = MFMA16(aG[s],   *(const bf16x8_t*)(bp+32*s),    a1);
          a2 = MFMA16(aG[s+1], *(const bf16x8_t*)(bp+32*(s+1)), a2);
        }
        // prefetch for op[io+1]
        if (on.type==1){
          const bf16* px = xT + (((size_t)wg*256 + on.t)*16 + l15)*96 + 8*q;
          pX[0] = *(const bf16x8_t*)(px);
          pX[1] = *(const bf16x8_t*)(px + 32);
        }
        if ((on.type==3 || on.type==4) && on.hsrc==1){
          const bf16* ps = sav + (size_t)(wg*64+on.srcidx)*2048 + l15*128 + 8*q;
          #pragma unroll
          for (int s=0;s<4;++s) pHB[s] = *(const bf16x8_t*)(ps + 32*s);
        }
        if (on.type==4 && on.hsrc==1){
          const bf16* ph = sav + (size_t)(wg*64+on.srcidx)*2048;
          #pragma unroll
          for (int g2=0;g2<2;++g2){ if (g2<ng){ int j=16*(wv+4*g2)+l15;
            if (j<100){
              #pragma unroll
              for (int i=0;i<4;++i) pHold[g2][i] = __bfloat162float(ph[(4*q+i)*128 + j]);
            } } }
        }
        float db = db_l[lvl];
        #pragma unroll
        for (int i=0;i<4;++i){ float v=fmaxf(a1[i]+a2[i]+db,0.f); s_dec[(4*q+i)*72 + c16]=__float2bfloat16(v); }
      }
      BAR();
      // gemm2: A=dec [16,64], B=mean_W^T strip -> out + ring ns
      bf16x8_t aD[2];
      #pragma unroll
      for (int s=0;s<2;++s) aD[s] = *(const bf16x8_t*)(s_dec + l15*72 + 8*q + 32*s);
      { f32x4_t am=(f32x4_t){0,0,0,0};
        am = MFMA16(aD[0], mw0, am);
        am = MFMA16(aD[1], mw1, am);
        float mb = mb_l[lvl];
        #pragma unroll
        for (int i=0;i<4;++i){ int r=4*q+i; size_t b=(size_t)wg*16+r;
          float m = am[i]+mb;
          s_ring[(size_t)(slot*16 + r)*120 + c16] = __float2bfloat16(m);
          if (c16>=1) out[(b*64 + (c16-1))*256 + t] = m;
          else        out[(b*64 + 63)*256 + t]      = 1.0f;
        } }
      BAR();
    }
  }
}

// ---------------- launch ----------------
extern "C" void kernel_launch(void* const* d_in, const int* in_sizes, int n_in,
                              void* d_out, int out_size, void* d_ws, size_t ws_size,
                              hipStream_t stream){
  (void)out_size;
  const float *a=nullptr,*gru_W=nullptr,*gru_U=nullptr,*gru_b=nullptr,*bgru_W=nullptr,
              *bgru_U=nullptr,*bgru_b=nullptr,*dec_W=nullptr,*dec_b=nullptr,
              *mean_W=nullptr,*mean_b=nullptr;
  int nU=0, nb6=0;
  for (int i=0;i<n_in;++i){
    const float* p=(const float*)d_in[i]; int s=in_sizes[i];
    if      (s==25165824) a=p;
    else if (s==19200)    gru_W=p;
    else if (s==19500)    bgru_W=p;
    else if (s==30000)    { if(nU++==0) gru_U=p; else bgru_U=p; }
    else if (s==600)      { if(nb6++==0) gru_b=p; else bgru_b=p; }
    else if (s==40000)    dec_W=p;
    else if (s==200)      dec_b=p;
    else if (s==12800)    mean_W=p;
    else if (s==256)      mean_b=p;
  }
  if (!a||!gru_W||!gru_U||!gru_b||!bgru_W||!bgru_U||!bgru_b||!dec_W||!dec_b||!mean_W||!mean_b){
    a=(const float*)d_in[0]; gru_W=(const float*)d_in[1]; gru_U=(const float*)d_in[2];
    gru_b=(const float*)d_in[3]; bgru_W=(const float*)d_in[4]; bgru_U=(const float*)d_in[5];
    bgru_b=(const float*)d_in[6]; dec_W=(const float*)d_in[7]; dec_b=(const float*)d_in[8];
    mean_W=(const float*)d_in[9]; mean_b=(const float*)d_in[10];
  }
  unsigned char* ws = (unsigned char*)d_ws;
  float* out = (float*)d_out;

  k_obs  <<<512,  64, 0, stream>>>(a, out);
  if (ws_size < WS_NEED) return;

  k_sz   <<<2048, 256, 0, stream>>>((uint4*)(ws+SAV_OFF));
  k_xt   <<<512, 256, 0, stream>>>(a, (bf16*)(ws+XT_OFF));
  k_wt   <<<336, 128, 0, stream>>>(gru_U, bgru_U, gru_W, bgru_W,
                                   (bf16*)(ws+UF_OFF), (bf16*)(ws+UB_OFF),
                                   (bf16*)(ws+WF_OFF), (bf16*)(ws+WB_OFF));
  k_wbf  <<<84,   64, 0, stream>>>((const bf16*)(ws+WB_OFF), (const bf16*)(ws+WF_OFF),
                                   (uint4*)(ws+WBF_OFF));
  k_decw <<<256, 256, 0, stream>>>(dec_W, (bf16*)(ws+DW_OFF));
  k_mw   <<<256,  64, 0, stream>>>(mean_W, (bf16*)(ws+MW_OFF));
  k_consts<<<1,  256, 0, stream>>>(gru_b, bgru_b, mean_b, dec_b, (float*)(ws+CST_OFF));
  naomi_main<<<32, 256, 0, stream>>>(ws, out);
}

// Round 7
// 1772.836 us; speedup vs baseline: 2.6836x; 1.5312x over previous
//
#include <hip/hip_runtime.h>
#include <hip/hip_bf16.h>
#include <cstdint>
#include <cstddef>

using bf16 = __hip_bfloat16;
typedef __attribute__((ext_vector_type(8))) short   bf16x8_t;  // 8 bf16 (4 VGPRs)
typedef __attribute__((ext_vector_type(4))) float   f32x4_t;   // mfma accumulator

// ---------------- workspace byte offsets ----------------
#define XT_OFF   ((size_t)0)            // [32 wg][256 t][16 r][96] bf16 (coalesced per-wave X)
#define UF_OFF   ((size_t)25165824)     // [336][128] bf16 gate-ordered U strips (fwd)
#define UB_OFF   ((size_t)25251840)     // (bwd)
#define WF_OFF   ((size_t)25337856)     // fwd W shifted: row k -> gru_W[k-1], k=1..64 (K=128 strip)
#define WB_OFF   ((size_t)25423872)     // bwd W: row k -> bgru_W[k], k=0..64
#define DW_OFF   ((size_t)25509888)     // dec_W strips [4][64][256] bf16
#define MW_OFF   ((size_t)25640960)     // mean_W^T strips [4][64][64] bf16
#define SAV_OFF  ((size_t)25673728)     // saved h_back [32 wg][64 slot][16*128] bf16 (8,388,608 B)
#define CST_OFF  ((size_t)34062336)     // fp32: bf0,bf1,bb0,bb1[336 ea], mb[256], db[256]
#define WBF_OFF  ((size_t)34069760)     // frag-linear W tables: [Wb 43008 B][Wf 43008 B]
#define WS_NEED  ((size_t)34155776)

// LDS frag-table bases (permanent)
#define WBF_LDS  63024
#define WFF_LDS  106032
// total LDS = 63024 + 86016 = 149,040 B (<= 160 KiB, 1 WG/CU)

#define MFMA16(a,b,c) __builtin_amdgcn_mfma_f32_16x16x32_bf16((a),(b),(c),0,0,0)

// counted barrier: drain LDS only; global loads/stores stay in flight across it.
#define BAR()    asm volatile("s_waitcnt lgkmcnt(0)\n\ts_barrier" ::: "memory")

// ---------------- prep kernels (fp32 inputs -> bf16 internal) ----------------
__global__ void k_xt(const float* __restrict__ a, bf16* __restrict__ xT){
  int b=blockIdx.x, t=threadIdx.x;
  int wgi=b>>4, r=b&15;
  bf16* dst = xT + (((size_t)wgi*256 + t)*16 + r)*96;
  const float* ap = a + (size_t)b*64*256*3;
  for (int c=0;c<64;++c) dst[c] = __float2bfloat16(ap[((size_t)c*256+t)*3]);
  dst[64] = __float2bfloat16(ap[(size_t)t*3 + 2]);
  bf16 z = __float2bfloat16(0.f);
  for (int c=65;c<96;++c) dst[c]=z;
}

__global__ void k_obs(const float* __restrict__ a, float* __restrict__ out){
  int b=blockIdx.x, d=threadIdx.x; // 64 threads
  for (int kk=0;kk<16;++kk){ int t=kk*16;
    float v = (d<63)? a[(((size_t)b*64 + d+1)*256 + t)*3]
                    : a[((size_t)b*64*256 + t)*3 + 2];
    out[((size_t)b*64 + d)*256 + t] = v;
  }
}

__global__ void k_wt(const float* __restrict__ gru_U, const float* __restrict__ bgru_U,
                     const float* __restrict__ gru_W, const float* __restrict__ bgru_W,
                     bf16* Uf, bf16* Ub, bf16* Wf, bf16* Wb){
  int c=blockIdx.x, k=threadIdx.x; // 336 x 128
  int g=c/48, rm=c%48, e=rm/16, l=rm%16, j=16*g+l;
  bool val = j<100; int gc = val? (e*100+j) : 0;
  bf16 z = __float2bfloat16(0.f);
  Uf[(size_t)c*128+k] = (val&&k<100)? __float2bfloat16(gru_U[k*300+gc]) : z;
  Ub[(size_t)c*128+k] = (val&&k<100)? __float2bfloat16(bgru_U[k*300+gc]) : z;
  Wf[(size_t)c*128+k] = (val&&k>=1&&k<=64)? __float2bfloat16(gru_W[(k-1)*300+gc]) : z;
  Wb[(size_t)c*128+k] = (val&&k<65)? __float2bfloat16(bgru_W[k*300+gc]) : z;
}

// frag-linear copy of W tables (k=0..63, 2 slices): [tbl][strip st][e][s][lane]
__global__ void k_wbf(const bf16* __restrict__ Wb, const bf16* __restrict__ Wf,
                      uint4* __restrict__ dst){
  int bid=blockIdx.x;  // 84: 0..41 Wb, 42..83 Wf
  int l=threadIdx.x;   // 64
  int tbl=bid/42, r2=bid%42;
  int st=r2/6, rr=r2%6, e=rr/2, s=rr%2;
  int c=48*st+16*e+(l&15);
  int k=8*(l>>4)+32*s;
  const bf16* src = tbl? Wf : Wb;
  dst[bid*64+l] = *(const uint4*)(src + (size_t)c*128 + k);
}

__global__ void k_decw(const float* __restrict__ dec_W, bf16* dWt){
  int idx=blockIdx.x; int lvl=idx/64, n=idx%64; int k=threadIdx.x; // 256 blocks x 256 thr
  float v=0.f;
  if (n<50){
    if (k<100) v = dec_W[(lvl*200+k)*50+n];            // h rows 0..99
    else if (k>=128 && k<228) v = dec_W[(lvl*200+k-28)*50+n]; // hb rows 100..199
  }
  dWt[(size_t)idx*256+k] = __float2bfloat16(v);
}

__global__ void k_mw(const float* __restrict__ mean_W, bf16* MW){
  int idx=blockIdx.x; int lvl=idx/64, c=idx%64; int k=threadIdx.x; // 64
  MW[(size_t)idx*64+k] = (k<50)? __float2bfloat16(mean_W[(lvl*50+k)*64+c]) : __float2bfloat16(0.f);
}

__global__ void k_consts(const float* __restrict__ gru_b, const float* __restrict__ bgru_b,
                         const float* __restrict__ mean_b, const float* __restrict__ dec_b,
                         float* cst){
  int tid=threadIdx.x;
  for (int u=tid; u<336; u+=256){
    int c=u; int g=c/48, rm=c%48, e=rm/16, l=rm%16, j=16*g+l;
    float b0f=0,b1f=0,b0b=0,b1b=0;
    if (j<100){ int gc=e*100+j;
      b0f=gru_b[gc];  b1f=gru_b[300+gc];
      b0b=bgru_b[gc]; b1b=bgru_b[300+gc]; }
    cst[u]=b0f; cst[336+u]=b1f; cst[672+u]=b0b; cst[1008+u]=b1b;
  }
  if (tid<256){
    int lvl=tid/64, m=tid%64;
    cst[1344+tid]=mean_b[lvl*64+m];
    cst[1600+tid]=(m<50)? dec_b[lvl*50+m] : 0.f;
  }
}

__global__ void k_sz(uint4* p){
  p[(size_t)blockIdx.x*256 + threadIdx.x] = make_uint4(0u,0u,0u,0u);
}

// ---------------- specialized backward GRU cell (unchanged from R6) ----------------
static __device__ __forceinline__ void bcell_step(
  int t, int bc, int sv,
  unsigned char* smem, const bf16* xT, unsigned char* sav8,
  int wg, int tid, int l15, int q, int wv, int ng,
  const bf16x8_t (&rUb)[2][3][4], const float (&W64b)[2][3],
  const float (&Bz0)[2][2], const float (&Br0)[2][2], const float (&Bn0)[2][2],
  const float (&Bz1)[2][2], const float (&Br1)[2][2], const float (&Bn1)[2][2],
  float (&hb_reg)[2][4], bf16x8_t (&pX)[2])
{
  const int lane = tid & 63;
  const bf16* px = xT + (((size_t)wg*256 + (t-1))*16 + l15)*96 + 8*q;
  bf16x8_t nX0 = *(const bf16x8_t*)(px);
  bf16x8_t nX1 = *(const bf16x8_t*)(px + 32);
  const bf16* hp = (const bf16*)(smem + 6784) + bc*1696 + l15*104 + 8*q;
  bf16x8_t aH[4];
  #pragma unroll
  for (int s=0;s<4;++s) aH[s] = *(const bf16x8_t*)(hp + 32*s);

  f32x4_t accB[2][3], accA[2][3];
  #pragma unroll
  for (int g2=0;g2<2;++g2)
    #pragma unroll
    for (int e=0;e<3;++e){ accB[g2][e]=(f32x4_t){0,0,0,0}; accA[g2][e]=(f32x4_t){0,0,0,0}; }

  #pragma unroll
  for (int g2=0;g2<2;++g2){ if (g2<ng){
    #pragma unroll
    for (int e=0;e<3;++e){
      #pragma unroll
      for (int s=0;s<4;++s)
        accB[g2][e] = MFMA16(aH[s], rUb[g2][e][s], accB[g2][e]);
    } } }
  #pragma unroll
  for (int g2=0;g2<2;++g2){ if (g2<ng){
    #pragma unroll
    for (int e=0;e<3;++e){
      #pragma unroll
      for (int s=0;s<2;++s){
        const bf16x8_t bw = *(const bf16x8_t*)(smem + WBF_LDS + ((((wv+4*g2)*3+e)*2+s)<<10) + lane*16);
        accA[g2][e] = MFMA16(pX[s], bw, accA[g2][e]);
      } } } }
  if (sv>=0 && tid<208){
    int r=tid/13, cc=tid-13*r;
    const uint4 v = *(const uint4*)(smem + 6784 + bc*3392 + r*208 + cc*16);
    *(uint4*)(sav8 + ((size_t)(wg*64+sv))*4096 + (size_t)r*256 + cc*16) = v;
  }
  const bool mk = ((t&15)==0);
  bf16* wr = (bf16*)(smem + 6784) + (bc^1)*1696;
  #pragma unroll
  for (int g2=0;g2<2;++g2){ if (g2<ng){ int j=16*(wv+4*g2)+l15;
    if (j<100){
      float b0z=Bz0[g2][0], b0r=Br0[g2][0], b0n=Bn0[g2][0];
      float b1z=Bz1[g2][0], b1r=Br1[g2][0], b1n=Bn1[g2][0];
      #pragma unroll
      for (int i=0;i<4;++i){
        int r=4*q+i;
        float gz=accA[g2][0][i], gr=accA[g2][1][i], gn=accA[g2][2][i];
        if (mk){ gz+=W64b[g2][0]; gr+=W64b[g2][1]; gn+=W64b[g2][2]; }
        float hz=accB[g2][0][i], hr=accB[g2][1][i], hnv=accB[g2][2][i];
        float hold = hb_reg[g2][i];
        float az = gz+b0z+hz+b1z; az=fminf(fmaxf(az,-30.f),30.f);
        float ar = gr+b0r+hr+b1r; ar=fminf(fmaxf(ar,-30.f),30.f);
        float z  = 1.f/(1.f+__expf(-az));
        float rg = 1.f/(1.f+__expf(-ar));
        float an = gn+b0n+rg*(hnv+b1n); an=fminf(fmaxf(an,-15.f),15.f);
        float e2 = __expf(2.f*an);
        float nn = (e2-1.f)/(e2+1.f);
        float hnew = z*hold + (1.f-z)*nn;
        hb_reg[g2][i]=hnew;
        wr[r*104+j] = __float2bfloat16(hnew);
      }
    } } }
  pX[0]=nX0; pX[1]=nX1;
  BAR();
}

// ---------------- main persistent kernel: 32 WGs x 256 thr, 16 batch rows each ----------------
__launch_bounds__(256, 1)
__global__ void naomi_main(unsigned char* __restrict__ ws, float* __restrict__ out){
  const int tid=threadIdx.x, wg=blockIdx.x;
  const int lane=tid&63, wv=tid>>6;
  const int l15=lane&15, q=lane>>4;
  const int ng=(wv<3)?2:1;

  const bf16* xT = (const bf16*)(ws + XT_OFF);
  const bf16* Uf = (const bf16*)(ws + UF_OFF);
  const bf16* Ub = (const bf16*)(ws + UB_OFF);
  const bf16* Wf = (const bf16*)(ws + WF_OFF);
  const bf16* Wb = (const bf16*)(ws + WB_OFF);
  const bf16* dW = (const bf16*)(ws + DW_OFF);
  const bf16* MW = (const bf16*)(ws + MW_OFF);
  bf16* sav = (bf16*)(ws + SAV_OFF);
  unsigned char* sav8 = (unsigned char*)(ws + SAV_OFF);
  const float* cst = (const float*)(ws + CST_OFF);

  // LDS (149,040 B): s_h 2x[16][104] | s_hbk 2x[16][104] | s_dec [16][72]+pad |
  //   ring [8][16][120] | spl [4][16][128] | Wb frags 43008 | Wf frags 43008
  __shared__ alignas(16) unsigned char smem[149040];
  bf16* s_h    = (bf16*)(smem + 0);      // 6784 B (two 1696-elem buffers)
  bf16* s_hbk  = (bf16*)(smem + 6784);   // 6784 B
  bf16* s_dec  = (bf16*)(smem + 13568);  // 2352 B
  bf16* s_ring = (bf16*)(smem + 15920);  // 30720 B
  bf16* s_spl  = (bf16*)(smem + 46640);  // 16384 B

  for (int u=tid; u<15756; u+=256) ((uint32_t*)smem)[u]=0u;
  { uint4* df=(uint4*)(smem+WBF_LDS); const uint4* sf=(const uint4*)(ws+WBF_OFF);
    for (int u=tid; u<5376; u+=256) df[u]=sf[u]; }

  // per-thread gate biases [g2][dir: 0=bwd 1=fwd]
  float Bz0[2][2],Br0[2][2],Bn0[2][2],Bz1[2][2],Br1[2][2],Bn1[2][2];
  #pragma unroll
  for (int g2=0; g2<2; ++g2){
    if (g2<ng){
      int cz=48*(wv+4*g2)+l15;
      Bz0[g2][1]=cst[cz];      Br0[g2][1]=cst[cz+16];      Bn0[g2][1]=cst[cz+32];
      Bz1[g2][1]=cst[336+cz];  Br1[g2][1]=cst[336+cz+16];  Bn1[g2][1]=cst[336+cz+32];
      Bz0[g2][0]=cst[672+cz];  Br0[g2][0]=cst[672+cz+16];  Bn0[g2][0]=cst[672+cz+32];
      Bz1[g2][0]=cst[1008+cz]; Br1[g2][0]=cst[1008+cz+16]; Bn1[g2][0]=cst[1008+cz+32];
    } else {
      Bz0[g2][0]=Bz0[g2][1]=Br0[g2][0]=Br0[g2][1]=Bn0[g2][0]=Bn0[g2][1]=0.f;
      Bz1[g2][0]=Bz1[g2][1]=Br1[g2][0]=Br1[g2][1]=Bn1[g2][0]=Bn1[g2][1]=0.f;
    }
  }
  const int c16 = 16*wv+l15;
  float mb_l[4], db_l[4];
  #pragma unroll
  for (int l=0;l<4;++l){ mb_l[l]=cst[1344+l*64+c16]; db_l[l]=cst[1600+l*64+c16]; }

  bf16x8_t rUf[2][3][4], rUb[2][3][4];
  #pragma unroll
  for (int g2=0; g2<2; ++g2){
    if (g2<ng){
      #pragma unroll
      for (int e=0;e<3;++e){ int c=48*(wv+4*g2)+16*e+l15;
        #pragma unroll
        for (int s=0;s<4;++s)
          rUb[g2][e][s] = *(const bf16x8_t*)(Ub + (size_t)c*128 + 8*q + 32*s);
      }
    }
  }
  float W64b[2][3], W64f[2][3];
  #pragma unroll
  for (int g2=0; g2<2; ++g2){
    if (g2<ng){
      #pragma unroll
      for (int e=0;e<3;++e){ int c=48*(wv+4*g2)+16*e+l15;
        W64b[g2][e] = __bfloat162float(Wb[(size_t)c*128 + 64]);
        W64f[g2][e] = __bfloat162float(Wf[(size_t)c*128 + 64]); }
    } else {
      W64b[g2][0]=W64b[g2][1]=W64b[g2][2]=0.f;
      W64f[g2][0]=W64f[g2][1]=W64f[g2][2]=0.f;
    }
  }
  __syncthreads();

  float h_reg[2][4], hb_reg[2][4];
  #pragma unroll
  for (int g2=0;g2<2;++g2){
    #pragma unroll
    for (int i=0;i<4;++i){ h_reg[g2][i]=0.f; hb_reg[g2][i]=0.f; }
  }
  int hcur=0, bcur=0;

  bf16x8_t pX[2], pHB[4], rS16[4];
  float pHold[2][4];
  #pragma unroll
  for (int g2=0;g2<2;++g2){
    #pragma unroll
    for (int i=0;i<4;++i) pHold[g2][i]=0.f;
  }
  { const bf16* px = xT + (((size_t)wg*256 + 255)*16 + l15)*96 + 8*q;
    pX[0] = *(const bf16x8_t*)(px);
    pX[1] = *(const bf16x8_t*)(px + 32);
  }

  // ================= specialized backward sweep: t = 255 .. 1 =================
  bcell_step(255, 0, 63, smem, xT, sav8, wg, tid, l15, q, wv, ng,
             rUb, W64b, Bz0, Br0, Bn0, Bz1, Br1, Bn1, hb_reg, pX);
  for (int t=254; t>=2; t-=2){
    int m=t&15;
    int sv1 = (m==8)? ((t>>4)<<2) : (m==12)? (((t>>4)<<2)+1) : (m==14)? (((t>>4)<<2)+2) : -1;
    bcell_step(t, 1, sv1, smem, xT, sav8, wg, tid, l15, q, wv, ng,
               rUb, W64b, Bz0, Br0, Bn0, Bz1, Br1, Bn1, hb_reg, pX);
    int sv2 = (((t-1)&15)==15)? ((((t-1)>>4)<<2)+3) : -1;
    bcell_step(t-1, 0, sv2, smem, xT, sav8, wg, tid, l15, q, wv, ng,
               rUb, W64b, Bz0, Br0, Bn0, Bz1, Br1, Bn1, hb_reg, pX);
  }
  bcur = 1;   // parity after 255 steps

  // ================= bwd -> fwd transition =================
  #pragma unroll
  for (int g2=0; g2<2; ++g2){
    if (g2<ng){
      #pragma unroll
      for (int e=0;e<3;++e){ int c=48*(wv+4*g2)+16*e+l15;
        #pragma unroll
        for (int s=0;s<4;++s)
          rUf[g2][e][s] = *(const bf16x8_t*)(Uf + (size_t)c*128 + 8*q + 32*s);
      }
    }
  }
  __syncthreads();   // full drain: sav stores visible before fwd sav reads

  // ================= straight-line forward phase =================
  // --- op building blocks (branch-free; identical math to the R6 op-machine) ---
#define GRU_MATH() \
  float az=gz+b0z+hz+b1z; az=fminf(fmaxf(az,-30.f),30.f); \
  float ar=gr+b0r+hr+b1r; ar=fminf(fmaxf(ar,-30.f),30.f); \
  float z_=1.f/(1.f+__expf(-az)); float rg=1.f/(1.f+__expf(-ar)); \
  float an=gn+b0n+rg*(hnv+b1n); an=fminf(fmaxf(an,-15.f),15.f); \
  float e2=__expf(2.f*an); float nn=(e2-1.f)/(e2+1.f); \
  float hnew=z_*hold+(1.f-z_)*nn;

#define LOADH_SH() \
  { const bf16* hp_=s_h+hcur*1696+l15*104+8*q; \
    _Pragma("unroll") for(int s=0;s<4;++s) aH[s]=*(const bf16x8_t*)(hp_+32*s); }
#define LOADH_HBK() \
  { const bf16* hp_=s_hbk+bcur*1696+l15*104+8*q; \
    _Pragma("unroll") for(int s=0;s<4;++s) aH[s]=*(const bf16x8_t*)(hp_+32*s); }
#define LOADX_RING(RS) \
  bf16x8_t aX0,aX1; \
  { const bf16* xp_=s_ring+(size_t)((RS)*16+l15)*120+8*q; \
    aX0=*(const bf16x8_t*)(xp_); aX1=*(const bf16x8_t*)(xp_+32); }

#define MM_FWD() \
  f32x4_t accB[2][3], accA[2][3]; \
  _Pragma("unroll") for (int g2=0;g2<2;++g2){ _Pragma("unroll") for (int e=0;e<3;++e){ accB[g2][e]=(f32x4_t){0,0,0,0}; accA[g2][e]=(f32x4_t){0,0,0,0}; } } \
  _Pragma("unroll") for (int g2=0;g2<2;++g2){ if (g2<ng){ \
    _Pragma("unroll") for (int e=0;e<3;++e){ \
      _Pragma("unroll") for (int s=0;s<4;++s) accB[g2][e]=MFMA16(aH[s],rUf[g2][e][s],accB[g2][e]); \
      const unsigned char* fb_=smem+WFF_LDS+((((wv+4*g2)*3+e)*2)<<10)+lane*16; \
      accA[g2][e]=MFMA16(aX0,*(const bf16x8_t*)(fb_),accA[g2][e]); \
      accA[g2][e]=MFMA16(aX1,*(const bf16x8_t*)(fb_+1024),accA[g2][e]); } } }

#define MM_BWD_X() \
  f32x4_t accB[2][3], accA[2][3]; \
  _Pragma("unroll") for (int g2=0;g2<2;++g2){ _Pragma("unroll") for (int e=0;e<3;++e){ accB[g2][e]=(f32x4_t){0,0,0,0}; accA[g2][e]=(f32x4_t){0,0,0,0}; } } \
  _Pragma("unroll") for (int g2=0;g2<2;++g2){ if (g2<ng){ \
    _Pragma("unroll") for (int e=0;e<3;++e){ \
      _Pragma("unroll") for (int s=0;s<4;++s) accB[g2][e]=MFMA16(aH[s],rUb[g2][e][s],accB[g2][e]); \
      const unsigned char* fb_=smem+WBF_LDS+((((wv+4*g2)*3+e)*2)<<10)+lane*16; \
      accA[g2][e]=MFMA16(aX0,*(const bf16x8_t*)(fb_),accA[g2][e]); \
      accA[g2][e]=MFMA16(aX1,*(const bf16x8_t*)(fb_+1024),accA[g2][e]); } } }

#define MM_BWD_NOX() \
  f32x4_t accB[2][3]; \
  _Pragma("unroll") for (int g2=0;g2<2;++g2){ _Pragma("unroll") for (int e=0;e<3;++e) accB[g2][e]=(f32x4_t){0,0,0,0}; } \
  _Pragma("unroll") for (int g2=0;g2<2;++g2){ if (g2<ng){ \
    _Pragma("unroll") for (int e=0;e<3;++e){ \
      _Pragma("unroll") for (int s=0;s<4;++s) accB[g2][e]=MFMA16(aH[s],rUb[g2][e][s],accB[g2][e]); } } }

#define FWD_GATE() \
  { bf16* wr_=s_h+(hcur^1)*1696; \
    _Pragma("unroll") for (int g2=0;g2<2;++g2){ if (g2<ng){ const int j=16*(wv+4*g2)+l15; \
      if (j<100){ \
        const float b0z=Bz0[g2][1],b0r=Br0[g2][1],b0n=Bn0[g2][1],b1z=Bz1[g2][1],b1r=Br1[g2][1],b1n=Bn1[g2][1]; \
        _Pragma("unroll") for (int i=0;i<4;++i){ const int r_=4*q+i; \
          const float gz=accA[g2][0][i]+W64f[g2][0], gr=accA[g2][1][i]+W64f[g2][1], gn=accA[g2][2][i]+W64f[g2][2]; \
          const float hz=accB[g2][0][i],hr=accB[g2][1][i],hnv=accB[g2][2][i]; \
          const float hold=h_reg[g2][i]; \
          GRU_MATH() \
          h_reg[g2][i]=hnew; wr_[r_*104+j]=__float2bfloat16(hnew); } } } } \
    hcur^=1; BAR(); }

#define CH_GATE_X(HOLDE, SP) \
  { bf16* wr_=s_hbk+(bcur^1)*1696; \
    _Pragma("unroll") for (int g2=0;g2<2;++g2){ if (g2<ng){ const int j=16*(wv+4*g2)+l15; \
      if (j<100){ \
        const float b0z=Bz0[g2][0],b0r=Br0[g2][0],b0n=Bn0[g2][0],b1z=Bz1[g2][0],b1r=Br1[g2][0],b1n=Bn1[g2][0]; \
        _Pragma("unroll") for (int i=0;i<4;++i){ const int r_=4*q+i; \
          const float gz=accA[g2][0][i]+W64b[g2][0], gr=accA[g2][1][i]+W64b[g2][1], gn=accA[g2][2][i]+W64b[g2][2]; \
          const float hz=accB[g2][0][i],hr=accB[g2][1][i],hnv=accB[g2][2][i]; \
          const float hold=(HOLDE); \
          GRU_MATH() \
          hb_reg[g2][i]=hnew; wr_[r_*104+j]=__float2bfloat16(hnew); \
          if ((SP)>=0) s_spl[(size_t)(SP)*2048+r_*128+j]=__float2bfloat16(hnew); } } } } \
    bcur^=1; BAR(); }

#define CH_GATE_NOX(HOLDE, SP) \
  { bf16* wr_=s_hbk+(bcur^1)*1696; \
    _Pragma("unroll") for (int g2=0;g2<2;++g2){ if (g2<ng){ const int j=16*(wv+4*g2)+l15; \
      if (j<100){ \
        const float b0z=Bz0[g2][0],b0r=Br0[g2][0],b0n=Bn0[g2][0],b1z=Bz1[g2][0],b1r=Br1[g2][0],b1n=Bn1[g2][0]; \
        _Pragma("unroll") for (int i=0;i<4;++i){ const int r_=4*q+i; \
          const float gz=0.f, gr=0.f, gn=0.f; \
          const float hz=accB[g2][0][i],hr=accB[g2][1][i],hnv=accB[g2][2][i]; \
          const float hold=(HOLDE); \
          GRU_MATH() \
          hb_reg[g2][i]=hnew; wr_[r_*104+j]=__float2bfloat16(hnew); \
          if ((SP)>=0) s_spl[(size_t)(SP)*2048+r_*128+j]=__float2bfloat16(hnew); } } } } \
    bcur^=1; BAR(); }

#define FF_OP(RS)       { bf16x8_t aH[4]; LOADH_SH()  LOADX_RING(RS) MM_FWD()   FWD_GATE() }
#define FA_OP()         { bf16x8_t aH[4]; LOADH_SH()  bf16x8_t aX0=pX[0],aX1=pX[1]; MM_FWD() FWD_GATE() }
#define CH_CUR(SP)      { bf16x8_t aH[4]; LOADH_HBK() MM_BWD_NOX() CH_GATE_NOX(hb_reg[g2][i], SP) }
#define CH_CURX(RS,SP)  { bf16x8_t aH[4]; LOADH_HBK() LOADX_RING(RS) MM_BWD_X() CH_GATE_X(hb_reg[g2][i], SP) }
#define CH_SAVX(RS,SP)  { bf16x8_t aH[4]; _Pragma("unroll") for(int s=0;s<4;++s) aH[s]=pHB[s]; \
                          LOADX_RING(RS) MM_BWD_X() CH_GATE_X(pHold[g2][i], SP) }
#define CH_SPLX(SI,RS,SP) { bf16x8_t aH[4]; \
                          { const bf16* hp_=s_spl+(size_t)(SI)*2048+l15*128+8*q; \
                            _Pragma("unroll") for(int s=0;s<4;++s) aH[s]=*(const bf16x8_t*)(hp_+32*s); } \
                          LOADX_RING(RS) MM_BWD_X() \
                          CH_GATE_X(__bfloat162float(s_spl[(size_t)(SI)*2048+r_*128+j]), SP) }

#define DEC_COMMON(LVL, DT) \
  const int t_=ba+(DT); \
  const bf16* bpM_=MW+((size_t)((LVL)*64+c16))*64+8*q; \
  const bf16x8_t mw0_=*(const bf16x8_t*)(bpM_), mw1_=*(const bf16x8_t*)(bpM_+32); \
  bf16x8_t aG[8]; \
  { const bf16* hp_=s_h+hcur*1696+l15*104+8*q; \
    _Pragma("unroll") for(int s=0;s<4;++s) aG[s]=*(const bf16x8_t*)(hp_+32*s); }

#define DEC_TAIL(LVL, SLOT) \
  { const bf16* bp_=dW+((size_t)((LVL)*64+c16))*256+8*q; \
    f32x4_t a1=(f32x4_t){0,0,0,0},a2=(f32x4_t){0,0,0,0}; \
    _Pragma("unroll") for(int s=0;s<8;s+=2){ \
      a1=MFMA16(aG[s],  *(const bf16x8_t*)(bp_+32*s),    a1); \
      a2=MFMA16(aG[s+1],*(const bf16x8_t*)(bp_+32*(s+1)),a2); } \
    const float db_=db_l[(LVL)]; \
    _Pragma("unroll") for(int i=0;i<4;++i){ float v_=fmaxf(a1[i]+a2[i]+db_,0.f); s_dec[(4*q+i)*72+c16]=__float2bfloat16(v_);} } \
  BAR(); \
  { bf16x8_t aD0=*(const bf16x8_t*)(s_dec+l15*72+8*q), aD1=*(const bf16x8_t*)(s_dec+l15*72+8*q+32); \
    f32x4_t am=(f32x4_t){0,0,0,0}; am=MFMA16(aD0,mw0_,am); am=MFMA16(aD1,mw1_,am); \
    const float mb_=mb_l[(LVL)]; \
    _Pragma("unroll") for(int i=0;i<4;++i){ const int r_=4*q+i; const size_t b_=(size_t)wg*16+r_; \
      const float m_=am[i]+mb_; \
      s_ring[(size_t)((SLOT)*16+r_)*120+c16]=__float2bfloat16(m_); \
      if (c16>=1) out[(b_*64+(c16-1))*256+t_]=m_; else out[(b_*64+63)*256+t_]=1.0f; } } \
  BAR();

#define DEC_SAV(LVL,DT,SLOT) { DEC_COMMON(LVL,DT) \
  _Pragma("unroll") for(int s=0;s<4;++s) aG[4+s]=rS16[s]; \
  DEC_TAIL(LVL,SLOT) }
#define DEC_CUR(LVL,DT,SLOT) { DEC_COMMON(LVL,DT) \
  { const bf16* hp_=s_hbk+bcur*1696+l15*104+8*q; \
    _Pragma("unroll") for(int s=0;s<4;++s) aG[4+s]=*(const bf16x8_t*)(hp_+32*s); } \
  DEC_TAIL(LVL,SLOT) }
#define DEC_SPL(LVL,DT,SLOT,SI) { DEC_COMMON(LVL,DT) \
  { const bf16* hp_=s_spl+(size_t)(SI)*2048+l15*128+8*q; \
    _Pragma("unroll") for(int s=0;s<4;++s) aG[4+s]=*(const bf16x8_t*)(hp_+32*s); } \
  DEC_TAIL(LVL,SLOT) }

#define PREF_RS16(SLOT) { \
  const bf16* ps_=sav+(size_t)(wg*64+(SLOT))*2048+l15*128+8*q; \
  _Pragma("unroll") for(int s=0;s<4;++s) rS16[s]=*(const bf16x8_t*)(ps_+32*s); }
#define PREF_HB(SLOT) { \
  const bf16* ps_=sav+(size_t)(wg*64+(SLOT))*2048+l15*128+8*q; \
  _Pragma("unroll") for(int s=0;s<4;++s) pHB[s]=*(const bf16x8_t*)(ps_+32*s); \
  const bf16* ph_=sav+(size_t)(wg*64+(SLOT))*2048; \
  _Pragma("unroll") for (int g2=0;g2<2;++g2){ if (g2<ng){ const int j=16*(wv+4*g2)+l15; \
    if (j<100){ _Pragma("unroll") for(int i=0;i<4;++i) pHold[g2][i]=__bfloat162float(ph_[(4*q+i)*128+j]); } } } }
#define PREF_PX(T) { \
  const bf16* px_=xT+(((size_t)wg*256+(size_t)(T))*16+l15)*96+8*q; \
  pX[0]=*(const bf16x8_t*)(px_); pX[1]=*(const bf16x8_t*)(px_+32); }

  // prologue: prefetch sav frags for block 0, then FA(0) (pX holds X(t=0))
  PREF_RS16(3)
  PREF_HB(0)
  FA_OP()

  #pragma unroll 1
  for (int blk=0; blk<16; ++blk){
    const int ba=16*blk;
    const int sb=4*blk;    // sav slots: s9=sb, s13=sb+1, s15=sb+2, s16=sb+3
    DEC_SAV(3, 8, 0)
    CH_SAVX(0, 0)
    CH_CUR(1)
    CH_CUR(-1)
    CH_CUR(-1)
    DEC_SPL(2, 4, 4, 0)
    CH_CURX(4, 2)
    CH_CUR(-1)
    DEC_SPL(1, 2, 2, 2)
    CH_CURX(2, -1)
    DEC_CUR(0, 1, 1)
    FF_OP(1) FF_OP(2)
    DEC_SPL(0, 3, 3, 2)
    FF_OP(3) FF_OP(4)
    DEC_SPL(1, 6, 6, 0)
    CH_SPLX(1, 6, -1)
    DEC_CUR(0, 5, 5)
    FF_OP(5) FF_OP(6)
    DEC_SPL(0, 7, 7, 0)
    FF_OP(7) FF_OP(0)
    PREF_HB(sb+1)
    DEC_SAV(2, 12, 4)
    CH_SAVX(4, 3)
    CH_CUR(-1)
    DEC_SPL(1, 10, 2, 3)
    CH_CURX(2, -1)
    DEC_CUR(0, 9, 1)
    FF_OP(1) FF_OP(2)
    DEC_SPL(0, 11, 3, 3)
    FF_OP(3) FF_OP(4)
    PREF_HB(sb+2)
    DEC_SAV(1, 14, 6)
    CH_SAVX(6, -1)
    DEC_CUR(0, 13, 5)
    FF_OP(5) FF_OP(6)
    DEC_SAV(0, 15, 7)
    if (blk<15){
      PREF_RS16(sb+7)
      PREF_HB(sb+4)
      PREF_PX(ba+16)
      FF_OP(7)
      FA_OP()
    }
  }
}

// ---------------- launch ----------------
extern "C" void kernel_launch(void* const* d_in, const int* in_sizes, int n_in,
                              void* d_out, int out_size, void* d_ws, size_t ws_size,
                              hipStream_t stream){
  (void)out_size;
  const float *a=nullptr,*gru_W=nullptr,*gru_U=nullptr,*gru_b=nullptr,*bgru_W=nullptr,
              *bgru_U=nullptr,*bgru_b=nullptr,*dec_W=nullptr,*dec_b=nullptr,
              *mean_W=nullptr,*mean_b=nullptr;
  int nU=0, nb6=0;
  for (int i=0;i<n_in;++i){
    const float* p=(const float*)d_in[i]; int s=in_sizes[i];
    if      (s==25165824) a=p;
    else if (s==19200)    gru_W=p;
    else if (s==19500)    bgru_W=p;
    else if (s==30000)    { if(nU++==0) gru_U=p; else bgru_U=p; }
    else if (s==600)      { if(nb6++==0) gru_b=p; else bgru_b=p; }
    else if (s==40000)    dec_W=p;
    else if (s==200)      dec_b=p;
    else if (s==12800)    mean_W=p;
    else if (s==256)      mean_b=p;
  }
  if (!a||!gru_W||!gru_U||!gru_b||!bgru_W||!bgru_U||!bgru_b||!dec_W||!dec_b||!mean_W||!mean_b){
    a=(const float*)d_in[0]; gru_W=(const float*)d_in[1]; gru_U=(const float*)d_in[2];
    gru_b=(const float*)d_in[3]; bgru_W=(const float*)d_in[4]; bgru_U=(const float*)d_in[5];
    bgru_b=(const float*)d_in[6]; dec_W=(const float*)d_in[7]; dec_b=(const float*)d_in[8];
    mean_W=(const float*)d_in[9]; mean_b=(const float*)d_in[10];
  }
  unsigned char* ws = (unsigned char*)d_ws;
  float* out = (float*)d_out;

  k_obs  <<<512,  64, 0, stream>>>(a, out);
  if (ws_size < WS_NEED) return;

  k_sz   <<<2048, 256, 0, stream>>>((uint4*)(ws+SAV_OFF));
  k_xt   <<<512, 256, 0, stream>>>(a, (bf16*)(ws+XT_OFF));
  k_wt   <<<336, 128, 0, stream>>>(gru_U, bgru_U, gru_W, bgru_W,
                                   (bf16*)(ws+UF_OFF), (bf16*)(ws+UB_OFF),
                                   (bf16*)(ws+WF_OFF), (bf16*)(ws+WB_OFF));
  k_wbf  <<<84,   64, 0, stream>>>((const bf16*)(ws+WB_OFF), (const bf16*)(ws+WF_OFF),
                                   (uint4*)(ws+WBF_OFF));
  k_decw <<<256, 256, 0, stream>>>(dec_W, (bf16*)(ws+DW_OFF));
  k_mw   <<<256,  64, 0, stream>>>(mean_W, (bf16*)(ws+MW_OFF));
  k_consts<<<1,  256, 0, stream>>>(gru_b, bgru_b, mean_b, dec_b, (float*)(ws+CST_OFF));
  naomi_main<<<32, 256, 0, stream>>>(ws, out);
}

// Round 8
// 1694.428 us; speedup vs baseline: 2.8078x; 1.0463x over previous
//
#include <hip/hip_runtime.h>
#include <hip/hip_bf16.h>
#include <cstdint>
#include <cstddef>

using bf16 = __hip_bfloat16;
typedef __attribute__((ext_vector_type(8))) short   bf16x8_t;  // 8 bf16 (4 VGPRs)
typedef __attribute__((ext_vector_type(4))) float   f32x4_t;   // mfma accumulator

// ---------------- workspace byte offsets ----------------
#define XT_OFF   ((size_t)0)            // [32 wg][256 t][16 r][96] bf16 (coalesced per-wave X)
#define UF_OFF   ((size_t)25165824)     // [336][128] bf16 gate-ordered U strips (fwd)
#define UB_OFF   ((size_t)25251840)     // (bwd)
#define WF_OFF   ((size_t)25337856)     // fwd W shifted: row k -> gru_W[k-1], k=1..64 (K=128 strip)
#define WB_OFF   ((size_t)25423872)     // bwd W: row k -> bgru_W[k], k=0..64
#define DW_OFF   ((size_t)25509888)     // dec_W strips [4][64][256] bf16
#define MW_OFF   ((size_t)25640960)     // mean_W^T strips [4][64][64] bf16
#define SAV_OFF  ((size_t)25673728)     // saved h_back [32 wg][64 slot][16*128] bf16 (8,388,608 B)
#define CST_OFF  ((size_t)34062336)     // fp32: bf0,bf1,bb0,bb1[336 ea], mb[256], db[256]
#define WBF_OFF  ((size_t)34069760)     // frag-linear W tables: [Wb 43008 B][Wf 43008 B]
#define WS_NEED  ((size_t)34155776)

// LDS frag-table bases (permanent)
#define WBF_LDS  63024
#define WFF_LDS  106032
// total LDS = 63024 + 86016 = 149,040 B (<= 160 KiB, 1 WG/CU)

#define MFMA16(a,b,c) __builtin_amdgcn_mfma_f32_16x16x32_bf16((a),(b),(c),0,0,0)

// counted barrier: drain LDS only; global loads/stores stay in flight across it.
#define BAR()    asm volatile("s_waitcnt lgkmcnt(0)\n\ts_barrier" ::: "memory")

// ---------------- prep kernels (fp32 inputs -> bf16 internal) ----------------
__global__ void k_xt(const float* __restrict__ a, bf16* __restrict__ xT){
  int b=blockIdx.x, t=threadIdx.x;
  int wgi=b>>4, r=b&15;
  bf16 buf[96];
  const float* ap = a + (size_t)b*64*256*3;
  #pragma unroll
  for (int c=0;c<64;++c) buf[c] = __float2bfloat16(ap[((size_t)c*256+t)*3]);
  buf[64] = __float2bfloat16(ap[(size_t)t*3 + 2]);
  bf16 z = __float2bfloat16(0.f);
  #pragma unroll
  for (int c=65;c<96;++c) buf[c]=z;
  uint4* dst = (uint4*)(xT + (((size_t)wgi*256 + t)*16 + r)*96);
  const uint4* src = (const uint4*)buf;
  #pragma unroll
  for (int k=0;k<12;++k) dst[k]=src[k];
}

__global__ void k_obs(const float* __restrict__ a, float* __restrict__ out){
  int b=blockIdx.x, d=threadIdx.x; // 64 threads
  for (int kk=0;kk<16;++kk){ int t=kk*16;
    float v = (d<63)? a[(((size_t)b*64 + d+1)*256 + t)*3]
                    : a[((size_t)b*64*256 + t)*3 + 2];
    out[((size_t)b*64 + d)*256 + t] = v;
  }
}

__global__ void k_wt(const float* __restrict__ gru_U, const float* __restrict__ bgru_U,
                     const float* __restrict__ gru_W, const float* __restrict__ bgru_W,
                     bf16* Uf, bf16* Ub, bf16* Wf, bf16* Wb){
  int c=blockIdx.x, k=threadIdx.x; // 336 x 128
  int g=c/48, rm=c%48, e=rm/16, l=rm%16, j=16*g+l;
  bool val = j<100; int gc = val? (e*100+j) : 0;
  bf16 z = __float2bfloat16(0.f);
  Uf[(size_t)c*128+k] = (val&&k<100)? __float2bfloat16(gru_U[k*300+gc]) : z;
  Ub[(size_t)c*128+k] = (val&&k<100)? __float2bfloat16(bgru_U[k*300+gc]) : z;
  Wf[(size_t)c*128+k] = (val&&k>=1&&k<=64)? __float2bfloat16(gru_W[(k-1)*300+gc]) : z;
  Wb[(size_t)c*128+k] = (val&&k<65)? __float2bfloat16(bgru_W[k*300+gc]) : z;
}

// frag-linear copy of W tables (k=0..63, 2 slices): [tbl][strip st][e][s][lane]
__global__ void k_wbf(const bf16* __restrict__ Wb, const bf16* __restrict__ Wf,
                      uint4* __restrict__ dst){
  int bid=blockIdx.x;  // 84: 0..41 Wb, 42..83 Wf
  int l=threadIdx.x;   // 64
  int tbl=bid/42, r2=bid%42;
  int st=r2/6, rr=r2%6, e=rr/2, s=rr%2;
  int c=48*st+16*e+(l&15);
  int k=8*(l>>4)+32*s;
  const bf16* src = tbl? Wf : Wb;
  dst[bid*64+l] = *(const uint4*)(src + (size_t)c*128 + k);
}

__global__ void k_decw(const float* __restrict__ dec_W, bf16* dWt){
  int idx=blockIdx.x; int lvl=idx/64, n=idx%64; int k=threadIdx.x; // 256 blocks x 256 thr
  float v=0.f;
  if (n<50){
    if (k<100) v = dec_W[(lvl*200+k)*50+n];            // h rows 0..99
    else if (k>=128 && k<228) v = dec_W[(lvl*200+k-28)*50+n]; // hb rows 100..199
  }
  dWt[(size_t)idx*256+k] = __float2bfloat16(v);
}

__global__ void k_mw(const float* __restrict__ mean_W, bf16* MW){
  int idx=blockIdx.x; int lvl=idx/64, c=idx%64; int k=threadIdx.x; // 64
  MW[(size_t)idx*64+k] = (k<50)? __float2bfloat16(mean_W[(lvl*50+k)*64+c]) : __float2bfloat16(0.f);
}

__global__ void k_consts(const float* __restrict__ gru_b, const float* __restrict__ bgru_b,
                         const float* __restrict__ mean_b, const float* __restrict__ dec_b,
                         float* cst){
  int tid=threadIdx.x;
  for (int u=tid; u<336; u+=256){
    int c=u; int g=c/48, rm=c%48, e=rm/16, l=rm%16, j=16*g+l;
    float b0f=0,b1f=0,b0b=0,b1b=0;
    if (j<100){ int gc=e*100+j;
      b0f=gru_b[gc];  b1f=gru_b[300+gc];
      b0b=bgru_b[gc]; b1b=bgru_b[300+gc]; }
    cst[u]=b0f; cst[336+u]=b1f; cst[672+u]=b0b; cst[1008+u]=b1b;
  }
  if (tid<256){
    int lvl=tid/64, m=tid%64;
    cst[1344+tid]=mean_b[lvl*64+m];
    cst[1600+tid]=(m<50)? dec_b[lvl*50+m] : 0.f;
  }
}

__global__ void k_sz(uint4* p){
  p[(size_t)blockIdx.x*256 + threadIdx.x] = make_uint4(0u,0u,0u,0u);
}

// ---------------- specialized backward GRU cell ----------------
static __device__ __forceinline__ void bcell_step(
  int t, int bc, int sv,
  unsigned char* smem, const bf16* xT, unsigned char* sav8,
  int wg, int tid, int l15, int q, int wv, int ng,
  const bf16x8_t (&rUb)[2][3][4], const float (&W64b)[2][3],
  const float (&Bz0)[2][2], const float (&Br0)[2][2], const float (&Bn0)[2][2],
  const float (&Bz1)[2][2], const float (&Br1)[2][2], const float (&Bn1)[2][2],
  float (&hb_reg)[2][4], bf16x8_t (&pX)[2])
{
  const int lane = tid & 63;
  const bf16* px = xT + (((size_t)wg*256 + (t-1))*16 + l15)*96 + 8*q;
  bf16x8_t nX0 = *(const bf16x8_t*)(px);
  bf16x8_t nX1 = *(const bf16x8_t*)(px + 32);
  const bf16* hp = (const bf16*)(smem + 6784) + bc*1696 + l15*104 + 8*q;
  bf16x8_t aH[4];
  #pragma unroll
  for (int s=0;s<4;++s) aH[s] = *(const bf16x8_t*)(hp + 32*s);

  f32x4_t accB[2][3], accA[2][3];
  #pragma unroll
  for (int g2=0;g2<2;++g2)
    #pragma unroll
    for (int e=0;e<3;++e){ accB[g2][e]=(f32x4_t){0,0,0,0}; accA[g2][e]=(f32x4_t){0,0,0,0}; }

  #pragma unroll
  for (int g2=0;g2<2;++g2){ if (g2<ng){
    #pragma unroll
    for (int e=0;e<3;++e){
      #pragma unroll
      for (int s=0;s<4;++s)
        accB[g2][e] = MFMA16(aH[s], rUb[g2][e][s], accB[g2][e]);
    } } }
  #pragma unroll
  for (int g2=0;g2<2;++g2){ if (g2<ng){
    #pragma unroll
    for (int e=0;e<3;++e){
      #pragma unroll
      for (int s=0;s<2;++s){
        const bf16x8_t bw = *(const bf16x8_t*)(smem + WBF_LDS + ((((wv+4*g2)*3+e)*2+s)<<10) + lane*16);
        accA[g2][e] = MFMA16(pX[s], bw, accA[g2][e]);
      } } } }
  if (sv>=0 && tid<208){
    int r=tid/13, cc=tid-13*r;
    const uint4 v = *(const uint4*)(smem + 6784 + bc*3392 + r*208 + cc*16);
    *(uint4*)(sav8 + ((size_t)(wg*64+sv))*4096 + (size_t)r*256 + cc*16) = v;
  }
  const bool mk = ((t&15)==0);
  bf16* wr = (bf16*)(smem + 6784) + (bc^1)*1696;
  #pragma unroll
  for (int g2=0;g2<2;++g2){ if (g2<ng){ int j=16*(wv+4*g2)+l15;
    if (j<100){
      float b0z=Bz0[g2][0], b0r=Br0[g2][0], b0n=Bn0[g2][0];
      float b1z=Bz1[g2][0], b1r=Br1[g2][0], b1n=Bn1[g2][0];
      #pragma unroll
      for (int i=0;i<4;++i){
        int r=4*q+i;
        float gz=accA[g2][0][i], gr=accA[g2][1][i], gn=accA[g2][2][i];
        if (mk){ gz+=W64b[g2][0]; gr+=W64b[g2][1]; gn+=W64b[g2][2]; }
        float hz=accB[g2][0][i], hr=accB[g2][1][i], hnv=accB[g2][2][i];
        float hold = hb_reg[g2][i];
        // sigmoid is IEEE-safe unclamped: exp(+inf)->inf, 1/(1+inf)->0
        float az = gz+b0z+hz+b1z;
        float ar = gr+b0r+hr+b1r;
        float z  = 1.f/(1.f+__expf(-az));
        float rg = 1.f/(1.f+__expf(-ar));
        float an = gn+b0n+rg*(hnv+b1n); an=fminf(fmaxf(an,-15.f),15.f);
        float e2 = __expf(2.f*an);
        float nn = (e2-1.f)/(e2+1.f);
        float hnew = z*hold + (1.f-z)*nn;
        hb_reg[g2][i]=hnew;
        wr[r*104+j] = __float2bfloat16(hnew);
      }
    } } }
  pX[0]=nX0; pX[1]=nX1;
  BAR();
}

// ---------------- main persistent kernel: 32 WGs x 256 thr, 16 batch rows each ----------------
__launch_bounds__(256, 1)
__global__ void naomi_main(unsigned char* __restrict__ ws, float* __restrict__ out){
  const int tid=threadIdx.x, wg=blockIdx.x;
  const int lane=tid&63, wv=tid>>6;
  const int l15=lane&15, q=lane>>4;
  const int ng=(wv<3)?2:1;

  const bf16* xT = (const bf16*)(ws + XT_OFF);
  const bf16* Uf = (const bf16*)(ws + UF_OFF);
  const bf16* Ub = (const bf16*)(ws + UB_OFF);
  const bf16* Wf = (const bf16*)(ws + WF_OFF);
  const bf16* Wb = (const bf16*)(ws + WB_OFF);
  const bf16* dW = (const bf16*)(ws + DW_OFF);
  const bf16* MW = (const bf16*)(ws + MW_OFF);
  bf16* sav = (bf16*)(ws + SAV_OFF);
  unsigned char* sav8 = (unsigned char*)(ws + SAV_OFF);
  const float* cst = (const float*)(ws + CST_OFF);

  // LDS (149,040 B): s_h 2x[16][104] | s_hbk 2x[16][104] | s_dec [16][72]+pad |
  //   ring [8][16][120] | spl [4][16][104] (stride 1664 elem; frag-tail overflow lands in
  //   zeroed LDS and is killed by B-operand zeros at k>=100) | Wb frags | Wf frags
  __shared__ alignas(16) unsigned char smem[149040];
  bf16* s_h    = (bf16*)(smem + 0);      // 6784 B (two 1696-elem buffers)
  bf16* s_hbk  = (bf16*)(smem + 6784);   // 6784 B
  bf16* s_dec  = (bf16*)(smem + 13568);  // 2352 B
  bf16* s_ring = (bf16*)(smem + 15920);  // 30720 B
  bf16* s_spl  = (bf16*)(smem + 46640);  // 13312 B used (+ zeroed slack to 63024)

  for (int u=tid; u<15756; u+=256) ((uint32_t*)smem)[u]=0u;
  { uint4* df=(uint4*)(smem+WBF_LDS); const uint4* sf=(const uint4*)(ws+WBF_OFF);
    for (int u=tid; u<5376; u+=256) df[u]=sf[u]; }

  // per-thread gate biases [g2][dir: 0=bwd 1=fwd]
  float Bz0[2][2],Br0[2][2],Bn0[2][2],Bz1[2][2],Br1[2][2],Bn1[2][2];
  #pragma unroll
  for (int g2=0; g2<2; ++g2){
    if (g2<ng){
      int cz=48*(wv+4*g2)+l15;
      Bz0[g2][1]=cst[cz];      Br0[g2][1]=cst[cz+16];      Bn0[g2][1]=cst[cz+32];
      Bz1[g2][1]=cst[336+cz];  Br1[g2][1]=cst[336+cz+16];  Bn1[g2][1]=cst[336+cz+32];
      Bz0[g2][0]=cst[672+cz];  Br0[g2][0]=cst[672+cz+16];  Bn0[g2][0]=cst[672+cz+32];
      Bz1[g2][0]=cst[1008+cz]; Br1[g2][0]=cst[1008+cz+16]; Bn1[g2][0]=cst[1008+cz+32];
    } else {
      Bz0[g2][0]=Bz0[g2][1]=Br0[g2][0]=Br0[g2][1]=Bn0[g2][0]=Bn0[g2][1]=0.f;
      Bz1[g2][0]=Bz1[g2][1]=Br1[g2][0]=Br1[g2][1]=Bn1[g2][0]=Bn1[g2][1]=0.f;
    }
  }
  const int c16 = 16*wv+l15;
  float mb_l[4], db_l[4];
  #pragma unroll
  for (int l=0;l<4;++l){ mb_l[l]=cst[1344+l*64+c16]; db_l[l]=cst[1600+l*64+c16]; }

  bf16x8_t rUf[2][3][4], rUb[2][3][4];
  #pragma unroll
  for (int g2=0; g2<2; ++g2){
    if (g2<ng){
      #pragma unroll
      for (int e=0;e<3;++e){ int c=48*(wv+4*g2)+16*e+l15;
        #pragma unroll
        for (int s=0;s<4;++s)
          rUb[g2][e][s] = *(const bf16x8_t*)(Ub + (size_t)c*128 + 8*q + 32*s);
      }
    }
  }
  float W64b[2][3], W64f[2][3];
  #pragma unroll
  for (int g2=0; g2<2; ++g2){
    if (g2<ng){
      #pragma unroll
      for (int e=0;e<3;++e){ int c=48*(wv+4*g2)+16*e+l15;
        W64b[g2][e] = __bfloat162float(Wb[(size_t)c*128 + 64]);
        W64f[g2][e] = __bfloat162float(Wf[(size_t)c*128 + 64]); }
    } else {
      W64b[g2][0]=W64b[g2][1]=W64b[g2][2]=0.f;
      W64f[g2][0]=W64f[g2][1]=W64f[g2][2]=0.f;
    }
  }
  __syncthreads();

  float h_reg[2][4], hb_reg[2][4];
  #pragma unroll
  for (int g2=0;g2<2;++g2){
    #pragma unroll
    for (int i=0;i<4;++i){ h_reg[g2][i]=0.f; hb_reg[g2][i]=0.f; }
  }
  int hcur=0, bcur=0;

  bf16x8_t pX[2], pHB[4], rS16[4];
  float pHold[2][4];
  #pragma unroll
  for (int g2=0;g2<2;++g2){
    #pragma unroll
    for (int i=0;i<4;++i) pHold[g2][i]=0.f;
  }
  { const bf16* px = xT + (((size_t)wg*256 + 255)*16 + l15)*96 + 8*q;
    pX[0] = *(const bf16x8_t*)(px);
    pX[1] = *(const bf16x8_t*)(px + 32);
  }

  // ================= specialized backward sweep: t = 255 .. 1 =================
  bcell_step(255, 0, 63, smem, xT, sav8, wg, tid, l15, q, wv, ng,
             rUb, W64b, Bz0, Br0, Bn0, Bz1, Br1, Bn1, hb_reg, pX);
  for (int t=254; t>=2; t-=2){
    int m=t&15;
    int sv1 = (m==8)? ((t>>4)<<2) : (m==12)? (((t>>4)<<2)+1) : (m==14)? (((t>>4)<<2)+2) : -1;
    bcell_step(t, 1, sv1, smem, xT, sav8, wg, tid, l15, q, wv, ng,
               rUb, W64b, Bz0, Br0, Bn0, Bz1, Br1, Bn1, hb_reg, pX);
    int sv2 = (((t-1)&15)==15)? ((((t-1)>>4)<<2)+3) : -1;
    bcell_step(t-1, 0, sv2, smem, xT, sav8, wg, tid, l15, q, wv, ng,
               rUb, W64b, Bz0, Br0, Bn0, Bz1, Br1, Bn1, hb_reg, pX);
  }
  bcur = 1;   // parity after 255 steps

  // ================= bwd -> fwd transition =================
  #pragma unroll
  for (int g2=0; g2<2; ++g2){
    if (g2<ng){
      #pragma unroll
      for (int e=0;e<3;++e){ int c=48*(wv+4*g2)+16*e+l15;
        #pragma unroll
        for (int s=0;s<4;++s)
          rUf[g2][e][s] = *(const bf16x8_t*)(Uf + (size_t)c*128 + 8*q + 32*s);
      }
    }
  }
  __syncthreads();   // full drain: sav stores visible before fwd sav reads

  // ================= straight-line forward phase =================
#define GRU_MATH() \
  float az=gz+b0z+hz+b1z; \
  float ar=gr+b0r+hr+b1r; \
  float z_=1.f/(1.f+__expf(-az)); float rg=1.f/(1.f+__expf(-ar)); \
  float an=gn+b0n+rg*(hnv+b1n); an=fminf(fmaxf(an,-15.f),15.f); \
  float e2=__expf(2.f*an); float nn=(e2-1.f)/(e2+1.f); \
  float hnew=z_*hold+(1.f-z_)*nn;

#define LOADH_SH() \
  { const bf16* hp_=s_h+hcur*1696+l15*104+8*q; \
    _Pragma("unroll") for(int s=0;s<4;++s) aH[s]=*(const bf16x8_t*)(hp_+32*s); }
#define LOADH_HBK() \
  { const bf16* hp_=s_hbk+bcur*1696+l15*104+8*q; \
    _Pragma("unroll") for(int s=0;s<4;++s) aH[s]=*(const bf16x8_t*)(hp_+32*s); }
#define LOADX_RING(RS) \
  bf16x8_t aX0,aX1; \
  { const bf16* xp_=s_ring+(size_t)((RS)*16+l15)*120+8*q; \
    aX0=*(const bf16x8_t*)(xp_); aX1=*(const bf16x8_t*)(xp_+32); }

#define MM_FWD() \
  f32x4_t accB[2][3], accA[2][3]; \
  _Pragma("unroll") for (int g2=0;g2<2;++g2){ _Pragma("unroll") for (int e=0;e<3;++e){ accB[g2][e]=(f32x4_t){0,0,0,0}; accA[g2][e]=(f32x4_t){0,0,0,0}; } } \
  _Pragma("unroll") for (int g2=0;g2<2;++g2){ if (g2<ng){ \
    _Pragma("unroll") for (int e=0;e<3;++e){ \
      _Pragma("unroll") for (int s=0;s<4;++s) accB[g2][e]=MFMA16(aH[s],rUf[g2][e][s],accB[g2][e]); \
      const unsigned char* fb_=smem+WFF_LDS+((((wv+4*g2)*3+e)*2)<<10)+lane*16; \
      accA[g2][e]=MFMA16(aX0,*(const bf16x8_t*)(fb_),accA[g2][e]); \
      accA[g2][e]=MFMA16(aX1,*(const bf16x8_t*)(fb_+1024),accA[g2][e]); } } }

#define MM_BWD_X() \
  f32x4_t accB[2][3], accA[2][3]; \
  _Pragma("unroll") for (int g2=0;g2<2;++g2){ _Pragma("unroll") for (int e=0;e<3;++e){ accB[g2][e]=(f32x4_t){0,0,0,0}; accA[g2][e]=(f32x4_t){0,0,0,0}; } } \
  _Pragma("unroll") for (int g2=0;g2<2;++g2){ if (g2<ng){ \
    _Pragma("unroll") for (int e=0;e<3;++e){ \
      _Pragma("unroll") for (int s=0;s<4;++s) accB[g2][e]=MFMA16(aH[s],rUb[g2][e][s],accB[g2][e]); \
      const unsigned char* fb_=smem+WBF_LDS+((((wv+4*g2)*3+e)*2)<<10)+lane*16; \
      accA[g2][e]=MFMA16(aX0,*(const bf16x8_t*)(fb_),accA[g2][e]); \
      accA[g2][e]=MFMA16(aX1,*(const bf16x8_t*)(fb_+1024),accA[g2][e]); } } }

#define MM_BWD_NOX() \
  f32x4_t accB[2][3]; \
  _Pragma("unroll") for (int g2=0;g2<2;++g2){ _Pragma("unroll") for (int e=0;e<3;++e) accB[g2][e]=(f32x4_t){0,0,0,0}; } \
  _Pragma("unroll") for (int g2=0;g2<2;++g2){ if (g2<ng){ \
    _Pragma("unroll") for (int e=0;e<3;++e){ \
      _Pragma("unroll") for (int s=0;s<4;++s) accB[g2][e]=MFMA16(aH[s],rUb[g2][e][s],accB[g2][e]); } } }

#define FWD_GATE() \
  { bf16* wr_=s_h+(hcur^1)*1696; \
    _Pragma("unroll") for (int g2=0;g2<2;++g2){ if (g2<ng){ const int j=16*(wv+4*g2)+l15; \
      if (j<100){ \
        const float b0z=Bz0[g2][1],b0r=Br0[g2][1],b0n=Bn0[g2][1],b1z=Bz1[g2][1],b1r=Br1[g2][1],b1n=Bn1[g2][1]; \
        _Pragma("unroll") for (int i=0;i<4;++i){ const int r_=4*q+i; \
          const float gz=accA[g2][0][i]+W64f[g2][0], gr=accA[g2][1][i]+W64f[g2][1], gn=accA[g2][2][i]+W64f[g2][2]; \
          const float hz=accB[g2][0][i],hr=accB[g2][1][i],hnv=accB[g2][2][i]; \
          const float hold=h_reg[g2][i]; \
          GRU_MATH() \
          h_reg[g2][i]=hnew; wr_[r_*104+j]=__float2bfloat16(hnew); } } } } \
    hcur^=1; BAR(); }

#define CH_GATE_X(HOLDE, SP) \
  { bf16* wr_=s_hbk+(bcur^1)*1696; \
    _Pragma("unroll") for (int g2=0;g2<2;++g2){ if (g2<ng){ const int j=16*(wv+4*g2)+l15; \
      if (j<100){ \
        const float b0z=Bz0[g2][0],b0r=Br0[g2][0],b0n=Bn0[g2][0],b1z=Bz1[g2][0],b1r=Br1[g2][0],b1n=Bn1[g2][0]; \
        _Pragma("unroll") for (int i=0;i<4;++i){ const int r_=4*q+i; \
          const float gz=accA[g2][0][i]+W64b[g2][0], gr=accA[g2][1][i]+W64b[g2][1], gn=accA[g2][2][i]+W64b[g2][2]; \
          const float hz=accB[g2][0][i],hr=accB[g2][1][i],hnv=accB[g2][2][i]; \
          const float hold=(HOLDE); \
          GRU_MATH() \
          hb_reg[g2][i]=hnew; wr_[r_*104+j]=__float2bfloat16(hnew); \
          if ((SP)>=0) s_spl[(size_t)(SP)*1664+r_*104+j]=__float2bfloat16(hnew); } } } } \
    bcur^=1; BAR(); }

#define CH_GATE_NOX(HOLDE, SP) \
  { bf16* wr_=s_hbk+(bcur^1)*1696; \
    _Pragma("unroll") for (int g2=0;g2<2;++g2){ if (g2<ng){ const int j=16*(wv+4*g2)+l15; \
      if (j<100){ \
        const float b0z=Bz0[g2][0],b0r=Br0[g2][0],b0n=Bn0[g2][0],b1z=Bz1[g2][0],b1r=Br1[g2][0],b1n=Bn1[g2][0]; \
        _Pragma("unroll") for (int i=0;i<4;++i){ const int r_=4*q+i; \
          const float gz=0.f, gr=0.f, gn=0.f; \
          const float hz=accB[g2][0][i],hr=accB[g2][1][i],hnv=accB[g2][2][i]; \
          const float hold=(HOLDE); \
          GRU_MATH() \
          hb_reg[g2][i]=hnew; wr_[r_*104+j]=__float2bfloat16(hnew); \
          if ((SP)>=0) s_spl[(size_t)(SP)*1664+r_*104+j]=__float2bfloat16(hnew); } } } } \
    bcur^=1; BAR(); }

#define FF_OP(RS)       { bf16x8_t aH[4]; LOADH_SH()  LOADX_RING(RS) MM_FWD()   FWD_GATE() }
#define FA_OP()         { bf16x8_t aH[4]; LOADH_SH()  bf16x8_t aX0=pX[0],aX1=pX[1]; MM_FWD() FWD_GATE() }
#define CH_CUR(SP)      { bf16x8_t aH[4]; LOADH_HBK() MM_BWD_NOX() CH_GATE_NOX(hb_reg[g2][i], SP) }
#define CH_CURX(RS,SP)  { bf16x8_t aH[4]; LOADH_HBK() LOADX_RING(RS) MM_BWD_X() CH_GATE_X(hb_reg[g2][i], SP) }
#define CH_SAVX(RS,SP)  { bf16x8_t aH[4]; _Pragma("unroll") for(int s=0;s<4;++s) aH[s]=pHB[s]; \
                          LOADX_RING(RS) MM_BWD_X() CH_GATE_X(pHold[g2][i], SP) }
#define CH_SPLX(SI,RS,SP) { bf16x8_t aH[4]; \
                          { const bf16* hp_=s_spl+(size_t)(SI)*1664+l15*104+8*q; \
                            _Pragma("unroll") for(int s=0;s<4;++s) aH[s]=*(const bf16x8_t*)(hp_+32*s); } \
                          LOADX_RING(RS) MM_BWD_X() \
                          CH_GATE_X(__bfloat162float(s_spl[(size_t)(SI)*1664+r_*104+j]), SP) }

#define DEC_COMMON(LVL, DT) \
  const int t_=ba+(DT); \
  const bf16* bpM_=MW+((size_t)((LVL)*64+c16))*64+8*q; \
  const bf16x8_t mw0_=*(const bf16x8_t*)(bpM_), mw1_=*(const bf16x8_t*)(bpM_+32); \
  bf16x8_t aG[8]; \
  { const bf16* hp_=s_h+hcur*1696+l15*104+8*q; \
    _Pragma("unroll") for(int s=0;s<4;++s) aG[s]=*(const bf16x8_t*)(hp_+32*s); }

#define DEC_TAIL(LVL, SLOT) \
  { const bf16* bp_=dW+((size_t)((LVL)*64+c16))*256+8*q; \
    f32x4_t a1=(f32x4_t){0,0,0,0},a2=(f32x4_t){0,0,0,0}; \
    _Pragma("unroll") for(int s=0;s<8;s+=2){ \
      a1=MFMA16(aG[s],  *(const bf16x8_t*)(bp_+32*s),    a1); \
      a2=MFMA16(aG[s+1],*(const bf16x8_t*)(bp_+32*(s+1)),a2); } \
    const float db_=db_l[(LVL)]; \
    _Pragma("unroll") for(int i=0;i<4;++i){ float v_=fmaxf(a1[i]+a2[i]+db_,0.f); s_dec[(4*q+i)*72+c16]=__float2bfloat16(v_);} } \
  BAR(); \
  { bf16x8_t aD0=*(const bf16x8_t*)(s_dec+l15*72+8*q), aD1=*(const bf16x8_t*)(s_dec+l15*72+8*q+32); \
    f32x4_t am=(f32x4_t){0,0,0,0}; am=MFMA16(aD0,mw0_,am); am=MFMA16(aD1,mw1_,am); \
    const float mb_=mb_l[(LVL)]; \
    _Pragma("unroll") for(int i=0;i<4;++i){ const int r_=4*q+i; const size_t b_=(size_t)wg*16+r_; \
      const float m_=am[i]+mb_; \
      s_ring[(size_t)((SLOT)*16+r_)*120+c16]=__float2bfloat16(m_); \
      if (c16>=1) out[(b_*64+(c16-1))*256+t_]=m_; else out[(b_*64+63)*256+t_]=1.0f; } } \
  BAR();

#define DEC_SAV(LVL,DT,SLOT) { DEC_COMMON(LVL,DT) \
  _Pragma("unroll") for(int s=0;s<4;++s) aG[4+s]=rS16[s]; \
  DEC_TAIL(LVL,SLOT) }
#define DEC_CUR(LVL,DT,SLOT) { DEC_COMMON(LVL,DT) \
  { const bf16* hp_=s_hbk+bcur*1696+l15*104+8*q; \
    _Pragma("unroll") for(int s=0;s<4;++s) aG[4+s]=*(const bf16x8_t*)(hp_+32*s); } \
  DEC_TAIL(LVL,SLOT) }
#define DEC_SPL(LVL,DT,SLOT,SI) { DEC_COMMON(LVL,DT) \
  { const bf16* hp_=s_spl+(size_t)(SI)*1664+l15*104+8*q; \
    _Pragma("unroll") for(int s=0;s<4;++s) aG[4+s]=*(const bf16x8_t*)(hp_+32*s); } \
  DEC_TAIL(LVL,SLOT) }

#define PREF_RS16(SLOT) { \
  const bf16* ps_=sav+(size_t)(wg*64+(SLOT))*2048+l15*128+8*q; \
  _Pragma("unroll") for(int s=0;s<4;++s) rS16[s]=*(const bf16x8_t*)(ps_+32*s); }
#define PREF_HB(SLOT) { \
  const bf16* ps_=sav+(size_t)(wg*64+(SLOT))*2048+l15*128+8*q; \
  _Pragma("unroll") for(int s=0;s<4;++s) pHB[s]=*(const bf16x8_t*)(ps_+32*s); \
  const bf16* ph_=sav+(size_t)(wg*64+(SLOT))*2048; \
  _Pragma("unroll") for (int g2=0;g2<2;++g2){ if (g2<ng){ const int j=16*(wv+4*g2)+l15; \
    if (j<100){ _Pragma("unroll") for(int i=0;i<4;++i) pHold[g2][i]=__bfloat162float(ph_[(4*q+i)*128+j]); } } } }
#define PREF_PX(T) { \
  const bf16* px_=xT+(((size_t)wg*256+(size_t)(T))*16+l15)*96+8*q; \
  pX[0]=*(const bf16x8_t*)(px_); pX[1]=*(const bf16x8_t*)(px_+32); }

  // prologue: prefetch sav frags for block 0, then FA(0) (pX holds X(t=0))
  PREF_RS16(3)
  PREF_HB(0)
  FA_OP()

  #pragma unroll 1
  for (int blk=0; blk<16; ++blk){
    const int ba=16*blk;
    const int sb=4*blk;    // sav slots: s9=sb, s13=sb+1, s15=sb+2, s16=sb+3
    DEC_SAV(3, 8, 0)
    CH_SAVX(0, 0)
    CH_CUR(1)
    CH_CUR(-1)
    CH_CUR(-1)
    DEC_SPL(2, 4, 4, 0)
    CH_CURX(4, 2)
    CH_CUR(-1)
    DEC_SPL(1, 2, 2, 2)
    CH_CURX(2, -1)
    DEC_CUR(0, 1, 1)
    FF_OP(1) FF_OP(2)
    DEC_SPL(0, 3, 3, 2)
    FF_OP(3) FF_OP(4)
    DEC_SPL(1, 6, 6, 0)
    CH_SPLX(1, 6, -1)
    DEC_CUR(0, 5, 5)
    FF_OP(5) FF_OP(6)
    DEC_SPL(0, 7, 7, 0)
    FF_OP(7) FF_OP(0)
    PREF_HB(sb+1)
    DEC_SAV(2, 12, 4)
    CH_SAVX(4, 3)
    CH_CUR(-1)
    DEC_SPL(1, 10, 2, 3)
    CH_CURX(2, -1)
    DEC_CUR(0, 9, 1)
    FF_OP(1) FF_OP(2)
    DEC_SPL(0, 11, 3, 3)
    FF_OP(3) FF_OP(4)
    PREF_HB(sb+2)
    DEC_SAV(1, 14, 6)
    CH_SAVX(6, -1)
    DEC_CUR(0, 13, 5)
    FF_OP(5) FF_OP(6)
    DEC_SAV(0, 15, 7)
    if (blk<15){
      PREF_RS16(sb+7)
      PREF_HB(sb+4)
      PREF_PX(ba+16)
      FF_OP(7)
      FA_OP()
    }
  }
}

// ---------------- launch ----------------
extern "C" void kernel_launch(void* const* d_in, const int* in_sizes, int n_in,
                              void* d_out, int out_size, void* d_ws, size_t ws_size,
                              hipStream_t stream){
  (void)out_size;
  const float *a=nullptr,*gru_W=nullptr,*gru_U=nullptr,*gru_b=nullptr,*bgru_W=nullptr,
              *bgru_U=nullptr,*bgru_b=nullptr,*dec_W=nullptr,*dec_b=nullptr,
              *mean_W=nullptr,*mean_b=nullptr;
  int nU=0, nb6=0;
  for (int i=0;i<n_in;++i){
    const float* p=(const float*)d_in[i]; int s=in_sizes[i];
    if      (s==25165824) a=p;
    else if (s==19200)    gru_W=p;
    else if (s==19500)    bgru_W=p;
    else if (s==30000)    { if(nU++==0) gru_U=p; else bgru_U=p; }
    else if (s==600)      { if(nb6++==0) gru_b=p; else bgru_b=p; }
    else if (s==40000)    dec_W=p;
    else if (s==200)      dec_b=p;
    else if (s==12800)    mean_W=p;
    else if (s==256)      mean_b=p;
  }
  if (!a||!gru_W||!gru_U||!gru_b||!bgru_W||!bgru_U||!bgru_b||!dec_W||!dec_b||!mean_W||!mean_b){
    a=(const float*)d_in[0]; gru_W=(const float*)d_in[1]; gru_U=(const float*)d_in[2];
    gru_b=(const float*)d_in[3]; bgru_W=(const float*)d_in[4]; bgru_U=(const float*)d_in[5];
    bgru_b=(const float*)d_in[6]; dec_W=(const float*)d_in[7]; dec_b=(const float*)d_in[8];
    mean_W=(const float*)d_in[9]; mean_b=(const float*)d_in[10];
  }
  unsigned char* ws = (unsigned char*)d_ws;
  float* out = (float*)d_out;

  k_obs  <<<512,  64, 0, stream>>>(a, out);
  if (ws_size < WS_NEED) return;

  k_sz   <<<2048, 256, 0, stream>>>((uint4*)(ws+SAV_OFF));
  k_xt   <<<512, 256, 0, stream>>>(a, (bf16*)(ws+XT_OFF));
  k_wt   <<<336, 128, 0, stream>>>(gru_U, bgru_U, gru_W, bgru_W,
                                   (bf16*)(ws+UF_OFF), (bf16*)(ws+UB_OFF),
                                   (bf16*)(ws+WF_OFF), (bf16*)(ws+WB_OFF));
  k_wbf  <<<84,   64, 0, stream>>>((const bf16*)(ws+WB_OFF), (const bf16*)(ws+WF_OFF),
                                   (uint4*)(ws+WBF_OFF));
  k_decw <<<256, 256, 0, stream>>>(dec_W, (bf16*)(ws+DW_OFF));
  k_mw   <<<256,  64, 0, stream>>>(mean_W, (bf16*)(ws+MW_OFF));
  k_consts<<<1,  256, 0, stream>>>(gru_b, bgru_b, mean_b, dec_b, (float*)(ws+CST_OFF));
  naomi_main<<<32, 256, 0, stream>>>(ws, out);
}